// Round 7
// baseline (2045.398 us; speedup 1.0000x reference)
//
#include <hip/hip_runtime.h>

// ---------------------------------------------------------------------------
// GCN3D: 3x GCNConv + fc (global), instance-norm, cluster pool, 2x GCNConv
// (pooled 1024-cluster graph), gather-broadcast, 3x GCNConv + fc (out).
// N=100000 nodes, E=1600000 edges, C=1024 clusters. All f32.
// R3: atomic cluster pooling -> cluster-CSR gather reduction (k_poolavg).
// R5 FAILED: __launch_bounds__(256,4) capped VGPR at 64 -> spill.
// R7: k_gemm2 "no-LDS GEMM": W from L2 (coalesced per 32-lane group), A via
//   broadcast float2/4 loads, no LDS, NO BARRIERS. Each wave reads only the
//   rows it writes -> in-place safe without __syncthreads.
// ---------------------------------------------------------------------------

#define NCLUST 1024

__device__ __forceinline__ float elu1(float x) { return x > 0.f ? x : expm1f(x); }

__global__ void k_zero(int4* __restrict__ p, int n4) {
    int i = blockIdx.x * 256 + threadIdx.x;
    if (i < n4) p[i] = make_int4(0, 0, 0, 0);
}

// ---------------- CSR build (shared by edge graph and cluster lists) --------
__global__ void k_hist(const int* __restrict__ key, int* __restrict__ deg, int E) {
    int e = blockIdx.x * 256 + threadIdx.x;
    if (e < E) atomicAdd(&deg[key[e]], 1);
}

__global__ void k_scan_block(const int* __restrict__ deg, int* __restrict__ rowptr,
                             int* __restrict__ bsum, int n) {
    __shared__ int lds[256];
    int tid = threadIdx.x;
    int base = blockIdx.x * 1024 + tid * 4;
    int v0 = base + 0 < n ? deg[base + 0] : 0;
    int v1 = base + 1 < n ? deg[base + 1] : 0;
    int v2 = base + 2 < n ? deg[base + 2] : 0;
    int v3 = base + 3 < n ? deg[base + 3] : 0;
    int tsum = v0 + v1 + v2 + v3;
    lds[tid] = tsum; __syncthreads();
    for (int off = 1; off < 256; off <<= 1) {
        int t = (tid >= off) ? lds[tid - off] : 0;
        __syncthreads();
        lds[tid] += t;
        __syncthreads();
    }
    int run = lds[tid] - tsum;
    if (base + 0 < n) rowptr[base + 0] = run; run += v0;
    if (base + 1 < n) rowptr[base + 1] = run; run += v1;
    if (base + 2 < n) rowptr[base + 2] = run; run += v2;
    if (base + 3 < n) rowptr[base + 3] = run;
    if (tid == 255) bsum[blockIdx.x] = lds[255];
}

__global__ void k_scan_tops(int* __restrict__ bsum, int nb) {
    __shared__ int lds[128];
    int tid = threadIdx.x;
    int v = tid < nb ? bsum[tid] : 0;
    lds[tid] = v; __syncthreads();
    for (int off = 1; off < 128; off <<= 1) {
        int t = (tid >= off) ? lds[tid - off] : 0;
        __syncthreads();
        lds[tid] += t;
        __syncthreads();
    }
    if (tid < nb) bsum[tid] = lds[tid] - v;
}

__global__ void k_scan_add(int* __restrict__ rowptr, const int* __restrict__ bsum, int n) {
    int i = blockIdx.x * 256 + threadIdx.x;
    if (i < n) rowptr[i] += bsum[i >> 10];
}

__global__ void k_dinv_bc(const int* __restrict__ deg, const int* __restrict__ cluster,
                          const int* __restrict__ inb, float* __restrict__ dinv,
                          int* __restrict__ bc, int n) {
    int i = blockIdx.x * 256 + threadIdx.x;
    if (i < n) {
        dinv[i] = rsqrtf((float)deg[i] + 1.0f);
        bc[i] = cluster[i] + inb[i] * NCLUST;
    }
}

__global__ void k_fill(const int* __restrict__ src, const int* __restrict__ dst,
                       const float* __restrict__ dinv, const int* __restrict__ rowptr,
                       int* __restrict__ fill, int* __restrict__ csr_src,
                       float* __restrict__ csr_w, int E) {
    int e = blockIdx.x * 256 + threadIdx.x;
    if (e >= E) return;
    int d = dst[e];
    int pos = rowptr[d] + atomicAdd(&fill[d], 1);
    int s = src[e];
    csr_src[pos] = s;
    csr_w[pos] = dinv[s];
}

// cluster member lists
__global__ void k_cfill(const int* __restrict__ bc, const int* __restrict__ crowptr,
                        int* __restrict__ cfill, int* __restrict__ cnodes, int n) {
    int i = blockIdx.x * 256 + threadIdx.x;
    if (i >= n) return;
    int c = bc[i];
    int pos = crowptr[c] + atomicAdd(&cfill[c], 1);
    cnodes[pos] = i;
}

// ---------------- GCN propagation: out = S*h (+bias, elu) ----------------
__global__ __launch_bounds__(256) void k_prop4(
        const float* __restrict__ h, const float* __restrict__ dinv,
        const int* __restrict__ rowptr, const int* __restrict__ deg,
        const int* __restrict__ csr_src, const float* __restrict__ csr_w,
        const float* __restrict__ bias, float* __restrict__ out,
        int n, int F, int lshift, int flags) {
    int gid = blockIdx.x * 256 + threadIdx.x;
    int node = gid >> lshift;
    if (node >= n) return;
    int fi = (gid & ((1 << lshift) - 1)) * 4;
    int start = rowptr[node];
    int cnt = deg[node];
    float ax = 0.f, ay = 0.f, az = 0.f, aw = 0.f;
    for (int j = 0; j < cnt; j++) {
        int s = csr_src[start + j];
        float w = csr_w[start + j];
        const float4 v = *reinterpret_cast<const float4*>(&h[(size_t)s * F + fi]);
        ax += w * v.x; ay += w * v.y; az += w * v.z; aw += w * v.w;
    }
    float di = dinv[node];
    const float4 sv = *reinterpret_cast<const float4*>(&h[(size_t)node * F + fi]);
    float4 o;
    o.x = di * ax + di * di * sv.x;
    o.y = di * ay + di * di * sv.y;
    o.z = di * az + di * di * sv.z;
    o.w = di * aw + di * di * sv.w;
    if (flags) {
        const float4 b = *reinterpret_cast<const float4*>(&bias[fi]);
        o.x = elu1(o.x + b.x); o.y = elu1(o.y + b.y);
        o.z = elu1(o.z + b.z); o.w = elu1(o.w + b.w);
    }
    *reinterpret_cast<float4*>(&out[(size_t)node * F + fi]) = o;
}

__global__ void k_prop3(const float* __restrict__ h, const float* __restrict__ dinv,
                        const int* __restrict__ rowptr, const int* __restrict__ deg,
                        const int* __restrict__ csr_src, const float* __restrict__ csr_w,
                        const float* __restrict__ bias, float* __restrict__ out,
                        int n, int flags) {
    int node = blockIdx.x * 256 + threadIdx.x;
    if (node >= n) return;
    int start = rowptr[node], cnt = deg[node];
    float a0 = 0.f, a1 = 0.f, a2 = 0.f;
    for (int j = 0; j < cnt; j++) {
        int s = csr_src[start + j];
        float w = csr_w[start + j];
        a0 += w * h[(size_t)s * 3 + 0];
        a1 += w * h[(size_t)s * 3 + 1];
        a2 += w * h[(size_t)s * 3 + 2];
    }
    float di = dinv[node];
    float o0 = di * a0 + di * di * h[(size_t)node * 3 + 0];
    float o1 = di * a1 + di * di * h[(size_t)node * 3 + 1];
    float o2 = di * a2 + di * di * h[(size_t)node * 3 + 2];
    if (flags) {
        o0 = elu1(o0 + bias[0]); o1 = elu1(o1 + bias[1]); o2 = elu1(o2 + bias[2]);
    }
    out[(size_t)node * 3 + 0] = o0;
    out[(size_t)node * 3 + 1] = o1;
    out[(size_t)node * 3 + 2] = o2;
}

// ---------------- no-LDS GEMM: C = A[N,K] @ W[K,BN] (+add[idx],+bias,elu) ---
// 256 threads = 8 row-groups (g) x 32 lanes; group owns TM=8 rows, lane owns
// TN=BN/32 cols (chunks of CW at col and col+BN/2). W loads are coalesced and
// L2-resident; A loads are group-broadcast (1-2 addresses per wave per instr).
// No LDS, no barriers. In-place safe: a wave reads only the rows it writes.
// K % KU == 0. KU=2 for BN=256 (VGPR pressure), else 4.
template <int BN, int KU>
__global__ __launch_bounds__(256) void k_gemm2(
        const float* __restrict__ A, const float* __restrict__ W,
        const float* __restrict__ bias, const float* __restrict__ add,
        const int* __restrict__ addidx, float* __restrict__ C,
        int N, int K, int flags) {
    constexpr int TM = 8;
    constexpr int TN = BN / 32;                 // 8,4,2,1
    constexpr int NCH = (TN > 4) ? 2 : 1;       // col chunks
    constexpr int CW = (TN > 4) ? 4 : TN;       // chunk width
    const int t = threadIdx.x;
    const int l = t & 63;
    const int g = ((t >> 6) << 1) | (l >> 5);   // 0..7
    const int col = (l & 31) * CW;
    const int row0 = blockIdx.x * 64 + g * TM;

    const float* ap[TM];
#pragma unroll
    for (int i = 0; i < TM; i++) {
        int r = row0 + i; r = r < N ? r : N - 1;   // clamp stays in-block
        ap[i] = A + (size_t)r * K;
    }
    const float* wp = W + col;

    float acc[TM][TN];
#pragma unroll
    for (int i = 0; i < TM; i++)
#pragma unroll
        for (int j = 0; j < TN; j++) acc[i][j] = 0.f;

    for (int k0 = 0; k0 < K; k0 += KU) {
        float a[TM][KU];
#pragma unroll
        for (int i = 0; i < TM; i++) {
            if constexpr (KU == 4) {
                const float4 v = *reinterpret_cast<const float4*>(ap[i] + k0);
                a[i][0] = v.x; a[i][1] = v.y; a[i][2] = v.z; a[i][3] = v.w;
            } else {
                const float2 v = *reinterpret_cast<const float2*>(ap[i] + k0);
                a[i][0] = v.x; a[i][1] = v.y;
            }
        }
#pragma unroll
        for (int kk = 0; kk < KU; kk++) {
            float wv[TN];
#pragma unroll
            for (int c = 0; c < NCH; c++) {
                if constexpr (CW == 4) {
                    const float4 v = *reinterpret_cast<const float4*>(wp + (size_t)kk * BN + c * (BN / 2));
                    wv[c * 4 + 0] = v.x; wv[c * 4 + 1] = v.y;
                    wv[c * 4 + 2] = v.z; wv[c * 4 + 3] = v.w;
                } else if constexpr (CW == 2) {
                    const float2 v = *reinterpret_cast<const float2*>(wp + (size_t)kk * BN);
                    wv[0] = v.x; wv[1] = v.y;
                } else {
                    wv[0] = wp[(size_t)kk * BN];
                }
            }
#pragma unroll
            for (int i = 0; i < TM; i++)
#pragma unroll
                for (int j = 0; j < TN; j++) acc[i][j] += a[i][kk] * wv[j];
        }
        wp += (size_t)KU * BN;
    }
    // epilogue
#pragma unroll
    for (int i = 0; i < TM; i++) {
        int row = row0 + i;
        if (row >= N) break;
        int g2 = (add != nullptr) ? addidx[row] : 0;
#pragma unroll
        for (int c = 0; c < NCH; c++) {
            int cc = col + c * (BN / 2);
            float o[CW];
#pragma unroll
            for (int j = 0; j < CW; j++) o[j] = acc[i][c * CW + j];
            if (add != nullptr) {
#pragma unroll
                for (int j = 0; j < CW; j++) o[j] += add[(size_t)g2 * BN + cc + j];
            }
            if (flags) {
#pragma unroll
                for (int j = 0; j < CW; j++) o[j] = elu1(o[j] + bias[cc + j]);
            }
            if constexpr (CW == 4) {
                *reinterpret_cast<float4*>(&C[(size_t)row * BN + cc]) =
                    make_float4(o[0], o[1], o[2], o[3]);
            } else if constexpr (CW == 2) {
                *reinterpret_cast<float2*>(&C[(size_t)row * BN + cc]) = make_float2(o[0], o[1]);
            } else {
                C[(size_t)row * BN + cc] = o[0];
            }
        }
    }
}

// ---------------- simple fc (small shapes: K=3 layer, local C=1024 stack) ----
template <int M, int RPT>
__global__ __launch_bounds__(256) void k_fc(
        const float* __restrict__ A, const float* __restrict__ W,
        const float* __restrict__ bias, const float* __restrict__ add,
        const int* __restrict__ addidx, float* __restrict__ C,
        int N, int K, int flags) {
    constexpr int TX = M / 4;
    constexpr int TY = 256 / TX;
    constexpr int RB = TY * RPT;
    int tx = threadIdx.x % TX;
    int ty = threadIdx.x / TX;
    int row0 = blockIdx.x * RB + ty * RPT;
    float4 acc[RPT];
#pragma unroll
    for (int r = 0; r < RPT; r++) acc[r] = make_float4(0.f, 0.f, 0.f, 0.f);
    for (int k = 0; k < K; k++) {
        float4 w = *reinterpret_cast<const float4*>(&W[(size_t)k * M + tx * 4]);
#pragma unroll
        for (int r = 0; r < RPT; r++) {
            int row = row0 + r;
            row = row < N ? row : N - 1;
            float a = A[(size_t)row * K + k];
            acc[r].x += a * w.x; acc[r].y += a * w.y;
            acc[r].z += a * w.z; acc[r].w += a * w.w;
        }
    }
    if (add != nullptr) {
#pragma unroll
        for (int r = 0; r < RPT; r++) {
            int row = row0 + r;
            if (row < N) {
                int g = addidx[row];
                const float4 v = *reinterpret_cast<const float4*>(&add[(size_t)g * M + tx * 4]);
                acc[r].x += v.x; acc[r].y += v.y; acc[r].z += v.z; acc[r].w += v.w;
            }
        }
    }
    __syncthreads();
    float4 b = make_float4(0.f, 0.f, 0.f, 0.f);
    if (flags) b = *reinterpret_cast<const float4*>(&bias[tx * 4]);
#pragma unroll
    for (int r = 0; r < RPT; r++) {
        int row = row0 + r;
        if (row >= N) break;
        float4 o = acc[r];
        o.x += b.x; o.y += b.y; o.z += b.z; o.w += b.w;
        if (flags) { o.x = elu1(o.x); o.y = elu1(o.y); o.z = elu1(o.z); o.w = elu1(o.w); }
        *reinterpret_cast<float4*>(&C[(size_t)row * M + tx * 4]) = o;
    }
}

// M = 3 (W: K x 3)
__global__ void k_fc3(const float* __restrict__ A, const float* __restrict__ W,
                      const float* __restrict__ b, float* __restrict__ C,
                      int n, int K, int flags) {
    int r = blockIdx.x * 256 + threadIdx.x;
    if (r >= n) return;
    float a0 = 0.f, a1 = 0.f, a2 = 0.f;
    for (int k = 0; k < K; k++) {
        float a = A[(size_t)r * K + k];
        a0 += a * W[k * 3 + 0]; a1 += a * W[k * 3 + 1]; a2 += a * W[k * 3 + 2];
    }
    if (flags) {
        a0 = elu1(a0 + b[0]); a1 = elu1(a1 + b[1]); a2 = elu1(a2 + b[2]);
    }
    C[(size_t)r * 3 + 0] = a0;
    C[(size_t)r * 3 + 1] = a1;
    C[(size_t)r * 3 + 2] = a2;
}

// ---------------- instance norm (in-place apply) ----------------
__global__ void k_instats(const float* __restrict__ h, float* __restrict__ sum,
                          float* __restrict__ sumsq, int n) {
    int c = threadIdx.x;
    int r0 = blockIdx.x * 128;
    int r1 = r0 + 128 < n ? r0 + 128 : n;
    float s = 0.f, q = 0.f;
    for (int r = r0; r < r1; r++) {
        float v = h[(size_t)r * 256 + c];
        s += v; q += v * v;
    }
    atomicAdd(&sum[c], s);
    atomicAdd(&sumsq[c], q);
}

__global__ void k_infinal(const float* __restrict__ sum, const float* __restrict__ sumsq,
                          float* __restrict__ mu, float* __restrict__ rstd, int n) {
    int c = threadIdx.x;
    float m = sum[c] / (float)n;
    float var = sumsq[c] / (float)n - m * m;
    mu[c] = m;
    rstd[c] = rsqrtf(var + 1e-5f);
}

__global__ void k_innorm(float* __restrict__ h, const float* __restrict__ mu,
                         const float* __restrict__ rstd, int n) {
    int gid = blockIdx.x * 256 + threadIdx.x;
    int node = gid >> 6;
    if (node >= n) return;
    int c = (gid & 63) * 4;
    float4 v = *reinterpret_cast<const float4*>(&h[(size_t)node * 256 + c]);
    float4 m = *reinterpret_cast<const float4*>(&mu[c]);
    float4 rs = *reinterpret_cast<const float4*>(&rstd[c]);
    v.x = (v.x - m.x) * rs.x; v.y = (v.y - m.y) * rs.y;
    v.z = (v.z - m.z) * rs.z; v.w = (v.w - m.w) * rs.w;
    *reinterpret_cast<float4*>(&h[(size_t)node * 256 + c]) = v;
}

// ---------------- cluster pooling (CSR gather, no atomics) ----------------
__global__ __launch_bounds__(256) void k_poolavg(
        const float* __restrict__ y, const int* __restrict__ crowptr,
        const int* __restrict__ cdeg, const int* __restrict__ cnodes,
        float* __restrict__ px) {
    int cl = blockIdx.x;
    int c  = threadIdx.x;
    int start = crowptr[cl];
    int cnt = cdeg[cl];
    float acc = 0.f;
    for (int j = 0; j < cnt; j++) {
        int node = cnodes[start + j];
        acc += y[(size_t)node * 256 + c];
    }
    px[(size_t)cl * 256 + c] = acc / fmaxf((float)cnt, 1.0f);
}

__global__ void k_pooledges(const int* __restrict__ src, const int* __restrict__ dst,
                            const int* __restrict__ bc, unsigned char* __restrict__ bmT, int E) {
    int e = blockIdx.x * 256 + threadIdx.x;
    if (e >= E) return;
    int ps = bc[src[e]];
    int pd = bc[dst[e]];
    bmT[(size_t)pd * NCLUST + ps] = 1;
}

// block per dst cluster; 256 threads sum the 1024-byte bitmap row
__global__ __launch_bounds__(256) void k_pooldeg(
        const unsigned char* __restrict__ bmT, float* __restrict__ dinvp) {
    int d = blockIdx.x;
    int t = threadIdx.x;
    const unsigned int v = reinterpret_cast<const unsigned int*>(bmT + (size_t)d * NCLUST)[t];
    int s = (v & 0xff) + ((v >> 8) & 0xff) + ((v >> 16) & 0xff) + ((v >> 24) & 0xff);
    if (t == (d >> 2)) s -= (v >> ((d & 3) * 8)) & 0xff;   // exclude self-loop
    __shared__ int red[256];
    red[t] = s; __syncthreads();
    for (int o = 128; o > 0; o >>= 1) {
        if (t < o) red[t] += red[t + o];
        __syncthreads();
    }
    if (t == 0) dinvp[d] = rsqrtf((float)red[0] + 1.0f);
}

__global__ void k_proppool(const float* __restrict__ h, const float* __restrict__ dinvp,
                           const unsigned char* __restrict__ bmT, const float* __restrict__ bias,
                           float* __restrict__ out, int F) {
    int d = blockIdx.x;
    int f = threadIdx.x;
    float acc = 0.f;
    for (int s = 0; s < NCLUST; s++) {
        if (s == d) continue;
        if (bmT[(size_t)d * NCLUST + s]) acc += dinvp[s] * h[(size_t)s * F + f];
    }
    float di = dinvp[d];
    float r = di * acc + di * di * h[(size_t)d * F + f] + bias[f];
    out[(size_t)d * F + f] = elu1(r);
}

// ---------------------------------------------------------------------------
extern "C" void kernel_launch(void* const* d_in, const int* in_sizes, int n_in,
                              void* d_out, int out_size, void* d_ws, size_t ws_size,
                              hipStream_t stream) {
    const float* x       = (const float*)d_in[0];
    const int*   adj     = (const int*)d_in[1];
    const int*   inb     = (const int*)d_in[3];
    const int*   cluster = (const int*)d_in[4];
    const float* WG1  = (const float*)d_in[5];   const float* bG1  = (const float*)d_in[6];
    const float* WfG1 = (const float*)d_in[7];   const float* bfG1 = (const float*)d_in[8];
    const float* WG2  = (const float*)d_in[9];   const float* bG2  = (const float*)d_in[10];
    const float* WfG2 = (const float*)d_in[11];  const float* bfG2 = (const float*)d_in[12];
    const float* WL1  = (const float*)d_in[13];  const float* bL1  = (const float*)d_in[14];
    const float* WfL1 = (const float*)d_in[15];  const float* bfL1 = (const float*)d_in[16];
    const float* WL2  = (const float*)d_in[17];  const float* bL2  = (const float*)d_in[18];
    const float* WfL2 = (const float*)d_in[19];  const float* bfL2 = (const float*)d_in[20];
    const float* WO1  = (const float*)d_in[21];  const float* bO1  = (const float*)d_in[22];
    const float* WfO1 = (const float*)d_in[23];  const float* bfO1 = (const float*)d_in[24];
    const float* WO2  = (const float*)d_in[25];  const float* bO2  = (const float*)d_in[26];
    const float* WfO2 = (const float*)d_in[27];  const float* bfO2 = (const float*)d_in[28];
    const float* WO3  = (const float*)d_in[29];  const float* bO3  = (const float*)d_in[30];
    const float* WfO3 = (const float*)d_in[31];  const float* bfO3 = (const float*)d_in[32];
    float* out = (float*)d_out;

    const int n = in_sizes[0] / 3;       // 100000
    const int E = in_sizes[1] / 2;       // 1600000
    const int* src = adj;
    const int* dst = adj + E;

    // ---- workspace carve (~173 MB) ----
    char* ws = (char*)d_ws;
    size_t off = 0;
    auto alloc = [&](size_t bytes) -> void* {
        void* p = ws + off;
        off = (off + bytes + 255) & ~(size_t)255;
        return p;
    };
    int*   deg     = (int*)alloc((size_t)n * 4);     // zero span 1 start
    int*   fill    = (int*)alloc((size_t)n * 4);
    int*   cdeg    = (int*)alloc(NCLUST * 4);
    int*   cfill   = (int*)alloc(NCLUST * 4);
    int*   rowptr  = (int*)alloc((size_t)n * 4);     // zero span 1 end (exclusive)
    int*   crowptr = (int*)alloc(NCLUST * 4);
    int*   cnodes  = (int*)alloc((size_t)n * 4);
    int*   bcarr   = (int*)alloc((size_t)n * 4);
    float* dinv    = (float*)alloc((size_t)n * 4);
    int*   bsum    = (int*)alloc(512);
    int*   csr_src = (int*)alloc((size_t)E * 4);
    float* csr_w   = (float*)alloc((size_t)E * 4);
    float* X       = (float*)alloc((size_t)n * 256 * 4);
    float* B       = (float*)alloc((size_t)n * 128 * 4);
    float* insum   = (float*)alloc(256 * 4);         // zero span 2 start
    float* insumsq = (float*)alloc(256 * 4);
    float* px      = (float*)alloc((size_t)NCLUST * 256 * 4);
    unsigned char* bmT = (unsigned char*)alloc((size_t)NCLUST * NCLUST);
    float* mu      = (float*)alloc(256 * 4);         // zero span 2 end (exclusive)
    float* rstd    = (float*)alloc(256 * 4);
    float* dinvp   = (float*)alloc(NCLUST * 4);
    float* lA      = (float*)alloc((size_t)NCLUST * 128 * 4);
    float* lB      = (float*)alloc((size_t)NCLUST * 128 * 4);
    (void)ws_size; (void)n_in; (void)out_size;

    float* B0 = B;
    float* B1 = B + (size_t)n * 64;

    auto cdiv = [](int a, int b) { return (a + b - 1) / b; };
    const int EB = cdiv(E, 256);
    const int GB = cdiv(n, 64);          // gemm2 grid

    // ---- zero scratch ----
    int nz1 = (int)(((char*)rowptr - (char*)deg) / 16);
    int nz2 = (int)(((char*)mu - (char*)insum) / 16);
    k_zero<<<cdiv(nz1, 256), 256, 0, stream>>>((int4*)deg, nz1);
    k_zero<<<cdiv(nz2, 256), 256, 0, stream>>>((int4*)insum, nz2);

    // ---- CSR build (edges) ----
    k_hist<<<EB, 256, 0, stream>>>(dst, deg, E);
    int nb = cdiv(n, 1024);
    k_scan_block<<<nb, 256, 0, stream>>>(deg, rowptr, bsum, n);
    k_scan_tops<<<1, 128, 0, stream>>>(bsum, nb);
    k_scan_add<<<cdiv(n, 256), 256, 0, stream>>>(rowptr, bsum, n);
    k_dinv_bc<<<cdiv(n, 256), 256, 0, stream>>>(deg, cluster, inb, dinv, bcarr, n);
    k_fill<<<EB, 256, 0, stream>>>(src, dst, dinv, rowptr, fill, csr_src, csr_w, E);

    // ---- CSR build (cluster member lists) ----
    k_hist<<<cdiv(n, 256), 256, 0, stream>>>(bcarr, cdeg, n);
    k_scan_block<<<1, 256, 0, stream>>>(cdeg, crowptr, bsum, NCLUST);
    k_cfill<<<cdiv(n, 256), 256, 0, stream>>>(bcarr, crowptr, cfill, cnodes, n);

    // ---- global GCN stack ----
    k_prop3<<<cdiv(n, 256), 256, 0, stream>>>(x, dinv, rowptr, deg, csr_src, csr_w,
                                              nullptr, B0, n, 0);
    k_fc<64, 2><<<cdiv(n, 32), 256, 0, stream>>>(B0, WG1, bG1, nullptr, nullptr, B1, n, 3, 1);
    // h2 = elu(h1 @ WfG1 + bfG1)  (B1 in-place, 64 square)
    k_gemm2<64, 4><<<GB, 256, 0, stream>>>(B1, WfG1, bfG1, nullptr, nullptr, B1, n, 64, 1);
    k_prop4<<<cdiv(n * 16, 256), 256, 0, stream>>>(B1, dinv, rowptr, deg, csr_src, csr_w,
                                                   nullptr, B0, n, 64, 4, 0);
    // h3 = elu(p64 @ WG2 + bG2)  (X)
    k_gemm2<256, 2><<<GB, 256, 0, stream>>>(B0, WG2, bG2, nullptr, nullptr, X, n, 64, 1);
    // h4 = elu(h3 @ WfG2 + bfG2)  (X in-place)
    k_gemm2<256, 2><<<GB, 256, 0, stream>>>(X, WfG2, bfG2, nullptr, nullptr, X, n, 256, 1);

    // ---- instance norm (in place) -> y = X ----
    k_instats<<<cdiv(n, 128), 256, 0, stream>>>(X, insum, insumsq, n);
    k_infinal<<<1, 256, 0, stream>>>(insum, insumsq, mu, rstd, n);
    k_innorm<<<cdiv(n * 64, 256), 256, 0, stream>>>(X, mu, rstd, n);

    // ---- cluster pooling (gather) ----
    k_poolavg<<<NCLUST, 256, 0, stream>>>(X, crowptr, cdeg, cnodes, px);
    k_pooledges<<<EB, 256, 0, stream>>>(src, dst, bcarr, bmT, E);
    k_pooldeg<<<NCLUST, 256, 0, stream>>>(bmT, dinvp);

    // ---- local (pooled) GCN stack ----
    k_fc<128, 2><<<cdiv(NCLUST, 16), 256, 0, stream>>>(px, WL1, nullptr, nullptr, nullptr,
                                                       lA, NCLUST, 256, 0);
    k_proppool<<<NCLUST, 128, 0, stream>>>(lA, dinvp, bmT, bL1, lB, 128);
    k_fc<128, 2><<<cdiv(NCLUST, 16), 256, 0, stream>>>(lB, WfL1, bfL1, nullptr, nullptr,
                                                       lA, NCLUST, 128, 1);
    k_fc<64, 2><<<cdiv(NCLUST, 32), 256, 0, stream>>>(lA, WL2, nullptr, nullptr, nullptr,
                                                      lB, NCLUST, 128, 0);
    k_proppool<<<NCLUST, 64, 0, stream>>>(lB, dinvp, bmT, bL2, lA, 64);
    k_fc<64, 2><<<cdiv(NCLUST, 32), 256, 0, stream>>>(lA, WfL2, bfL2, nullptr, nullptr,
                                                      lB, NCLUST, 64, 1);
    k_fc<128, 2><<<cdiv(NCLUST, 16), 256, 0, stream>>>(lB, WO1 + (size_t)256 * 128, nullptr,
                                                       nullptr, nullptr, lA, NCLUST, 64, 0);

    // ---- output GCN stack ----
    // t1 = y @ WO1[0:256,:] + compO[bc]  (B, N x 128)
    k_gemm2<128, 4><<<GB, 256, 0, stream>>>(X, WO1, nullptr, lA, bcarr, B, n, 256, 0);
    k_prop4<<<cdiv(n * 32, 256), 256, 0, stream>>>(B, dinv, rowptr, deg, csr_src, csr_w,
                                                   bO1, X, n, 128, 5, 1);
    // o2 = elu(o1 @ WfO1 + bfO1)  (X in-place)
    k_gemm2<128, 4><<<GB, 256, 0, stream>>>(X, WfO1, bfO1, nullptr, nullptr, X, n, 128, 1);
    // t2 = o2 @ WO2  (B, N x 32)
    k_gemm2<32, 4><<<GB, 256, 0, stream>>>(X, WO2, nullptr, nullptr, nullptr, B, n, 128, 0);
    k_prop4<<<cdiv(n * 8, 256), 256, 0, stream>>>(B, dinv, rowptr, deg, csr_src, csr_w,
                                                  bO2, X, n, 32, 3, 1);
    // o4 = elu(o3 @ WfO2 + bfO2)  (X in-place)
    k_gemm2<32, 4><<<GB, 256, 0, stream>>>(X, WfO2, bfO2, nullptr, nullptr, X, n, 32, 1);
    k_fc3<<<cdiv(n, 256), 256, 0, stream>>>(X, WO3, nullptr, B, n, 32, 0);
    k_prop3<<<cdiv(n, 256), 256, 0, stream>>>(B, dinv, rowptr, deg, csr_src, csr_w,
                                              bO3, X, n, 1);
    k_fc3<<<cdiv(n, 256), 256, 0, stream>>>(X, WfO3, bfO3, out, n, 3, 1);
}

// Round 8
// 1983.914 us; speedup vs baseline: 1.0310x; 1.0310x over previous
//
#include <hip/hip_runtime.h>

// ---------------------------------------------------------------------------
// GCN3D: 3x GCNConv + fc (global), instance-norm, cluster pool, 2x GCNConv
// (pooled 1024-cluster graph), gather-broadcast, 3x GCNConv + fc (out).
// N=100000 nodes, E=1600000 edges, C=1024 clusters. All f32.
// R3: atomic pooling -> cluster-CSR gather. R5 FAILED: launch_bounds(256,4)
// spills. R7 FAILED: W direct from L2 stalls (L1 too small for 256KB W).
// R8: k_gemm3 hybrid: A via group-broadcast global loads (row owned by one
//   32-lane group -> L1 broadcast, no LDS, no transpose scatter); W double-
//   buffered in LDS (one barrier per K-tile, latency hidden under FMAs).
// ---------------------------------------------------------------------------

#define NCLUST 1024

__device__ __forceinline__ float elu1(float x) { return x > 0.f ? x : expm1f(x); }

__global__ void k_zero(int4* __restrict__ p, int n4) {
    int i = blockIdx.x * 256 + threadIdx.x;
    if (i < n4) p[i] = make_int4(0, 0, 0, 0);
}

// ---------------- CSR build (shared by edge graph and cluster lists) --------
__global__ void k_hist(const int* __restrict__ key, int* __restrict__ deg, int E) {
    int e = blockIdx.x * 256 + threadIdx.x;
    if (e < E) atomicAdd(&deg[key[e]], 1);
}

__global__ void k_scan_block(const int* __restrict__ deg, int* __restrict__ rowptr,
                             int* __restrict__ bsum, int n) {
    __shared__ int lds[256];
    int tid = threadIdx.x;
    int base = blockIdx.x * 1024 + tid * 4;
    int v0 = base + 0 < n ? deg[base + 0] : 0;
    int v1 = base + 1 < n ? deg[base + 1] : 0;
    int v2 = base + 2 < n ? deg[base + 2] : 0;
    int v3 = base + 3 < n ? deg[base + 3] : 0;
    int tsum = v0 + v1 + v2 + v3;
    lds[tid] = tsum; __syncthreads();
    for (int off = 1; off < 256; off <<= 1) {
        int t = (tid >= off) ? lds[tid - off] : 0;
        __syncthreads();
        lds[tid] += t;
        __syncthreads();
    }
    int run = lds[tid] - tsum;
    if (base + 0 < n) rowptr[base + 0] = run; run += v0;
    if (base + 1 < n) rowptr[base + 1] = run; run += v1;
    if (base + 2 < n) rowptr[base + 2] = run; run += v2;
    if (base + 3 < n) rowptr[base + 3] = run;
    if (tid == 255) bsum[blockIdx.x] = lds[255];
}

__global__ void k_scan_tops(int* __restrict__ bsum, int nb) {
    __shared__ int lds[128];
    int tid = threadIdx.x;
    int v = tid < nb ? bsum[tid] : 0;
    lds[tid] = v; __syncthreads();
    for (int off = 1; off < 128; off <<= 1) {
        int t = (tid >= off) ? lds[tid - off] : 0;
        __syncthreads();
        lds[tid] += t;
        __syncthreads();
    }
    if (tid < nb) bsum[tid] = lds[tid] - v;
}

__global__ void k_scan_add(int* __restrict__ rowptr, const int* __restrict__ bsum, int n) {
    int i = blockIdx.x * 256 + threadIdx.x;
    if (i < n) rowptr[i] += bsum[i >> 10];
}

__global__ void k_dinv_bc(const int* __restrict__ deg, const int* __restrict__ cluster,
                          const int* __restrict__ inb, float* __restrict__ dinv,
                          int* __restrict__ bc, int n) {
    int i = blockIdx.x * 256 + threadIdx.x;
    if (i < n) {
        dinv[i] = rsqrtf((float)deg[i] + 1.0f);
        bc[i] = cluster[i] + inb[i] * NCLUST;
    }
}

__global__ void k_fill(const int* __restrict__ src, const int* __restrict__ dst,
                       const float* __restrict__ dinv, const int* __restrict__ rowptr,
                       int* __restrict__ fill, int* __restrict__ csr_src,
                       float* __restrict__ csr_w, int E) {
    int e = blockIdx.x * 256 + threadIdx.x;
    if (e >= E) return;
    int d = dst[e];
    int pos = rowptr[d] + atomicAdd(&fill[d], 1);
    int s = src[e];
    csr_src[pos] = s;
    csr_w[pos] = dinv[s];
}

// cluster member lists
__global__ void k_cfill(const int* __restrict__ bc, const int* __restrict__ crowptr,
                        int* __restrict__ cfill, int* __restrict__ cnodes, int n) {
    int i = blockIdx.x * 256 + threadIdx.x;
    if (i >= n) return;
    int c = bc[i];
    int pos = crowptr[c] + atomicAdd(&cfill[c], 1);
    cnodes[pos] = i;
}

// ---------------- GCN propagation: out = S*h (+bias, elu) ----------------
__global__ __launch_bounds__(256) void k_prop4(
        const float* __restrict__ h, const float* __restrict__ dinv,
        const int* __restrict__ rowptr, const int* __restrict__ deg,
        const int* __restrict__ csr_src, const float* __restrict__ csr_w,
        const float* __restrict__ bias, float* __restrict__ out,
        int n, int F, int lshift, int flags) {
    int gid = blockIdx.x * 256 + threadIdx.x;
    int node = gid >> lshift;
    if (node >= n) return;
    int fi = (gid & ((1 << lshift) - 1)) * 4;
    int start = rowptr[node];
    int cnt = deg[node];
    float ax = 0.f, ay = 0.f, az = 0.f, aw = 0.f;
    for (int j = 0; j < cnt; j++) {
        int s = csr_src[start + j];
        float w = csr_w[start + j];
        const float4 v = *reinterpret_cast<const float4*>(&h[(size_t)s * F + fi]);
        ax += w * v.x; ay += w * v.y; az += w * v.z; aw += w * v.w;
    }
    float di = dinv[node];
    const float4 sv = *reinterpret_cast<const float4*>(&h[(size_t)node * F + fi]);
    float4 o;
    o.x = di * ax + di * di * sv.x;
    o.y = di * ay + di * di * sv.y;
    o.z = di * az + di * di * sv.z;
    o.w = di * aw + di * di * sv.w;
    if (flags) {
        const float4 b = *reinterpret_cast<const float4*>(&bias[fi]);
        o.x = elu1(o.x + b.x); o.y = elu1(o.y + b.y);
        o.z = elu1(o.z + b.z); o.w = elu1(o.w + b.w);
    }
    *reinterpret_cast<float4*>(&out[(size_t)node * F + fi]) = o;
}

__global__ void k_prop3(const float* __restrict__ h, const float* __restrict__ dinv,
                        const int* __restrict__ rowptr, const int* __restrict__ deg,
                        const int* __restrict__ csr_src, const float* __restrict__ csr_w,
                        const float* __restrict__ bias, float* __restrict__ out,
                        int n, int flags) {
    int node = blockIdx.x * 256 + threadIdx.x;
    if (node >= n) return;
    int start = rowptr[node], cnt = deg[node];
    float a0 = 0.f, a1 = 0.f, a2 = 0.f;
    for (int j = 0; j < cnt; j++) {
        int s = csr_src[start + j];
        float w = csr_w[start + j];
        a0 += w * h[(size_t)s * 3 + 0];
        a1 += w * h[(size_t)s * 3 + 1];
        a2 += w * h[(size_t)s * 3 + 2];
    }
    float di = dinv[node];
    float o0 = di * a0 + di * di * h[(size_t)node * 3 + 0];
    float o1 = di * a1 + di * di * h[(size_t)node * 3 + 1];
    float o2 = di * a2 + di * di * h[(size_t)node * 3 + 2];
    if (flags) {
        o0 = elu1(o0 + bias[0]); o1 = elu1(o1 + bias[1]); o2 = elu1(o2 + bias[2]);
    }
    out[(size_t)node * 3 + 0] = o0;
    out[(size_t)node * 3 + 1] = o1;
    out[(size_t)node * 3 + 2] = o2;
}

// ------- hybrid GEMM: C = A[N,K] @ W[K,BN] (+add[idx], +bias, elu) ---------
// 256 threads = 8 row-groups x 32 lanes; group owns TM=8 rows, lane owns
// TN=BN/32 cols (CW-wide chunks at col and col+BN/2).
// A: group-broadcast global loads (each row read only by its owning group).
// W: double-buffered LDS tiles (BK=16), ONE barrier per tile.
// In-place safe: a wave reads (A) and writes (C) only its own rows; tail
// clamped rows are computed but never stored. K % 16 == 0, KU | 16.
template <int BN, int KU>
__global__ __launch_bounds__(256) void k_gemm3(
        const float* __restrict__ A, const float* __restrict__ W,
        const float* __restrict__ bias, const float* __restrict__ add,
        const int* __restrict__ addidx, float* __restrict__ C,
        int N, int K, int flags) {
    constexpr int TM = 8;
    constexpr int TN = BN / 32;                 // 8,4,2,1
    constexpr int NCH = (TN > 4) ? 2 : 1;
    constexpr int CW = (TN > 4) ? 4 : TN;
    constexpr int BK = 16;
    constexpr int NW4 = (BK * BN) / 4;          // float4s per tile
    __shared__ float Ws[2][BK * BN];
    const int t = threadIdx.x;
    const int l = t & 63;
    const int g = ((t >> 6) << 1) | (l >> 5);   // 0..7
    const int col = (l & 31) * CW;
    const int row0 = blockIdx.x * 64 + g * TM;

    const float* ap[TM];
#pragma unroll
    for (int i = 0; i < TM; i++) {
        int r = row0 + i; r = r < N ? r : N - 1;
        ap[i] = A + (size_t)r * K;
    }

    float acc[TM][TN];
#pragma unroll
    for (int i = 0; i < TM; i++)
#pragma unroll
        for (int j = 0; j < TN; j++) acc[i][j] = 0.f;

    const int nt = K / BK;
    // stage tile 0
#pragma unroll
    for (int f4 = t; f4 < NW4; f4 += 256) {
        *reinterpret_cast<float4*>(&Ws[0][f4 * 4]) =
            *reinterpret_cast<const float4*>(&W[(size_t)f4 * 4]);
    }
    __syncthreads();

    for (int s = 0; s < nt; ++s) {
        const int cur = s & 1;
        // prefetch next W tile into the other buffer (overlaps compute)
        if (s + 1 < nt) {
            const float* wsrc = W + (size_t)(s + 1) * BK * BN;
#pragma unroll
            for (int f4 = t; f4 < NW4; f4 += 256) {
                *reinterpret_cast<float4*>(&Ws[cur ^ 1][f4 * 4]) =
                    *reinterpret_cast<const float4*>(&wsrc[f4 * 4]);
            }
        }
        const int k0 = s * BK;
#pragma unroll
        for (int ku = 0; ku < BK; ku += KU) {
            float a[TM][KU];
#pragma unroll
            for (int i = 0; i < TM; i++) {
                if constexpr (KU == 4) {
                    const float4 v = *reinterpret_cast<const float4*>(ap[i] + k0 + ku);
                    a[i][0] = v.x; a[i][1] = v.y; a[i][2] = v.z; a[i][3] = v.w;
                } else {
                    const float2 v = *reinterpret_cast<const float2*>(ap[i] + k0 + ku);
                    a[i][0] = v.x; a[i][1] = v.y;
                }
            }
#pragma unroll
            for (int kk = 0; kk < KU; kk++) {
                float wv[TN];
#pragma unroll
                for (int c = 0; c < NCH; c++) {
                    if constexpr (CW == 4) {
                        const float4 v = *reinterpret_cast<const float4*>(
                            &Ws[cur][(ku + kk) * BN + col + c * (BN / 2)]);
                        wv[c * 4 + 0] = v.x; wv[c * 4 + 1] = v.y;
                        wv[c * 4 + 2] = v.z; wv[c * 4 + 3] = v.w;
                    } else if constexpr (CW == 2) {
                        const float2 v = *reinterpret_cast<const float2*>(
                            &Ws[cur][(ku + kk) * BN + col]);
                        wv[0] = v.x; wv[1] = v.y;
                    } else {
                        wv[0] = Ws[cur][(ku + kk) * BN + col];
                    }
                }
#pragma unroll
                for (int i = 0; i < TM; i++)
#pragma unroll
                    for (int j = 0; j < TN; j++) acc[i][j] += a[i][kk] * wv[j];
            }
        }
        __syncthreads();   // readers done with Ws[cur]; writes to Ws[cur^1] visible
    }
    // epilogue (wave-exclusive rows; no barrier needed)
#pragma unroll
    for (int i = 0; i < TM; i++) {
        int row = row0 + i;
        if (row >= N) break;
        int g2 = (add != nullptr) ? addidx[row] : 0;
#pragma unroll
        for (int c = 0; c < NCH; c++) {
            int cc = col + c * (BN / 2);
            float o[CW];
#pragma unroll
            for (int j = 0; j < CW; j++) o[j] = acc[i][c * CW + j];
            if (add != nullptr) {
#pragma unroll
                for (int j = 0; j < CW; j++) o[j] += add[(size_t)g2 * BN + cc + j];
            }
            if (flags) {
#pragma unroll
                for (int j = 0; j < CW; j++) o[j] = elu1(o[j] + bias[cc + j]);
            }
            if constexpr (CW == 4) {
                *reinterpret_cast<float4*>(&C[(size_t)row * BN + cc]) =
                    make_float4(o[0], o[1], o[2], o[3]);
            } else if constexpr (CW == 2) {
                *reinterpret_cast<float2*>(&C[(size_t)row * BN + cc]) = make_float2(o[0], o[1]);
            } else {
                C[(size_t)row * BN + cc] = o[0];
            }
        }
    }
}

// ---------------- simple fc (small shapes: K=3 layer, local C=1024 stack) ----
template <int M, int RPT>
__global__ __launch_bounds__(256) void k_fc(
        const float* __restrict__ A, const float* __restrict__ W,
        const float* __restrict__ bias, const float* __restrict__ add,
        const int* __restrict__ addidx, float* __restrict__ C,
        int N, int K, int flags) {
    constexpr int TX = M / 4;
    constexpr int TY = 256 / TX;
    constexpr int RB = TY * RPT;
    int tx = threadIdx.x % TX;
    int ty = threadIdx.x / TX;
    int row0 = blockIdx.x * RB + ty * RPT;
    float4 acc[RPT];
#pragma unroll
    for (int r = 0; r < RPT; r++) acc[r] = make_float4(0.f, 0.f, 0.f, 0.f);
    for (int k = 0; k < K; k++) {
        float4 w = *reinterpret_cast<const float4*>(&W[(size_t)k * M + tx * 4]);
#pragma unroll
        for (int r = 0; r < RPT; r++) {
            int row = row0 + r;
            row = row < N ? row : N - 1;
            float a = A[(size_t)row * K + k];
            acc[r].x += a * w.x; acc[r].y += a * w.y;
            acc[r].z += a * w.z; acc[r].w += a * w.w;
        }
    }
    if (add != nullptr) {
#pragma unroll
        for (int r = 0; r < RPT; r++) {
            int row = row0 + r;
            if (row < N) {
                int g = addidx[row];
                const float4 v = *reinterpret_cast<const float4*>(&add[(size_t)g * M + tx * 4]);
                acc[r].x += v.x; acc[r].y += v.y; acc[r].z += v.z; acc[r].w += v.w;
            }
        }
    }
    __syncthreads();
    float4 b = make_float4(0.f, 0.f, 0.f, 0.f);
    if (flags) b = *reinterpret_cast<const float4*>(&bias[tx * 4]);
#pragma unroll
    for (int r = 0; r < RPT; r++) {
        int row = row0 + r;
        if (row >= N) break;
        float4 o = acc[r];
        o.x += b.x; o.y += b.y; o.z += b.z; o.w += b.w;
        if (flags) { o.x = elu1(o.x); o.y = elu1(o.y); o.z = elu1(o.z); o.w = elu1(o.w); }
        *reinterpret_cast<float4*>(&C[(size_t)row * M + tx * 4]) = o;
    }
}

// M = 3 (W: K x 3)
__global__ void k_fc3(const float* __restrict__ A, const float* __restrict__ W,
                      const float* __restrict__ b, float* __restrict__ C,
                      int n, int K, int flags) {
    int r = blockIdx.x * 256 + threadIdx.x;
    if (r >= n) return;
    float a0 = 0.f, a1 = 0.f, a2 = 0.f;
    for (int k = 0; k < K; k++) {
        float a = A[(size_t)r * K + k];
        a0 += a * W[k * 3 + 0]; a1 += a * W[k * 3 + 1]; a2 += a * W[k * 3 + 2];
    }
    if (flags) {
        a0 = elu1(a0 + b[0]); a1 = elu1(a1 + b[1]); a2 = elu1(a2 + b[2]);
    }
    C[(size_t)r * 3 + 0] = a0;
    C[(size_t)r * 3 + 1] = a1;
    C[(size_t)r * 3 + 2] = a2;
}

// ---------------- instance norm (in-place apply) ----------------
__global__ void k_instats(const float* __restrict__ h, float* __restrict__ sum,
                          float* __restrict__ sumsq, int n) {
    int c = threadIdx.x;
    int r0 = blockIdx.x * 128;
    int r1 = r0 + 128 < n ? r0 + 128 : n;
    float s = 0.f, q = 0.f;
    for (int r = r0; r < r1; r++) {
        float v = h[(size_t)r * 256 + c];
        s += v; q += v * v;
    }
    atomicAdd(&sum[c], s);
    atomicAdd(&sumsq[c], q);
}

__global__ void k_infinal(const float* __restrict__ sum, const float* __restrict__ sumsq,
                          float* __restrict__ mu, float* __restrict__ rstd, int n) {
    int c = threadIdx.x;
    float m = sum[c] / (float)n;
    float var = sumsq[c] / (float)n - m * m;
    mu[c] = m;
    rstd[c] = rsqrtf(var + 1e-5f);
}

__global__ void k_innorm(float* __restrict__ h, const float* __restrict__ mu,
                         const float* __restrict__ rstd, int n) {
    int gid = blockIdx.x * 256 + threadIdx.x;
    int node = gid >> 6;
    if (node >= n) return;
    int c = (gid & 63) * 4;
    float4 v = *reinterpret_cast<const float4*>(&h[(size_t)node * 256 + c]);
    float4 m = *reinterpret_cast<const float4*>(&mu[c]);
    float4 rs = *reinterpret_cast<const float4*>(&rstd[c]);
    v.x = (v.x - m.x) * rs.x; v.y = (v.y - m.y) * rs.y;
    v.z = (v.z - m.z) * rs.z; v.w = (v.w - m.w) * rs.w;
    *reinterpret_cast<float4*>(&h[(size_t)node * 256 + c]) = v;
}

// ---------------- cluster pooling (CSR gather, no atomics) ----------------
__global__ __launch_bounds__(256) void k_poolavg(
        const float* __restrict__ y, const int* __restrict__ crowptr,
        const int* __restrict__ cdeg, const int* __restrict__ cnodes,
        float* __restrict__ px) {
    int cl = blockIdx.x;
    int c  = threadIdx.x;
    int start = crowptr[cl];
    int cnt = cdeg[cl];
    float acc = 0.f;
    for (int j = 0; j < cnt; j++) {
        int node = cnodes[start + j];
        acc += y[(size_t)node * 256 + c];
    }
    px[(size_t)cl * 256 + c] = acc / fmaxf((float)cnt, 1.0f);
}

__global__ void k_pooledges(const int* __restrict__ src, const int* __restrict__ dst,
                            const int* __restrict__ bc, unsigned char* __restrict__ bmT, int E) {
    int e = blockIdx.x * 256 + threadIdx.x;
    if (e >= E) return;
    int ps = bc[src[e]];
    int pd = bc[dst[e]];
    bmT[(size_t)pd * NCLUST + ps] = 1;
}

// block per dst cluster; 256 threads sum the 1024-byte bitmap row
__global__ __launch_bounds__(256) void k_pooldeg(
        const unsigned char* __restrict__ bmT, float* __restrict__ dinvp) {
    int d = blockIdx.x;
    int t = threadIdx.x;
    const unsigned int v = reinterpret_cast<const unsigned int*>(bmT + (size_t)d * NCLUST)[t];
    int s = (v & 0xff) + ((v >> 8) & 0xff) + ((v >> 16) & 0xff) + ((v >> 24) & 0xff);
    if (t == (d >> 2)) s -= (v >> ((d & 3) * 8)) & 0xff;   // exclude self-loop
    __shared__ int red[256];
    red[t] = s; __syncthreads();
    for (int o = 128; o > 0; o >>= 1) {
        if (t < o) red[t] += red[t + o];
        __syncthreads();
    }
    if (t == 0) dinvp[d] = rsqrtf((float)red[0] + 1.0f);
}

__global__ void k_proppool(const float* __restrict__ h, const float* __restrict__ dinvp,
                           const unsigned char* __restrict__ bmT, const float* __restrict__ bias,
                           float* __restrict__ out, int F) {
    int d = blockIdx.x;
    int f = threadIdx.x;
    float acc = 0.f;
    for (int s = 0; s < NCLUST; s++) {
        if (s == d) continue;
        if (bmT[(size_t)d * NCLUST + s]) acc += dinvp[s] * h[(size_t)s * F + f];
    }
    float di = dinvp[d];
    float r = di * acc + di * di * h[(size_t)d * F + f] + bias[f];
    out[(size_t)d * F + f] = elu1(r);
}

// ---------------------------------------------------------------------------
extern "C" void kernel_launch(void* const* d_in, const int* in_sizes, int n_in,
                              void* d_out, int out_size, void* d_ws, size_t ws_size,
                              hipStream_t stream) {
    const float* x       = (const float*)d_in[0];
    const int*   adj     = (const int*)d_in[1];
    const int*   inb     = (const int*)d_in[3];
    const int*   cluster = (const int*)d_in[4];
    const float* WG1  = (const float*)d_in[5];   const float* bG1  = (const float*)d_in[6];
    const float* WfG1 = (const float*)d_in[7];   const float* bfG1 = (const float*)d_in[8];
    const float* WG2  = (const float*)d_in[9];   const float* bG2  = (const float*)d_in[10];
    const float* WfG2 = (const float*)d_in[11];  const float* bfG2 = (const float*)d_in[12];
    const float* WL1  = (const float*)d_in[13];  const float* bL1  = (const float*)d_in[14];
    const float* WfL1 = (const float*)d_in[15];  const float* bfL1 = (const float*)d_in[16];
    const float* WL2  = (const float*)d_in[17];  const float* bL2  = (const float*)d_in[18];
    const float* WfL2 = (const float*)d_in[19];  const float* bfL2 = (const float*)d_in[20];
    const float* WO1  = (const float*)d_in[21];  const float* bO1  = (const float*)d_in[22];
    const float* WfO1 = (const float*)d_in[23];  const float* bfO1 = (const float*)d_in[24];
    const float* WO2  = (const float*)d_in[25];  const float* bO2  = (const float*)d_in[26];
    const float* WfO2 = (const float*)d_in[27];  const float* bfO2 = (const float*)d_in[28];
    const float* WO3  = (const float*)d_in[29];  const float* bO3  = (const float*)d_in[30];
    const float* WfO3 = (const float*)d_in[31];  const float* bfO3 = (const float*)d_in[32];
    float* out = (float*)d_out;

    const int n = in_sizes[0] / 3;       // 100000
    const int E = in_sizes[1] / 2;       // 1600000
    const int* src = adj;
    const int* dst = adj + E;

    // ---- workspace carve (~173 MB) ----
    char* ws = (char*)d_ws;
    size_t off = 0;
    auto alloc = [&](size_t bytes) -> void* {
        void* p = ws + off;
        off = (off + bytes + 255) & ~(size_t)255;
        return p;
    };
    int*   deg     = (int*)alloc((size_t)n * 4);     // zero span 1 start
    int*   fill    = (int*)alloc((size_t)n * 4);
    int*   cdeg    = (int*)alloc(NCLUST * 4);
    int*   cfill   = (int*)alloc(NCLUST * 4);
    int*   rowptr  = (int*)alloc((size_t)n * 4);     // zero span 1 end (exclusive)
    int*   crowptr = (int*)alloc(NCLUST * 4);
    int*   cnodes  = (int*)alloc((size_t)n * 4);
    int*   bcarr   = (int*)alloc((size_t)n * 4);
    float* dinv    = (float*)alloc((size_t)n * 4);
    int*   bsum    = (int*)alloc(512);
    int*   csr_src = (int*)alloc((size_t)E * 4);
    float* csr_w   = (float*)alloc((size_t)E * 4);
    float* X       = (float*)alloc((size_t)n * 256 * 4);
    float* B       = (float*)alloc((size_t)n * 128 * 4);
    float* insum   = (float*)alloc(256 * 4);         // zero span 2 start
    float* insumsq = (float*)alloc(256 * 4);
    float* px      = (float*)alloc((size_t)NCLUST * 256 * 4);
    unsigned char* bmT = (unsigned char*)alloc((size_t)NCLUST * NCLUST);
    float* mu      = (float*)alloc(256 * 4);         // zero span 2 end (exclusive)
    float* rstd    = (float*)alloc(256 * 4);
    float* dinvp   = (float*)alloc(NCLUST * 4);
    float* lA      = (float*)alloc((size_t)NCLUST * 128 * 4);
    float* lB      = (float*)alloc((size_t)NCLUST * 128 * 4);
    (void)ws_size; (void)n_in; (void)out_size;

    float* B0 = B;
    float* B1 = B + (size_t)n * 64;

    auto cdiv = [](int a, int b) { return (a + b - 1) / b; };
    const int EB = cdiv(E, 256);
    const int GB = cdiv(n, 64);          // gemm3 grid

    // ---- zero scratch ----
    int nz1 = (int)(((char*)rowptr - (char*)deg) / 16);
    int nz2 = (int)(((char*)mu - (char*)insum) / 16);
    k_zero<<<cdiv(nz1, 256), 256, 0, stream>>>((int4*)deg, nz1);
    k_zero<<<cdiv(nz2, 256), 256, 0, stream>>>((int4*)insum, nz2);

    // ---- CSR build (edges) ----
    k_hist<<<EB, 256, 0, stream>>>(dst, deg, E);
    int nb = cdiv(n, 1024);
    k_scan_block<<<nb, 256, 0, stream>>>(deg, rowptr, bsum, n);
    k_scan_tops<<<1, 128, 0, stream>>>(bsum, nb);
    k_scan_add<<<cdiv(n, 256), 256, 0, stream>>>(rowptr, bsum, n);
    k_dinv_bc<<<cdiv(n, 256), 256, 0, stream>>>(deg, cluster, inb, dinv, bcarr, n);
    k_fill<<<EB, 256, 0, stream>>>(src, dst, dinv, rowptr, fill, csr_src, csr_w, E);

    // ---- CSR build (cluster member lists) ----
    k_hist<<<cdiv(n, 256), 256, 0, stream>>>(bcarr, cdeg, n);
    k_scan_block<<<1, 256, 0, stream>>>(cdeg, crowptr, bsum, NCLUST);
    k_cfill<<<cdiv(n, 256), 256, 0, stream>>>(bcarr, crowptr, cfill, cnodes, n);

    // ---- global GCN stack ----
    k_prop3<<<cdiv(n, 256), 256, 0, stream>>>(x, dinv, rowptr, deg, csr_src, csr_w,
                                              nullptr, B0, n, 0);
    k_fc<64, 2><<<cdiv(n, 32), 256, 0, stream>>>(B0, WG1, bG1, nullptr, nullptr, B1, n, 3, 1);
    // h2 = elu(h1 @ WfG1 + bfG1)  (B1 in-place, 64 square)
    k_gemm3<64, 4><<<GB, 256, 0, stream>>>(B1, WfG1, bfG1, nullptr, nullptr, B1, n, 64, 1);
    k_prop4<<<cdiv(n * 16, 256), 256, 0, stream>>>(B1, dinv, rowptr, deg, csr_src, csr_w,
                                                   nullptr, B0, n, 64, 4, 0);
    // h3 = elu(p64 @ WG2 + bG2)  (X)
    k_gemm3<256, 2><<<GB, 256, 0, stream>>>(B0, WG2, bG2, nullptr, nullptr, X, n, 64, 1);
    // h4 = elu(h3 @ WfG2 + bfG2)  (X in-place)
    k_gemm3<256, 2><<<GB, 256, 0, stream>>>(X, WfG2, bfG2, nullptr, nullptr, X, n, 256, 1);

    // ---- instance norm (in place) -> y = X ----
    k_instats<<<cdiv(n, 128), 256, 0, stream>>>(X, insum, insumsq, n);
    k_infinal<<<1, 256, 0, stream>>>(insum, insumsq, mu, rstd, n);
    k_innorm<<<cdiv(n * 64, 256), 256, 0, stream>>>(X, mu, rstd, n);

    // ---- cluster pooling (gather) ----
    k_poolavg<<<NCLUST, 256, 0, stream>>>(X, crowptr, cdeg, cnodes, px);
    k_pooledges<<<EB, 256, 0, stream>>>(src, dst, bcarr, bmT, E);
    k_pooldeg<<<NCLUST, 256, 0, stream>>>(bmT, dinvp);

    // ---- local (pooled) GCN stack ----
    k_fc<128, 2><<<cdiv(NCLUST, 16), 256, 0, stream>>>(px, WL1, nullptr, nullptr, nullptr,
                                                       lA, NCLUST, 256, 0);
    k_proppool<<<NCLUST, 128, 0, stream>>>(lA, dinvp, bmT, bL1, lB, 128);
    k_fc<128, 2><<<cdiv(NCLUST, 16), 256, 0, stream>>>(lB, WfL1, bfL1, nullptr, nullptr,
                                                       lA, NCLUST, 128, 1);
    k_fc<64, 2><<<cdiv(NCLUST, 32), 256, 0, stream>>>(lA, WL2, nullptr, nullptr, nullptr,
                                                      lB, NCLUST, 128, 0);
    k_proppool<<<NCLUST, 64, 0, stream>>>(lB, dinvp, bmT, bL2, lA, 64);
    k_fc<64, 2><<<cdiv(NCLUST, 32), 256, 0, stream>>>(lA, WfL2, bfL2, nullptr, nullptr,
                                                      lB, NCLUST, 64, 1);
    k_fc<128, 2><<<cdiv(NCLUST, 16), 256, 0, stream>>>(lB, WO1 + (size_t)256 * 128, nullptr,
                                                       nullptr, nullptr, lA, NCLUST, 64, 0);

    // ---- output GCN stack ----
    // t1 = y @ WO1[0:256,:] + compO[bc]  (B, N x 128)
    k_gemm3<128, 4><<<GB, 256, 0, stream>>>(X, WO1, nullptr, lA, bcarr, B, n, 256, 0);
    k_prop4<<<cdiv(n * 32, 256), 256, 0, stream>>>(B, dinv, rowptr, deg, csr_src, csr_w,
                                                   bO1, X, n, 128, 5, 1);
    // o2 = elu(o1 @ WfO1 + bfO1)  (X in-place)
    k_gemm3<128, 4><<<GB, 256, 0, stream>>>(X, WfO1, bfO1, nullptr, nullptr, X, n, 128, 1);
    // t2 = o2 @ WO2  (B, N x 32)
    k_gemm3<32, 4><<<GB, 256, 0, stream>>>(X, WO2, nullptr, nullptr, nullptr, B, n, 128, 0);
    k_prop4<<<cdiv(n * 8, 256), 256, 0, stream>>>(B, dinv, rowptr, deg, csr_src, csr_w,
                                                  bO2, X, n, 32, 3, 1);
    // o4 = elu(o3 @ WfO2 + bfO2)  (X in-place)
    k_gemm3<32, 4><<<GB, 256, 0, stream>>>(X, WfO2, bfO2, nullptr, nullptr, X, n, 32, 1);
    k_fc3<<<cdiv(n, 256), 256, 0, stream>>>(X, WO3, nullptr, B, n, 32, 0);
    k_prop3<<<cdiv(n, 256), 256, 0, stream>>>(B, dinv, rowptr, deg, csr_src, csr_w,
                                              bO3, X, n, 1);
    k_fc3<<<cdiv(n, 256), 256, 0, stream>>>(X, WfO3, bfO3, out, n, 3, 1);
}

// Round 9
// 1600.134 us; speedup vs baseline: 1.2783x; 1.2398x over previous
//
#include <hip/hip_runtime.h>

// ---------------------------------------------------------------------------
// GCN3D: 3x GCNConv + fc (global), instance-norm, cluster pool, 2x GCNConv
// (pooled 1024-cluster graph), gather-broadcast, 3x GCNConv + fc (out).
// N=100000 nodes, E=1600000 edges, C=1024 clusters.
// R3: atomic pooling -> cluster-CSR gather.
// R9: dense fc layers -> split-bf16 MFMA (a_hi*w_hi + a_hi*w_lo + a_lo*w_hi,
//   fp32-equivalent precision). k_gmfma: no LDS, no barriers; W pre-packed to
//   fragment order (hi/lo bf16), A gathered per-lane + converted in-register.
//   Layouts: C/D col=lane&15,row=(lane>>4)*4+reg [m89-verified]; A/B
//   k = 4*(lane>>4)+j, elems 4-7 at k+16 [derived from m162 tr-read].
// ---------------------------------------------------------------------------

#define NCLUST 1024

typedef short bf16x8 __attribute__((ext_vector_type(8)));
typedef float f32x4 __attribute__((ext_vector_type(4)));

__device__ __forceinline__ float elu1(float x) { return x > 0.f ? x : expm1f(x); }

__device__ __forceinline__ unsigned f2bf(float f) {
    union { float f; unsigned u; } c; c.f = f;
    unsigned u = c.u;
    return (u + 0x7fffu + ((u >> 16) & 1u)) >> 16;
}
__device__ __forceinline__ float bf2f(unsigned h) {
    union { unsigned u; float f; } c; c.u = h << 16; return c.f;
}

union U8 { unsigned u[4]; bf16x8 v; };

__global__ void k_zero(int4* __restrict__ p, int n4) {
    int i = blockIdx.x * 256 + threadIdx.x;
    if (i < n4) p[i] = make_int4(0, 0, 0, 0);
}

// ---------------- CSR build (shared by edge graph and cluster lists) --------
__global__ void k_hist(const int* __restrict__ key, int* __restrict__ deg, int E) {
    int e = blockIdx.x * 256 + threadIdx.x;
    if (e < E) atomicAdd(&deg[key[e]], 1);
}

__global__ void k_scan_block(const int* __restrict__ deg, int* __restrict__ rowptr,
                             int* __restrict__ bsum, int n) {
    __shared__ int lds[256];
    int tid = threadIdx.x;
    int base = blockIdx.x * 1024 + tid * 4;
    int v0 = base + 0 < n ? deg[base + 0] : 0;
    int v1 = base + 1 < n ? deg[base + 1] : 0;
    int v2 = base + 2 < n ? deg[base + 2] : 0;
    int v3 = base + 3 < n ? deg[base + 3] : 0;
    int tsum = v0 + v1 + v2 + v3;
    lds[tid] = tsum; __syncthreads();
    for (int off = 1; off < 256; off <<= 1) {
        int t = (tid >= off) ? lds[tid - off] : 0;
        __syncthreads();
        lds[tid] += t;
        __syncthreads();
    }
    int run = lds[tid] - tsum;
    if (base + 0 < n) rowptr[base + 0] = run; run += v0;
    if (base + 1 < n) rowptr[base + 1] = run; run += v1;
    if (base + 2 < n) rowptr[base + 2] = run; run += v2;
    if (base + 3 < n) rowptr[base + 3] = run;
    if (tid == 255) bsum[blockIdx.x] = lds[255];
}

__global__ void k_scan_tops(int* __restrict__ bsum, int nb) {
    __shared__ int lds[128];
    int tid = threadIdx.x;
    int v = tid < nb ? bsum[tid] : 0;
    lds[tid] = v; __syncthreads();
    for (int off = 1; off < 128; off <<= 1) {
        int t = (tid >= off) ? lds[tid - off] : 0;
        __syncthreads();
        lds[tid] += t;
        __syncthreads();
    }
    if (tid < nb) bsum[tid] = lds[tid] - v;
}

__global__ void k_scan_add(int* __restrict__ rowptr, const int* __restrict__ bsum, int n) {
    int i = blockIdx.x * 256 + threadIdx.x;
    if (i < n) rowptr[i] += bsum[i >> 10];
}

__global__ void k_dinv_bc(const int* __restrict__ deg, const int* __restrict__ cluster,
                          const int* __restrict__ inb, float* __restrict__ dinv,
                          int* __restrict__ bc, int n) {
    int i = blockIdx.x * 256 + threadIdx.x;
    if (i < n) {
        dinv[i] = rsqrtf((float)deg[i] + 1.0f);
        bc[i] = cluster[i] + inb[i] * NCLUST;
    }
}

__global__ void k_fill(const int* __restrict__ src, const int* __restrict__ dst,
                       const float* __restrict__ dinv, const int* __restrict__ rowptr,
                       int* __restrict__ fill, int* __restrict__ csr_src,
                       float* __restrict__ csr_w, int E) {
    int e = blockIdx.x * 256 + threadIdx.x;
    if (e >= E) return;
    int d = dst[e];
    int pos = rowptr[d] + atomicAdd(&fill[d], 1);
    int s = src[e];
    csr_src[pos] = s;
    csr_w[pos] = dinv[s];
}

__global__ void k_cfill(const int* __restrict__ bc, const int* __restrict__ crowptr,
                        int* __restrict__ cfill, int* __restrict__ cnodes, int n) {
    int i = blockIdx.x * 256 + threadIdx.x;
    if (i >= n) return;
    int c = bc[i];
    int pos = crowptr[c] + atomicAdd(&cfill[c], 1);
    cnodes[pos] = i;
}

// ---------------- GCN propagation: out = S*h (+bias, elu) ----------------
__global__ __launch_bounds__(256) void k_prop4(
        const float* __restrict__ h, const float* __restrict__ dinv,
        const int* __restrict__ rowptr, const int* __restrict__ deg,
        const int* __restrict__ csr_src, const float* __restrict__ csr_w,
        const float* __restrict__ bias, float* __restrict__ out,
        int n, int F, int lshift, int flags) {
    int gid = blockIdx.x * 256 + threadIdx.x;
    int node = gid >> lshift;
    if (node >= n) return;
    int fi = (gid & ((1 << lshift) - 1)) * 4;
    int start = rowptr[node];
    int cnt = deg[node];
    float ax = 0.f, ay = 0.f, az = 0.f, aw = 0.f;
    for (int j = 0; j < cnt; j++) {
        int s = csr_src[start + j];
        float w = csr_w[start + j];
        const float4 v = *reinterpret_cast<const float4*>(&h[(size_t)s * F + fi]);
        ax += w * v.x; ay += w * v.y; az += w * v.z; aw += w * v.w;
    }
    float di = dinv[node];
    const float4 sv = *reinterpret_cast<const float4*>(&h[(size_t)node * F + fi]);
    float4 o;
    o.x = di * ax + di * di * sv.x;
    o.y = di * ay + di * di * sv.y;
    o.z = di * az + di * di * sv.z;
    o.w = di * aw + di * di * sv.w;
    if (flags) {
        const float4 b = *reinterpret_cast<const float4*>(&bias[fi]);
        o.x = elu1(o.x + b.x); o.y = elu1(o.y + b.y);
        o.z = elu1(o.z + b.z); o.w = elu1(o.w + b.w);
    }
    *reinterpret_cast<float4*>(&out[(size_t)node * F + fi]) = o;
}

__global__ void k_prop3(const float* __restrict__ h, const float* __restrict__ dinv,
                        const int* __restrict__ rowptr, const int* __restrict__ deg,
                        const int* __restrict__ csr_src, const float* __restrict__ csr_w,
                        const float* __restrict__ bias, float* __restrict__ out,
                        int n, int flags) {
    int node = blockIdx.x * 256 + threadIdx.x;
    if (node >= n) return;
    int start = rowptr[node], cnt = deg[node];
    float a0 = 0.f, a1 = 0.f, a2 = 0.f;
    for (int j = 0; j < cnt; j++) {
        int s = csr_src[start + j];
        float w = csr_w[start + j];
        a0 += w * h[(size_t)s * 3 + 0];
        a1 += w * h[(size_t)s * 3 + 1];
        a2 += w * h[(size_t)s * 3 + 2];
    }
    float di = dinv[node];
    float o0 = di * a0 + di * di * h[(size_t)node * 3 + 0];
    float o1 = di * a1 + di * di * h[(size_t)node * 3 + 1];
    float o2 = di * a2 + di * di * h[(size_t)node * 3 + 2];
    if (flags) {
        o0 = elu1(o0 + bias[0]); o1 = elu1(o1 + bias[1]); o2 = elu1(o2 + bias[2]);
    }
    out[(size_t)node * 3 + 0] = o0;
    out[(size_t)node * 3 + 1] = o1;
    out[(size_t)node * 3 + 2] = o2;
}

// ---- W pre-pack to MFMA fragment order (hi/lo bf16 pairs) ----
// Fragment: lane holds B[k][col], col=ct*16+(lane&15), k=k0+4*(lane>>4)+j
// (elems 0-3) and +16 (elems 4-7). Packed u32[j] = bf16(e[2j]) | bf16(e[2j+1])<<16.
__global__ void k_wpack(const float* __restrict__ W, unsigned* __restrict__ Phi,
                        unsigned* __restrict__ Plo, int K, int BN) {
    int t = blockIdx.x * 256 + threadIdx.x;
    int NT = BN / 16;
    int total = (K / 32) * NT * 64;
    if (t >= total) return;
    int lane = t & 63;
    int rest = t >> 6;
    int ct = rest % NT;
    int s = rest / NT;
    int col = ct * 16 + (lane & 15);
    int g = lane >> 4;
    int k0 = s * 32;
    float e[8];
#pragma unroll
    for (int j = 0; j < 4; j++) {
        e[j]     = W[(size_t)(k0 + 4 * g + j) * BN + col];
        e[4 + j] = W[(size_t)(k0 + 16 + 4 * g + j) * BN + col];
    }
#pragma unroll
    for (int j = 0; j < 4; j++) {
        unsigned h0 = f2bf(e[2 * j]), h1 = f2bf(e[2 * j + 1]);
        Phi[(size_t)t * 4 + j] = h0 | (h1 << 16);
        unsigned l0 = f2bf(e[2 * j] - bf2f(h0));
        unsigned l1 = f2bf(e[2 * j + 1] - bf2f(h1));
        Plo[(size_t)t * 4 + j] = l0 | (l1 << 16);
    }
}

// ---- split-bf16 MFMA GEMM: C = A[N,K] @ W[K,BN] (+add[idx], +bias, elu) ----
// 256 threads = 4 waves; wave w owns rows [row0+16w, +16); loops over
// BN/16 col-tiles x K/32 steps. No LDS, no barriers. In-place safe (wave
// reads/writes only its own rows; tail clamped rows computed, not stored).
template <int BN>
__global__ __launch_bounds__(256) void k_gmfma(
        const float* __restrict__ A, const unsigned* __restrict__ Phi,
        const unsigned* __restrict__ Plo, const float* __restrict__ bias,
        const float* __restrict__ add, const int* __restrict__ addidx,
        float* __restrict__ C, int N, int K, int flags) {
    constexpr int NT = BN / 16;
    const int t = threadIdx.x;
    const int w = t >> 6, l = t & 63;
    const int l15 = l & 15, g = l >> 4;
    const int row0 = blockIdx.x * 64 + w * 16;
    int arow = row0 + l15; arow = arow < N ? arow : N - 1;
    const float* ap = A + (size_t)arow * K;

    f32x4 acc[NT];
#pragma unroll
    for (int ct = 0; ct < NT; ct++) acc[ct] = (f32x4){0.f, 0.f, 0.f, 0.f};

    const int nk = K / 32;
    for (int s = 0; s < nk; ++s) {
        const int k0 = s * 32;
        const float4 a0 = *reinterpret_cast<const float4*>(ap + k0 + 4 * g);
        const float4 a1 = *reinterpret_cast<const float4*>(ap + k0 + 16 + 4 * g);
        float e[8] = {a0.x, a0.y, a0.z, a0.w, a1.x, a1.y, a1.z, a1.w};
        U8 ahi, alo;
#pragma unroll
        for (int j = 0; j < 4; j++) {
            unsigned h0 = f2bf(e[2 * j]), h1 = f2bf(e[2 * j + 1]);
            ahi.u[j] = h0 | (h1 << 16);
            unsigned l0 = f2bf(e[2 * j] - bf2f(h0));
            unsigned l1 = f2bf(e[2 * j + 1] - bf2f(h1));
            alo.u[j] = l0 | (l1 << 16);
        }
        const unsigned* pb = Phi + ((size_t)s * NT * 64 + l) * 4;
        const unsigned* pl = Plo + ((size_t)s * NT * 64 + l) * 4;
#pragma unroll
        for (int ct = 0; ct < NT; ct++) {
            U8 wh = *reinterpret_cast<const U8*>(pb + (size_t)ct * 256);
            U8 wl = *reinterpret_cast<const U8*>(pl + (size_t)ct * 256);
            acc[ct] = __builtin_amdgcn_mfma_f32_16x16x32_bf16(ahi.v, wh.v, acc[ct], 0, 0, 0);
            acc[ct] = __builtin_amdgcn_mfma_f32_16x16x32_bf16(ahi.v, wl.v, acc[ct], 0, 0, 0);
            acc[ct] = __builtin_amdgcn_mfma_f32_16x16x32_bf16(alo.v, wh.v, acc[ct], 0, 0, 0);
        }
    }
    // epilogue: D row = 4*g + r, col = ct*16 + l15
#pragma unroll
    for (int r = 0; r < 4; r++) {
        int row = row0 + 4 * g + r;
        if (row >= N) continue;
        int gi = (add != nullptr) ? addidx[row] : 0;
#pragma unroll
        for (int ct = 0; ct < NT; ct++) {
            int col = ct * 16 + l15;
            float o = acc[ct][r];
            if (add != nullptr) o += add[(size_t)gi * BN + col];
            if (flags) o = elu1(o + bias[col]);
            C[(size_t)row * BN + col] = o;
        }
    }
}

// ---------------- simple fc (small shapes: K=3 layer, local C=1024 stack) ----
template <int M, int RPT>
__global__ __launch_bounds__(256) void k_fc(
        const float* __restrict__ A, const float* __restrict__ W,
        const float* __restrict__ bias, const float* __restrict__ add,
        const int* __restrict__ addidx, float* __restrict__ C,
        int N, int K, int flags) {
    constexpr int TX = M / 4;
    constexpr int TY = 256 / TX;
    constexpr int RB = TY * RPT;
    int tx = threadIdx.x % TX;
    int ty = threadIdx.x / TX;
    int row0 = blockIdx.x * RB + ty * RPT;
    float4 acc[RPT];
#pragma unroll
    for (int r = 0; r < RPT; r++) acc[r] = make_float4(0.f, 0.f, 0.f, 0.f);
    for (int k = 0; k < K; k++) {
        float4 w = *reinterpret_cast<const float4*>(&W[(size_t)k * M + tx * 4]);
#pragma unroll
        for (int r = 0; r < RPT; r++) {
            int row = row0 + r;
            row = row < N ? row : N - 1;
            float a = A[(size_t)row * K + k];
            acc[r].x += a * w.x; acc[r].y += a * w.y;
            acc[r].z += a * w.z; acc[r].w += a * w.w;
        }
    }
    if (add != nullptr) {
#pragma unroll
        for (int r = 0; r < RPT; r++) {
            int row = row0 + r;
            if (row < N) {
                int g = addidx[row];
                const float4 v = *reinterpret_cast<const float4*>(&add[(size_t)g * M + tx * 4]);
                acc[r].x += v.x; acc[r].y += v.y; acc[r].z += v.z; acc[r].w += v.w;
            }
        }
    }
    __syncthreads();
    float4 b = make_float4(0.f, 0.f, 0.f, 0.f);
    if (flags) b = *reinterpret_cast<const float4*>(&bias[tx * 4]);
#pragma unroll
    for (int r = 0; r < RPT; r++) {
        int row = row0 + r;
        if (row >= N) break;
        float4 o = acc[r];
        o.x += b.x; o.y += b.y; o.z += b.z; o.w += b.w;
        if (flags) { o.x = elu1(o.x); o.y = elu1(o.y); o.z = elu1(o.z); o.w = elu1(o.w); }
        *reinterpret_cast<float4*>(&C[(size_t)row * M + tx * 4]) = o;
    }
}

// M = 3 (W: K x 3)
__global__ void k_fc3(const float* __restrict__ A, const float* __restrict__ W,
                      const float* __restrict__ b, float* __restrict__ C,
                      int n, int K, int flags) {
    int r = blockIdx.x * 256 + threadIdx.x;
    if (r >= n) return;
    float a0 = 0.f, a1 = 0.f, a2 = 0.f;
    for (int k = 0; k < K; k++) {
        float a = A[(size_t)r * K + k];
        a0 += a * W[k * 3 + 0]; a1 += a * W[k * 3 + 1]; a2 += a * W[k * 3 + 2];
    }
    if (flags) {
        a0 = elu1(a0 + b[0]); a1 = elu1(a1 + b[1]); a2 = elu1(a2 + b[2]);
    }
    C[(size_t)r * 3 + 0] = a0;
    C[(size_t)r * 3 + 1] = a1;
    C[(size_t)r * 3 + 2] = a2;
}

// ---------------- instance norm (in-place apply) ----------------
__global__ void k_instats(const float* __restrict__ h, float* __restrict__ sum,
                          float* __restrict__ sumsq, int n) {
    int c = threadIdx.x;
    int r0 = blockIdx.x * 128;
    int r1 = r0 + 128 < n ? r0 + 128 : n;
    float s = 0.f, q = 0.f;
    for (int r = r0; r < r1; r++) {
        float v = h[(size_t)r * 256 + c];
        s += v; q += v * v;
    }
    atomicAdd(&sum[c], s);
    atomicAdd(&sumsq[c], q);
}

__global__ void k_infinal(const float* __restrict__ sum, const float* __restrict__ sumsq,
                          float* __restrict__ mu, float* __restrict__ rstd, int n) {
    int c = threadIdx.x;
    float m = sum[c] / (float)n;
    float var = sumsq[c] / (float)n - m * m;
    mu[c] = m;
    rstd[c] = rsqrtf(var + 1e-5f);
}

__global__ void k_innorm(float* __restrict__ h, const float* __restrict__ mu,
                         const float* __restrict__ rstd, int n) {
    int gid = blockIdx.x * 256 + threadIdx.x;
    int node = gid >> 6;
    if (node >= n) return;
    int c = (gid & 63) * 4;
    float4 v = *reinterpret_cast<const float4*>(&h[(size_t)node * 256 + c]);
    float4 m = *reinterpret_cast<const float4*>(&mu[c]);
    float4 rs = *reinterpret_cast<const float4*>(&rstd[c]);
    v.x = (v.x - m.x) * rs.x; v.y = (v.y - m.y) * rs.y;
    v.z = (v.z - m.z) * rs.z; v.w = (v.w - m.w) * rs.w;
    *reinterpret_cast<float4*>(&h[(size_t)node * 256 + c]) = v;
}

// ---------------- cluster pooling (CSR gather, no atomics) ----------------
__global__ __launch_bounds__(256) void k_poolavg(
        const float* __restrict__ y, const int* __restrict__ crowptr,
        const int* __restrict__ cdeg, const int* __restrict__ cnodes,
        float* __restrict__ px) {
    int cl = blockIdx.x;
    int c  = threadIdx.x;
    int start = crowptr[cl];
    int cnt = cdeg[cl];
    float acc = 0.f;
    for (int j = 0; j < cnt; j++) {
        int node = cnodes[start + j];
        acc += y[(size_t)node * 256 + c];
    }
    px[(size_t)cl * 256 + c] = acc / fmaxf((float)cnt, 1.0f);
}

__global__ void k_pooledges(const int* __restrict__ src, const int* __restrict__ dst,
                            const int* __restrict__ bc, unsigned char* __restrict__ bmT, int E) {
    int e = blockIdx.x * 256 + threadIdx.x;
    if (e >= E) return;
    int ps = bc[src[e]];
    int pd = bc[dst[e]];
    bmT[(size_t)pd * NCLUST + ps] = 1;
}

__global__ __launch_bounds__(256) void k_pooldeg(
        const unsigned char* __restrict__ bmT, float* __restrict__ dinvp) {
    int d = blockIdx.x;
    int t = threadIdx.x;
    const unsigned int v = reinterpret_cast<const unsigned int*>(bmT + (size_t)d * NCLUST)[t];
    int s = (v & 0xff) + ((v >> 8) & 0xff) + ((v >> 16) & 0xff) + ((v >> 24) & 0xff);
    if (t == (d >> 2)) s -= (v >> ((d & 3) * 8)) & 0xff;
    __shared__ int red[256];
    red[t] = s; __syncthreads();
    for (int o = 128; o > 0; o >>= 1) {
        if (t < o) red[t] += red[t + o];
        __syncthreads();
    }
    if (t == 0) dinvp[d] = rsqrtf((float)red[0] + 1.0f);
}

__global__ void k_proppool(const float* __restrict__ h, const float* __restrict__ dinvp,
                           const unsigned char* __restrict__ bmT, const float* __restrict__ bias,
                           float* __restrict__ out, int F) {
    int d = blockIdx.x;
    int f = threadIdx.x;
    float acc = 0.f;
    for (int s = 0; s < NCLUST; s++) {
        if (s == d) continue;
        if (bmT[(size_t)d * NCLUST + s]) acc += dinvp[s] * h[(size_t)s * F + f];
    }
    float di = dinvp[d];
    float r = di * acc + di * di * h[(size_t)d * F + f] + bias[f];
    out[(size_t)d * F + f] = elu1(r);
}

// ---------------------------------------------------------------------------
extern "C" void kernel_launch(void* const* d_in, const int* in_sizes, int n_in,
                              void* d_out, int out_size, void* d_ws, size_t ws_size,
                              hipStream_t stream) {
    const float* x       = (const float*)d_in[0];
    const int*   adj     = (const int*)d_in[1];
    const int*   inb     = (const int*)d_in[3];
    const int*   cluster = (const int*)d_in[4];
    const float* WG1  = (const float*)d_in[5];   const float* bG1  = (const float*)d_in[6];
    const float* WfG1 = (const float*)d_in[7];   const float* bfG1 = (const float*)d_in[8];
    const float* WG2  = (const float*)d_in[9];   const float* bG2  = (const float*)d_in[10];
    const float* WfG2 = (const float*)d_in[11];  const float* bfG2 = (const float*)d_in[12];
    const float* WL1  = (const float*)d_in[13];  const float* bL1  = (const float*)d_in[14];
    const float* WfL1 = (const float*)d_in[15];  const float* bfL1 = (const float*)d_in[16];
    const float* WL2  = (const float*)d_in[17];  const float* bL2  = (const float*)d_in[18];
    const float* WfL2 = (const float*)d_in[19];  const float* bfL2 = (const float*)d_in[20];
    const float* WO1  = (const float*)d_in[21];  const float* bO1  = (const float*)d_in[22];
    const float* WfO1 = (const float*)d_in[23];  const float* bfO1 = (const float*)d_in[24];
    const float* WO2  = (const float*)d_in[25];  const float* bO2  = (const float*)d_in[26];
    const float* WfO2 = (const float*)d_in[27];  const float* bfO2 = (const float*)d_in[28];
    const float* WO3  = (const float*)d_in[29];  const float* bO3  = (const float*)d_in[30];
    const float* WfO3 = (const float*)d_in[31];  const float* bfO3 = (const float*)d_in[32];
    float* out = (float*)d_out;

    const int n = in_sizes[0] / 3;       // 100000
    const int E = in_sizes[1] / 2;       // 1600000
    const int* src = adj;
    const int* dst = adj + E;

    // ---- workspace carve (~174 MB) ----
    char* ws = (char*)d_ws;
    size_t off = 0;
    auto alloc = [&](size_t bytes) -> void* {
        void* p = ws + off;
        off = (off + bytes + 255) & ~(size_t)255;
        return p;
    };
    int*   deg     = (int*)alloc((size_t)n * 4);     // zero span 1 start
    int*   fill    = (int*)alloc((size_t)n * 4);
    int*   cdeg    = (int*)alloc(NCLUST * 4);
    int*   cfill   = (int*)alloc(NCLUST * 4);
    int*   rowptr  = (int*)alloc((size_t)n * 4);     // zero span 1 end (exclusive)
    int*   crowptr = (int*)alloc(NCLUST * 4);
    int*   cnodes  = (int*)alloc((size_t)n * 4);
    int*   bcarr   = (int*)alloc((size_t)n * 4);
    float* dinv    = (float*)alloc((size_t)n * 4);
    int*   bsum    = (int*)alloc(512);
    int*   csr_src = (int*)alloc((size_t)E * 4);
    float* csr_w   = (float*)alloc((size_t)E * 4);
    float* X       = (float*)alloc((size_t)n * 256 * 4);
    float* B       = (float*)alloc((size_t)n * 128 * 4);
    float* insum   = (float*)alloc(256 * 4);         // zero span 2 start
    float* insumsq = (float*)alloc(256 * 4);
    float* px      = (float*)alloc((size_t)NCLUST * 256 * 4);
    unsigned char* bmT = (unsigned char*)alloc((size_t)NCLUST * NCLUST);
    float* mu      = (float*)alloc(256 * 4);         // zero span 2 end (exclusive)
    float* rstd    = (float*)alloc(256 * 4);
    float* dinvp   = (float*)alloc(NCLUST * 4);
    float* lA      = (float*)alloc((size_t)NCLUST * 128 * 4);
    float* lB      = (float*)alloc((size_t)NCLUST * 128 * 4);
    // packed weights (u32 count = K*BN/2 each)
    unsigned* pfG1h = (unsigned*)alloc(2048 * 4);   unsigned* pfG1l = (unsigned*)alloc(2048 * 4);
    unsigned* pG2h  = (unsigned*)alloc(8192 * 4);   unsigned* pG2l  = (unsigned*)alloc(8192 * 4);
    unsigned* pfG2h = (unsigned*)alloc(32768 * 4);  unsigned* pfG2l = (unsigned*)alloc(32768 * 4);
    unsigned* pO1h  = (unsigned*)alloc(16384 * 4);  unsigned* pO1l  = (unsigned*)alloc(16384 * 4);
    unsigned* pfO1h = (unsigned*)alloc(8192 * 4);   unsigned* pfO1l = (unsigned*)alloc(8192 * 4);
    unsigned* pO2h  = (unsigned*)alloc(2048 * 4);   unsigned* pO2l  = (unsigned*)alloc(2048 * 4);
    unsigned* pfO2h = (unsigned*)alloc(512 * 4);    unsigned* pfO2l = (unsigned*)alloc(512 * 4);
    (void)ws_size; (void)n_in; (void)out_size;

    float* B0 = B;
    float* B1 = B + (size_t)n * 64;

    auto cdiv = [](int a, int b) { return (a + b - 1) / b; };
    const int EB = cdiv(E, 256);
    const int GB = cdiv(n, 64);          // gmfma grid

    // ---- zero scratch ----
    int nz1 = (int)(((char*)rowptr - (char*)deg) / 16);
    int nz2 = (int)(((char*)mu - (char*)insum) / 16);
    k_zero<<<cdiv(nz1, 256), 256, 0, stream>>>((int4*)deg, nz1);
    k_zero<<<cdiv(nz2, 256), 256, 0, stream>>>((int4*)insum, nz2);

    // ---- pack weights to MFMA fragment order ----
    k_wpack<<<cdiv(512, 256), 256, 0, stream>>>(WfG1, pfG1h, pfG1l, 64, 64);
    k_wpack<<<cdiv(2048, 256), 256, 0, stream>>>(WG2, pG2h, pG2l, 64, 256);
    k_wpack<<<cdiv(8192, 256), 256, 0, stream>>>(WfG2, pfG2h, pfG2l, 256, 256);
    k_wpack<<<cdiv(4096, 256), 256, 0, stream>>>(WO1, pO1h, pO1l, 256, 128);
    k_wpack<<<cdiv(2048, 256), 256, 0, stream>>>(WfO1, pfO1h, pfO1l, 128, 128);
    k_wpack<<<cdiv(512, 256), 256, 0, stream>>>(WO2, pO2h, pO2l, 128, 32);
    k_wpack<<<cdiv(128, 256), 256, 0, stream>>>(WfO2, pfO2h, pfO2l, 32, 32);

    // ---- CSR build (edges) ----
    k_hist<<<EB, 256, 0, stream>>>(dst, deg, E);
    int nb = cdiv(n, 1024);
    k_scan_block<<<nb, 256, 0, stream>>>(deg, rowptr, bsum, n);
    k_scan_tops<<<1, 128, 0, stream>>>(bsum, nb);
    k_scan_add<<<cdiv(n, 256), 256, 0, stream>>>(rowptr, bsum, n);
    k_dinv_bc<<<cdiv(n, 256), 256, 0, stream>>>(deg, cluster, inb, dinv, bcarr, n);
    k_fill<<<EB, 256, 0, stream>>>(src, dst, dinv, rowptr, fill, csr_src, csr_w, E);

    // ---- CSR build (cluster member lists) ----
    k_hist<<<cdiv(n, 256), 256, 0, stream>>>(bcarr, cdeg, n);
    k_scan_block<<<1, 256, 0, stream>>>(cdeg, crowptr, bsum, NCLUST);
    k_cfill<<<cdiv(n, 256), 256, 0, stream>>>(bcarr, crowptr, cfill, cnodes, n);

    // ---- global GCN stack ----
    k_prop3<<<cdiv(n, 256), 256, 0, stream>>>(x, dinv, rowptr, deg, csr_src, csr_w,
                                              nullptr, B0, n, 0);
    k_fc<64, 2><<<cdiv(n, 32), 256, 0, stream>>>(B0, WG1, bG1, nullptr, nullptr, B1, n, 3, 1);
    // h2 = elu(h1 @ WfG1 + bfG1)  (B1 in-place)
    k_gmfma<64><<<GB, 256, 0, stream>>>(B1, pfG1h, pfG1l, bfG1, nullptr, nullptr, B1, n, 64, 1);
    k_prop4<<<cdiv(n * 16, 256), 256, 0, stream>>>(B1, dinv, rowptr, deg, csr_src, csr_w,
                                                   nullptr, B0, n, 64, 4, 0);
    // h3 = elu(p64 @ WG2 + bG2)  (X)
    k_gmfma<256><<<GB, 256, 0, stream>>>(B0, pG2h, pG2l, bG2, nullptr, nullptr, X, n, 64, 1);
    // h4 = elu(h3 @ WfG2 + bfG2)  (X in-place)
    k_gmfma<256><<<GB, 256, 0, stream>>>(X, pfG2h, pfG2l, bfG2, nullptr, nullptr, X, n, 256, 1);

    // ---- instance norm (in place) -> y = X ----
    k_instats<<<cdiv(n, 128), 256, 0, stream>>>(X, insum, insumsq, n);
    k_infinal<<<1, 256, 0, stream>>>(insum, insumsq, mu, rstd, n);
    k_innorm<<<cdiv(n * 64, 256), 256, 0, stream>>>(X, mu, rstd, n);

    // ---- cluster pooling (gather) ----
    k_poolavg<<<NCLUST, 256, 0, stream>>>(X, crowptr, cdeg, cnodes, px);
    k_pooledges<<<EB, 256, 0, stream>>>(src, dst, bcarr, bmT, E);
    k_pooldeg<<<NCLUST, 256, 0, stream>>>(bmT, dinvp);

    // ---- local (pooled) GCN stack ----
    k_fc<128, 2><<<cdiv(NCLUST, 16), 256, 0, stream>>>(px, WL1, nullptr, nullptr, nullptr,
                                                       lA, NCLUST, 256, 0);
    k_proppool<<<NCLUST, 128, 0, stream>>>(lA, dinvp, bmT, bL1, lB, 128);
    k_fc<128, 2><<<cdiv(NCLUST, 16), 256, 0, stream>>>(lB, WfL1, bfL1, nullptr, nullptr,
                                                       lA, NCLUST, 128, 1);
    k_fc<64, 2><<<cdiv(NCLUST, 32), 256, 0, stream>>>(lA, WL2, nullptr, nullptr, nullptr,
                                                      lB, NCLUST, 128, 0);
    k_proppool<<<NCLUST, 64, 0, stream>>>(lB, dinvp, bmT, bL2, lA, 64);
    k_fc<64, 2><<<cdiv(NCLUST, 32), 256, 0, stream>>>(lA, WfL2, bfL2, nullptr, nullptr,
                                                      lB, NCLUST, 64, 1);
    k_fc<128, 2><<<cdiv(NCLUST, 16), 256, 0, stream>>>(lB, WO1 + (size_t)256 * 128, nullptr,
                                                       nullptr, nullptr, lA, NCLUST, 64, 0);

    // ---- output GCN stack ----
    // t1 = y @ WO1[0:256,:] + compO[bc]  (B, N x 128)
    k_gmfma<128><<<GB, 256, 0, stream>>>(X, pO1h, pO1l, nullptr, lA, bcarr, B, n, 256, 0);
    k_prop4<<<cdiv(n * 32, 256), 256, 0, stream>>>(B, dinv, rowptr, deg, csr_src, csr_w,
                                                   bO1, X, n, 128, 5, 1);
    // o2 = elu(o1 @ WfO1 + bfO1)  (X in-place)
    k_gmfma<128><<<GB, 256, 0, stream>>>(X, pfO1h, pfO1l, bfO1, nullptr, nullptr, X, n, 128, 1);
    // t2 = o2 @ WO2  (B, N x 32)
    k_gmfma<32><<<GB, 256, 0, stream>>>(X, pO2h, pO2l, nullptr, nullptr, nullptr, B, n, 128, 0);
    k_prop4<<<cdiv(n * 8, 256), 256, 0, stream>>>(B, dinv, rowptr, deg, csr_src, csr_w,
                                                  bO2, X, n, 32, 3, 1);
    // o4 = elu(o3 @ WfO2 + bfO2)  (X in-place)
    k_gmfma<32><<<GB, 256, 0, stream>>>(X, pfO2h, pfO2l, bfO2, nullptr, nullptr, X, n, 32, 1);
    k_fc3<<<cdiv(n, 256), 256, 0, stream>>>(X, WO3, nullptr, B, n, 32, 0);
    k_prop3<<<cdiv(n, 256), 256, 0, stream>>>(B, dinv, rowptr, deg, csr_src, csr_w,
                                              bO3, X, n, 1);
    k_fc3<<<cdiv(n, 256), 256, 0, stream>>>(X, WfO3, bfO3, out, n, 3, 1);
}

// Round 10
// 1347.189 us; speedup vs baseline: 1.5183x; 1.1878x over previous
//
#include <hip/hip_runtime.h>

// ---------------------------------------------------------------------------
// GCN3D: 3x GCNConv + fc (global), instance-norm, cluster pool, 2x GCNConv
// (pooled 1024-cluster graph), gather-broadcast, 3x GCNConv + fc (out).
// N=100000 nodes, E=1600000 edges, C=1024 clusters.
// R3: atomic pooling -> cluster-CSR gather.
// R9: dense fc layers -> split-bf16 MFMA (fp32-equivalent via 3 MFMAs).
// R10: k_proppool2 -- pooled propagation was a 1024-iter serial scan per
//   block (200us x2, VALUBusy 4%); now 1024-thread blocks, 8/16-way s-split
//   with predicated accumulate + LDS tree reduce.
// ---------------------------------------------------------------------------

#define NCLUST 1024

typedef short bf16x8 __attribute__((ext_vector_type(8)));
typedef float f32x4 __attribute__((ext_vector_type(4)));

__device__ __forceinline__ float elu1(float x) { return x > 0.f ? x : expm1f(x); }

__device__ __forceinline__ unsigned f2bf(float f) {
    union { float f; unsigned u; } c; c.f = f;
    unsigned u = c.u;
    return (u + 0x7fffu + ((u >> 16) & 1u)) >> 16;
}
__device__ __forceinline__ float bf2f(unsigned h) {
    union { unsigned u; float f; } c; c.u = h << 16; return c.f;
}

union U8 { unsigned u[4]; bf16x8 v; };

__global__ void k_zero(int4* __restrict__ p, int n4) {
    int i = blockIdx.x * 256 + threadIdx.x;
    if (i < n4) p[i] = make_int4(0, 0, 0, 0);
}

// ---------------- CSR build (shared by edge graph and cluster lists) --------
__global__ void k_hist(const int* __restrict__ key, int* __restrict__ deg, int E) {
    int e = blockIdx.x * 256 + threadIdx.x;
    if (e < E) atomicAdd(&deg[key[e]], 1);
}

__global__ void k_scan_block(const int* __restrict__ deg, int* __restrict__ rowptr,
                             int* __restrict__ bsum, int n) {
    __shared__ int lds[256];
    int tid = threadIdx.x;
    int base = blockIdx.x * 1024 + tid * 4;
    int v0 = base + 0 < n ? deg[base + 0] : 0;
    int v1 = base + 1 < n ? deg[base + 1] : 0;
    int v2 = base + 2 < n ? deg[base + 2] : 0;
    int v3 = base + 3 < n ? deg[base + 3] : 0;
    int tsum = v0 + v1 + v2 + v3;
    lds[tid] = tsum; __syncthreads();
    for (int off = 1; off < 256; off <<= 1) {
        int t = (tid >= off) ? lds[tid - off] : 0;
        __syncthreads();
        lds[tid] += t;
        __syncthreads();
    }
    int run = lds[tid] - tsum;
    if (base + 0 < n) rowptr[base + 0] = run; run += v0;
    if (base + 1 < n) rowptr[base + 1] = run; run += v1;
    if (base + 2 < n) rowptr[base + 2] = run; run += v2;
    if (base + 3 < n) rowptr[base + 3] = run;
    if (tid == 255) bsum[blockIdx.x] = lds[255];
}

__global__ void k_scan_tops(int* __restrict__ bsum, int nb) {
    __shared__ int lds[128];
    int tid = threadIdx.x;
    int v = tid < nb ? bsum[tid] : 0;
    lds[tid] = v; __syncthreads();
    for (int off = 1; off < 128; off <<= 1) {
        int t = (tid >= off) ? lds[tid - off] : 0;
        __syncthreads();
        lds[tid] += t;
        __syncthreads();
    }
    if (tid < nb) bsum[tid] = lds[tid] - v;
}

__global__ void k_scan_add(int* __restrict__ rowptr, const int* __restrict__ bsum, int n) {
    int i = blockIdx.x * 256 + threadIdx.x;
    if (i < n) rowptr[i] += bsum[i >> 10];
}

__global__ void k_dinv_bc(const int* __restrict__ deg, const int* __restrict__ cluster,
                          const int* __restrict__ inb, float* __restrict__ dinv,
                          int* __restrict__ bc, int n) {
    int i = blockIdx.x * 256 + threadIdx.x;
    if (i < n) {
        dinv[i] = rsqrtf((float)deg[i] + 1.0f);
        bc[i] = cluster[i] + inb[i] * NCLUST;
    }
}

__global__ void k_fill(const int* __restrict__ src, const int* __restrict__ dst,
                       const float* __restrict__ dinv, const int* __restrict__ rowptr,
                       int* __restrict__ fill, int* __restrict__ csr_src,
                       float* __restrict__ csr_w, int E) {
    int e = blockIdx.x * 256 + threadIdx.x;
    if (e >= E) return;
    int d = dst[e];
    int pos = rowptr[d] + atomicAdd(&fill[d], 1);
    int s = src[e];
    csr_src[pos] = s;
    csr_w[pos] = dinv[s];
}

__global__ void k_cfill(const int* __restrict__ bc, const int* __restrict__ crowptr,
                        int* __restrict__ cfill, int* __restrict__ cnodes, int n) {
    int i = blockIdx.x * 256 + threadIdx.x;
    if (i >= n) return;
    int c = bc[i];
    int pos = crowptr[c] + atomicAdd(&cfill[c], 1);
    cnodes[pos] = i;
}

// ---------------- GCN propagation: out = S*h (+bias, elu) ----------------
__global__ __launch_bounds__(256) void k_prop4(
        const float* __restrict__ h, const float* __restrict__ dinv,
        const int* __restrict__ rowptr, const int* __restrict__ deg,
        const int* __restrict__ csr_src, const float* __restrict__ csr_w,
        const float* __restrict__ bias, float* __restrict__ out,
        int n, int F, int lshift, int flags) {
    int gid = blockIdx.x * 256 + threadIdx.x;
    int node = gid >> lshift;
    if (node >= n) return;
    int fi = (gid & ((1 << lshift) - 1)) * 4;
    int start = rowptr[node];
    int cnt = deg[node];
    float ax = 0.f, ay = 0.f, az = 0.f, aw = 0.f;
    for (int j = 0; j < cnt; j++) {
        int s = csr_src[start + j];
        float w = csr_w[start + j];
        const float4 v = *reinterpret_cast<const float4*>(&h[(size_t)s * F + fi]);
        ax += w * v.x; ay += w * v.y; az += w * v.z; aw += w * v.w;
    }
    float di = dinv[node];
    const float4 sv = *reinterpret_cast<const float4*>(&h[(size_t)node * F + fi]);
    float4 o;
    o.x = di * ax + di * di * sv.x;
    o.y = di * ay + di * di * sv.y;
    o.z = di * az + di * di * sv.z;
    o.w = di * aw + di * di * sv.w;
    if (flags) {
        const float4 b = *reinterpret_cast<const float4*>(&bias[fi]);
        o.x = elu1(o.x + b.x); o.y = elu1(o.y + b.y);
        o.z = elu1(o.z + b.z); o.w = elu1(o.w + b.w);
    }
    *reinterpret_cast<float4*>(&out[(size_t)node * F + fi]) = o;
}

__global__ void k_prop3(const float* __restrict__ h, const float* __restrict__ dinv,
                        const int* __restrict__ rowptr, const int* __restrict__ deg,
                        const int* __restrict__ csr_src, const float* __restrict__ csr_w,
                        const float* __restrict__ bias, float* __restrict__ out,
                        int n, int flags) {
    int node = blockIdx.x * 256 + threadIdx.x;
    if (node >= n) return;
    int start = rowptr[node], cnt = deg[node];
    float a0 = 0.f, a1 = 0.f, a2 = 0.f;
    for (int j = 0; j < cnt; j++) {
        int s = csr_src[start + j];
        float w = csr_w[start + j];
        a0 += w * h[(size_t)s * 3 + 0];
        a1 += w * h[(size_t)s * 3 + 1];
        a2 += w * h[(size_t)s * 3 + 2];
    }
    float di = dinv[node];
    float o0 = di * a0 + di * di * h[(size_t)node * 3 + 0];
    float o1 = di * a1 + di * di * h[(size_t)node * 3 + 1];
    float o2 = di * a2 + di * di * h[(size_t)node * 3 + 2];
    if (flags) {
        o0 = elu1(o0 + bias[0]); o1 = elu1(o1 + bias[1]); o2 = elu1(o2 + bias[2]);
    }
    out[(size_t)node * 3 + 0] = o0;
    out[(size_t)node * 3 + 1] = o1;
    out[(size_t)node * 3 + 2] = o2;
}

// ---- W pre-pack to MFMA fragment order (hi/lo bf16 pairs) ----
__global__ void k_wpack(const float* __restrict__ W, unsigned* __restrict__ Phi,
                        unsigned* __restrict__ Plo, int K, int BN) {
    int t = blockIdx.x * 256 + threadIdx.x;
    int NT = BN / 16;
    int total = (K / 32) * NT * 64;
    if (t >= total) return;
    int lane = t & 63;
    int rest = t >> 6;
    int ct = rest % NT;
    int s = rest / NT;
    int col = ct * 16 + (lane & 15);
    int g = lane >> 4;
    int k0 = s * 32;
    float e[8];
#pragma unroll
    for (int j = 0; j < 4; j++) {
        e[j]     = W[(size_t)(k0 + 4 * g + j) * BN + col];
        e[4 + j] = W[(size_t)(k0 + 16 + 4 * g + j) * BN + col];
    }
#pragma unroll
    for (int j = 0; j < 4; j++) {
        unsigned h0 = f2bf(e[2 * j]), h1 = f2bf(e[2 * j + 1]);
        Phi[(size_t)t * 4 + j] = h0 | (h1 << 16);
        unsigned l0 = f2bf(e[2 * j] - bf2f(h0));
        unsigned l1 = f2bf(e[2 * j + 1] - bf2f(h1));
        Plo[(size_t)t * 4 + j] = l0 | (l1 << 16);
    }
}

// ---- split-bf16 MFMA GEMM: C = A[N,K] @ W[K,BN] (+add[idx], +bias, elu) ----
template <int BN>
__global__ __launch_bounds__(256) void k_gmfma(
        const float* __restrict__ A, const unsigned* __restrict__ Phi,
        const unsigned* __restrict__ Plo, const float* __restrict__ bias,
        const float* __restrict__ add, const int* __restrict__ addidx,
        float* __restrict__ C, int N, int K, int flags) {
    constexpr int NT = BN / 16;
    const int t = threadIdx.x;
    const int w = t >> 6, l = t & 63;
    const int l15 = l & 15, g = l >> 4;
    const int row0 = blockIdx.x * 64 + w * 16;
    int arow = row0 + l15; arow = arow < N ? arow : N - 1;
    const float* ap = A + (size_t)arow * K;

    f32x4 acc[NT];
#pragma unroll
    for (int ct = 0; ct < NT; ct++) acc[ct] = (f32x4){0.f, 0.f, 0.f, 0.f};

    const int nk = K / 32;
    for (int s = 0; s < nk; ++s) {
        const int k0 = s * 32;
        const float4 a0 = *reinterpret_cast<const float4*>(ap + k0 + 4 * g);
        const float4 a1 = *reinterpret_cast<const float4*>(ap + k0 + 16 + 4 * g);
        float e[8] = {a0.x, a0.y, a0.z, a0.w, a1.x, a1.y, a1.z, a1.w};
        U8 ahi, alo;
#pragma unroll
        for (int j = 0; j < 4; j++) {
            unsigned h0 = f2bf(e[2 * j]), h1 = f2bf(e[2 * j + 1]);
            ahi.u[j] = h0 | (h1 << 16);
            unsigned l0 = f2bf(e[2 * j] - bf2f(h0));
            unsigned l1 = f2bf(e[2 * j + 1] - bf2f(h1));
            alo.u[j] = l0 | (l1 << 16);
        }
        const unsigned* pb = Phi + ((size_t)s * NT * 64 + l) * 4;
        const unsigned* pl = Plo + ((size_t)s * NT * 64 + l) * 4;
#pragma unroll
        for (int ct = 0; ct < NT; ct++) {
            U8 wh = *reinterpret_cast<const U8*>(pb + (size_t)ct * 256);
            U8 wl = *reinterpret_cast<const U8*>(pl + (size_t)ct * 256);
            acc[ct] = __builtin_amdgcn_mfma_f32_16x16x32_bf16(ahi.v, wh.v, acc[ct], 0, 0, 0);
            acc[ct] = __builtin_amdgcn_mfma_f32_16x16x32_bf16(ahi.v, wl.v, acc[ct], 0, 0, 0);
            acc[ct] = __builtin_amdgcn_mfma_f32_16x16x32_bf16(alo.v, wh.v, acc[ct], 0, 0, 0);
        }
    }
#pragma unroll
    for (int r = 0; r < 4; r++) {
        int row = row0 + 4 * g + r;
        if (row >= N) continue;
        int gi = (add != nullptr) ? addidx[row] : 0;
#pragma unroll
        for (int ct = 0; ct < NT; ct++) {
            int col = ct * 16 + l15;
            float o = acc[ct][r];
            if (add != nullptr) o += add[(size_t)gi * BN + col];
            if (flags) o = elu1(o + bias[col]);
            C[(size_t)row * BN + col] = o;
        }
    }
}

// ---------------- simple fc (small shapes: K=3 layer, local C=1024 stack) ----
template <int M, int RPT>
__global__ __launch_bounds__(256) void k_fc(
        const float* __restrict__ A, const float* __restrict__ W,
        const float* __restrict__ bias, const float* __restrict__ add,
        const int* __restrict__ addidx, float* __restrict__ C,
        int N, int K, int flags) {
    constexpr int TX = M / 4;
    constexpr int TY = 256 / TX;
    constexpr int RB = TY * RPT;
    int tx = threadIdx.x % TX;
    int ty = threadIdx.x / TX;
    int row0 = blockIdx.x * RB + ty * RPT;
    float4 acc[RPT];
#pragma unroll
    for (int r = 0; r < RPT; r++) acc[r] = make_float4(0.f, 0.f, 0.f, 0.f);
    for (int k = 0; k < K; k++) {
        float4 w = *reinterpret_cast<const float4*>(&W[(size_t)k * M + tx * 4]);
#pragma unroll
        for (int r = 0; r < RPT; r++) {
            int row = row0 + r;
            row = row < N ? row : N - 1;
            float a = A[(size_t)row * K + k];
            acc[r].x += a * w.x; acc[r].y += a * w.y;
            acc[r].z += a * w.z; acc[r].w += a * w.w;
        }
    }
    if (add != nullptr) {
#pragma unroll
        for (int r = 0; r < RPT; r++) {
            int row = row0 + r;
            if (row < N) {
                int g = addidx[row];
                const float4 v = *reinterpret_cast<const float4*>(&add[(size_t)g * M + tx * 4]);
                acc[r].x += v.x; acc[r].y += v.y; acc[r].z += v.z; acc[r].w += v.w;
            }
        }
    }
    __syncthreads();
    float4 b = make_float4(0.f, 0.f, 0.f, 0.f);
    if (flags) b = *reinterpret_cast<const float4*>(&bias[tx * 4]);
#pragma unroll
    for (int r = 0; r < RPT; r++) {
        int row = row0 + r;
        if (row >= N) break;
        float4 o = acc[r];
        o.x += b.x; o.y += b.y; o.z += b.z; o.w += b.w;
        if (flags) { o.x = elu1(o.x); o.y = elu1(o.y); o.z = elu1(o.z); o.w = elu1(o.w); }
        *reinterpret_cast<float4*>(&C[(size_t)row * M + tx * 4]) = o;
    }
}

// M = 3 (W: K x 3)
__global__ void k_fc3(const float* __restrict__ A, const float* __restrict__ W,
                      const float* __restrict__ b, float* __restrict__ C,
                      int n, int K, int flags) {
    int r = blockIdx.x * 256 + threadIdx.x;
    if (r >= n) return;
    float a0 = 0.f, a1 = 0.f, a2 = 0.f;
    for (int k = 0; k < K; k++) {
        float a = A[(size_t)r * K + k];
        a0 += a * W[k * 3 + 0]; a1 += a * W[k * 3 + 1]; a2 += a * W[k * 3 + 2];
    }
    if (flags) {
        a0 = elu1(a0 + b[0]); a1 = elu1(a1 + b[1]); a2 = elu1(a2 + b[2]);
    }
    C[(size_t)r * 3 + 0] = a0;
    C[(size_t)r * 3 + 1] = a1;
    C[(size_t)r * 3 + 2] = a2;
}

// ---------------- instance norm (in-place apply) ----------------
__global__ void k_instats(const float* __restrict__ h, float* __restrict__ sum,
                          float* __restrict__ sumsq, int n) {
    int c = threadIdx.x;
    int r0 = blockIdx.x * 128;
    int r1 = r0 + 128 < n ? r0 + 128 : n;
    float s = 0.f, q = 0.f;
    for (int r = r0; r < r1; r++) {
        float v = h[(size_t)r * 256 + c];
        s += v; q += v * v;
    }
    atomicAdd(&sum[c], s);
    atomicAdd(&sumsq[c], q);
}

__global__ void k_infinal(const float* __restrict__ sum, const float* __restrict__ sumsq,
                          float* __restrict__ mu, float* __restrict__ rstd, int n) {
    int c = threadIdx.x;
    float m = sum[c] / (float)n;
    float var = sumsq[c] / (float)n - m * m;
    mu[c] = m;
    rstd[c] = rsqrtf(var + 1e-5f);
}

__global__ void k_innorm(float* __restrict__ h, const float* __restrict__ mu,
                         const float* __restrict__ rstd, int n) {
    int gid = blockIdx.x * 256 + threadIdx.x;
    int node = gid >> 6;
    if (node >= n) return;
    int c = (gid & 63) * 4;
    float4 v = *reinterpret_cast<const float4*>(&h[(size_t)node * 256 + c]);
    float4 m = *reinterpret_cast<const float4*>(&mu[c]);
    float4 rs = *reinterpret_cast<const float4*>(&rstd[c]);
    v.x = (v.x - m.x) * rs.x; v.y = (v.y - m.y) * rs.y;
    v.z = (v.z - m.z) * rs.z; v.w = (v.w - m.w) * rs.w;
    *reinterpret_cast<float4*>(&h[(size_t)node * 256 + c]) = v;
}

// ---------------- cluster pooling (CSR gather, no atomics) ----------------
__global__ __launch_bounds__(256) void k_poolavg(
        const float* __restrict__ y, const int* __restrict__ crowptr,
        const int* __restrict__ cdeg, const int* __restrict__ cnodes,
        float* __restrict__ px) {
    int cl = blockIdx.x;
    int c  = threadIdx.x;
    int start = crowptr[cl];
    int cnt = cdeg[cl];
    float acc = 0.f;
    for (int j = 0; j < cnt; j++) {
        int node = cnodes[start + j];
        acc += y[(size_t)node * 256 + c];
    }
    px[(size_t)cl * 256 + c] = acc / fmaxf((float)cnt, 1.0f);
}

__global__ void k_pooledges(const int* __restrict__ src, const int* __restrict__ dst,
                            const int* __restrict__ bc, unsigned char* __restrict__ bmT, int E) {
    int e = blockIdx.x * 256 + threadIdx.x;
    if (e >= E) return;
    int ps = bc[src[e]];
    int pd = bc[dst[e]];
    bmT[(size_t)pd * NCLUST + ps] = 1;
}

__global__ __launch_bounds__(256) void k_pooldeg(
        const unsigned char* __restrict__ bmT, float* __restrict__ dinvp) {
    int d = blockIdx.x;
    int t = threadIdx.x;
    const unsigned int v = reinterpret_cast<const unsigned int*>(bmT + (size_t)d * NCLUST)[t];
    int s = (v & 0xff) + ((v >> 8) & 0xff) + ((v >> 16) & 0xff) + ((v >> 24) & 0xff);
    if (t == (d >> 2)) s -= (v >> ((d & 3) * 8)) & 0xff;
    __shared__ int red[256];
    red[t] = s; __syncthreads();
    for (int o = 128; o > 0; o >>= 1) {
        if (t < o) red[t] += red[t + o];
        __syncthreads();
    }
    if (t == 0) dinvp[d] = rsqrtf((float)red[0] + 1.0f);
}

// pooled propagation: out[d][f] = elu(di*sum_s w_ds*h[s][f] + di^2*h[d][f] + b[f])
// 1024 threads = SG s-groups x F lanes; predicated accumulate + LDS reduce.
template <int F>
__global__ __launch_bounds__(1024) void k_proppool2(
        const float* __restrict__ h, const float* __restrict__ dinvp,
        const unsigned char* __restrict__ bmT, const float* __restrict__ bias,
        float* __restrict__ out) {
    constexpr int SG = 1024 / F;
    const int d = blockIdx.x;
    const int t = threadIdx.x;
    const int f = t & (F - 1);
    const int sg = t / F;
    const unsigned char* bmrow = bmT + (size_t)d * NCLUST;
    float acc = 0.f;
#pragma unroll 4
    for (int s = sg; s < NCLUST; s += SG) {
        float m = (s != d) ? (float)bmrow[s] : 0.f;
        acc += m * dinvp[s] * h[(size_t)s * F + f];
    }
    __shared__ float red[1024];
    red[t] = acc; __syncthreads();
#pragma unroll
    for (int o = SG / 2; o > 0; o >>= 1) {
        if (sg < o) red[t] += red[t + o * F];
        __syncthreads();
    }
    if (sg == 0) {
        float di = dinvp[d];
        float r = di * red[f] + di * di * h[(size_t)d * F + f] + bias[f];
        out[(size_t)d * F + f] = elu1(r);
    }
}

// ---------------------------------------------------------------------------
extern "C" void kernel_launch(void* const* d_in, const int* in_sizes, int n_in,
                              void* d_out, int out_size, void* d_ws, size_t ws_size,
                              hipStream_t stream) {
    const float* x       = (const float*)d_in[0];
    const int*   adj     = (const int*)d_in[1];
    const int*   inb     = (const int*)d_in[3];
    const int*   cluster = (const int*)d_in[4];
    const float* WG1  = (const float*)d_in[5];   const float* bG1  = (const float*)d_in[6];
    const float* WfG1 = (const float*)d_in[7];   const float* bfG1 = (const float*)d_in[8];
    const float* WG2  = (const float*)d_in[9];   const float* bG2  = (const float*)d_in[10];
    const float* WfG2 = (const float*)d_in[11];  const float* bfG2 = (const float*)d_in[12];
    const float* WL1  = (const float*)d_in[13];  const float* bL1  = (const float*)d_in[14];
    const float* WfL1 = (const float*)d_in[15];  const float* bfL1 = (const float*)d_in[16];
    const float* WL2  = (const float*)d_in[17];  const float* bL2  = (const float*)d_in[18];
    const float* WfL2 = (const float*)d_in[19];  const float* bfL2 = (const float*)d_in[20];
    const float* WO1  = (const float*)d_in[21];  const float* bO1  = (const float*)d_in[22];
    const float* WfO1 = (const float*)d_in[23];  const float* bfO1 = (const float*)d_in[24];
    const float* WO2  = (const float*)d_in[25];  const float* bO2  = (const float*)d_in[26];
    const float* WfO2 = (const float*)d_in[27];  const float* bfO2 = (const float*)d_in[28];
    const float* WO3  = (const float*)d_in[29];  const float* bO3  = (const float*)d_in[30];
    const float* WfO3 = (const float*)d_in[31];  const float* bfO3 = (const float*)d_in[32];
    float* out = (float*)d_out;

    const int n = in_sizes[0] / 3;       // 100000
    const int E = in_sizes[1] / 2;       // 1600000
    const int* src = adj;
    const int* dst = adj + E;

    // ---- workspace carve (~174 MB) ----
    char* ws = (char*)d_ws;
    size_t off = 0;
    auto alloc = [&](size_t bytes) -> void* {
        void* p = ws + off;
        off = (off + bytes + 255) & ~(size_t)255;
        return p;
    };
    int*   deg     = (int*)alloc((size_t)n * 4);     // zero span 1 start
    int*   fill    = (int*)alloc((size_t)n * 4);
    int*   cdeg    = (int*)alloc(NCLUST * 4);
    int*   cfill   = (int*)alloc(NCLUST * 4);
    int*   rowptr  = (int*)alloc((size_t)n * 4);     // zero span 1 end (exclusive)
    int*   crowptr = (int*)alloc(NCLUST * 4);
    int*   cnodes  = (int*)alloc((size_t)n * 4);
    int*   bcarr   = (int*)alloc((size_t)n * 4);
    float* dinv    = (float*)alloc((size_t)n * 4);
    int*   bsum    = (int*)alloc(512);
    int*   csr_src = (int*)alloc((size_t)E * 4);
    float* csr_w   = (float*)alloc((size_t)E * 4);
    float* X       = (float*)alloc((size_t)n * 256 * 4);
    float* B       = (float*)alloc((size_t)n * 128 * 4);
    float* insum   = (float*)alloc(256 * 4);         // zero span 2 start
    float* insumsq = (float*)alloc(256 * 4);
    float* px      = (float*)alloc((size_t)NCLUST * 256 * 4);
    unsigned char* bmT = (unsigned char*)alloc((size_t)NCLUST * NCLUST);
    float* mu      = (float*)alloc(256 * 4);         // zero span 2 end (exclusive)
    float* rstd    = (float*)alloc(256 * 4);
    float* dinvp   = (float*)alloc(NCLUST * 4);
    float* lA      = (float*)alloc((size_t)NCLUST * 128 * 4);
    float* lB      = (float*)alloc((size_t)NCLUST * 128 * 4);
    // packed weights (u32 count = K*BN/2 each)
    unsigned* pfG1h = (unsigned*)alloc(2048 * 4);   unsigned* pfG1l = (unsigned*)alloc(2048 * 4);
    unsigned* pG2h  = (unsigned*)alloc(8192 * 4);   unsigned* pG2l  = (unsigned*)alloc(8192 * 4);
    unsigned* pfG2h = (unsigned*)alloc(32768 * 4);  unsigned* pfG2l = (unsigned*)alloc(32768 * 4);
    unsigned* pO1h  = (unsigned*)alloc(16384 * 4);  unsigned* pO1l  = (unsigned*)alloc(16384 * 4);
    unsigned* pfO1h = (unsigned*)alloc(8192 * 4);   unsigned* pfO1l = (unsigned*)alloc(8192 * 4);
    unsigned* pO2h  = (unsigned*)alloc(2048 * 4);   unsigned* pO2l  = (unsigned*)alloc(2048 * 4);
    unsigned* pfO2h = (unsigned*)alloc(512 * 4);    unsigned* pfO2l = (unsigned*)alloc(512 * 4);
    (void)ws_size; (void)n_in; (void)out_size;

    float* B0 = B;
    float* B1 = B + (size_t)n * 64;

    auto cdiv = [](int a, int b) { return (a + b - 1) / b; };
    const int EB = cdiv(E, 256);
    const int GB = cdiv(n, 64);          // gmfma grid

    // ---- zero scratch ----
    int nz1 = (int)(((char*)rowptr - (char*)deg) / 16);
    int nz2 = (int)(((char*)mu - (char*)insum) / 16);
    k_zero<<<cdiv(nz1, 256), 256, 0, stream>>>((int4*)deg, nz1);
    k_zero<<<cdiv(nz2, 256), 256, 0, stream>>>((int4*)insum, nz2);

    // ---- pack weights to MFMA fragment order ----
    k_wpack<<<cdiv(512, 256), 256, 0, stream>>>(WfG1, pfG1h, pfG1l, 64, 64);
    k_wpack<<<cdiv(2048, 256), 256, 0, stream>>>(WG2, pG2h, pG2l, 64, 256);
    k_wpack<<<cdiv(8192, 256), 256, 0, stream>>>(WfG2, pfG2h, pfG2l, 256, 256);
    k_wpack<<<cdiv(4096, 256), 256, 0, stream>>>(WO1, pO1h, pO1l, 256, 128);
    k_wpack<<<cdiv(2048, 256), 256, 0, stream>>>(WfO1, pfO1h, pfO1l, 128, 128);
    k_wpack<<<cdiv(512, 256), 256, 0, stream>>>(WO2, pO2h, pO2l, 128, 32);
    k_wpack<<<cdiv(128, 256), 256, 0, stream>>>(WfO2, pfO2h, pfO2l, 32, 32);

    // ---- CSR build (edges) ----
    k_hist<<<EB, 256, 0, stream>>>(dst, deg, E);
    int nb = cdiv(n, 1024);
    k_scan_block<<<nb, 256, 0, stream>>>(deg, rowptr, bsum, n);
    k_scan_tops<<<1, 128, 0, stream>>>(bsum, nb);
    k_scan_add<<<cdiv(n, 256), 256, 0, stream>>>(rowptr, bsum, n);
    k_dinv_bc<<<cdiv(n, 256), 256, 0, stream>>>(deg, cluster, inb, dinv, bcarr, n);
    k_fill<<<EB, 256, 0, stream>>>(src, dst, dinv, rowptr, fill, csr_src, csr_w, E);

    // ---- CSR build (cluster member lists) ----
    k_hist<<<cdiv(n, 256), 256, 0, stream>>>(bcarr, cdeg, n);
    k_scan_block<<<1, 256, 0, stream>>>(cdeg, crowptr, bsum, NCLUST);
    k_cfill<<<cdiv(n, 256), 256, 0, stream>>>(bcarr, crowptr, cfill, cnodes, n);

    // ---- global GCN stack ----
    k_prop3<<<cdiv(n, 256), 256, 0, stream>>>(x, dinv, rowptr, deg, csr_src, csr_w,
                                              nullptr, B0, n, 0);
    k_fc<64, 2><<<cdiv(n, 32), 256, 0, stream>>>(B0, WG1, bG1, nullptr, nullptr, B1, n, 3, 1);
    // h2 = elu(h1 @ WfG1 + bfG1)  (B1 in-place)
    k_gmfma<64><<<GB, 256, 0, stream>>>(B1, pfG1h, pfG1l, bfG1, nullptr, nullptr, B1, n, 64, 1);
    k_prop4<<<cdiv(n * 16, 256), 256, 0, stream>>>(B1, dinv, rowptr, deg, csr_src, csr_w,
                                                   nullptr, B0, n, 64, 4, 0);
    // h3 = elu(p64 @ WG2 + bG2)  (X)
    k_gmfma<256><<<GB, 256, 0, stream>>>(B0, pG2h, pG2l, bG2, nullptr, nullptr, X, n, 64, 1);
    // h4 = elu(h3 @ WfG2 + bfG2)  (X in-place)
    k_gmfma<256><<<GB, 256, 0, stream>>>(X, pfG2h, pfG2l, bfG2, nullptr, nullptr, X, n, 256, 1);

    // ---- instance norm (in place) -> y = X ----
    k_instats<<<cdiv(n, 128), 256, 0, stream>>>(X, insum, insumsq, n);
    k_infinal<<<1, 256, 0, stream>>>(insum, insumsq, mu, rstd, n);
    k_innorm<<<cdiv(n * 64, 256), 256, 0, stream>>>(X, mu, rstd, n);

    // ---- cluster pooling (gather) ----
    k_poolavg<<<NCLUST, 256, 0, stream>>>(X, crowptr, cdeg, cnodes, px);
    k_pooledges<<<EB, 256, 0, stream>>>(src, dst, bcarr, bmT, E);
    k_pooldeg<<<NCLUST, 256, 0, stream>>>(bmT, dinvp);

    // ---- local (pooled) GCN stack ----
    k_fc<128, 2><<<cdiv(NCLUST, 16), 256, 0, stream>>>(px, WL1, nullptr, nullptr, nullptr,
                                                       lA, NCLUST, 256, 0);
    k_proppool2<128><<<NCLUST, 1024, 0, stream>>>(lA, dinvp, bmT, bL1, lB);
    k_fc<128, 2><<<cdiv(NCLUST, 16), 256, 0, stream>>>(lB, WfL1, bfL1, nullptr, nullptr,
                                                       lA, NCLUST, 128, 1);
    k_fc<64, 2><<<cdiv(NCLUST, 32), 256, 0, stream>>>(lA, WL2, nullptr, nullptr, nullptr,
                                                      lB, NCLUST, 128, 0);
    k_proppool2<64><<<NCLUST, 1024, 0, stream>>>(lB, dinvp, bmT, bL2, lA);
    k_fc<64, 2><<<cdiv(NCLUST, 32), 256, 0, stream>>>(lA, WfL2, bfL2, nullptr, nullptr,
                                                      lB, NCLUST, 64, 1);
    k_fc<128, 2><<<cdiv(NCLUST, 16), 256, 0, stream>>>(lB, WO1 + (size_t)256 * 128, nullptr,
                                                       nullptr, nullptr, lA, NCLUST, 64, 0);

    // ---- output GCN stack ----
    // t1 = y @ WO1[0:256,:] + compO[bc]  (B, N x 128)
    k_gmfma<128><<<GB, 256, 0, stream>>>(X, pO1h, pO1l, nullptr, lA, bcarr, B, n, 256, 0);
    k_prop4<<<cdiv(n * 32, 256), 256, 0, stream>>>(B, dinv, rowptr, deg, csr_src, csr_w,
                                                   bO1, X, n, 128, 5, 1);
    // o2 = elu(o1 @ WfO1 + bfO1)  (X in-place)
    k_gmfma<128><<<GB, 256, 0, stream>>>(X, pfO1h, pfO1l, bfO1, nullptr, nullptr, X, n, 128, 1);
    // t2 = o2 @ WO2  (B, N x 32)
    k_gmfma<32><<<GB, 256, 0, stream>>>(X, pO2h, pO2l, nullptr, nullptr, nullptr, B, n, 128, 0);
    k_prop4<<<cdiv(n * 8, 256), 256, 0, stream>>>(B, dinv, rowptr, deg, csr_src, csr_w,
                                                  bO2, X, n, 32, 3, 1);
    // o4 = elu(o3 @ WfO2 + bfO2)  (X in-place)
    k_gmfma<32><<<GB, 256, 0, stream>>>(X, pfO2h, pfO2l, bfO2, nullptr, nullptr, X, n, 32, 1);
    k_fc3<<<cdiv(n, 256), 256, 0, stream>>>(X, WO3, nullptr, B, n, 32, 0);
    k_prop3<<<cdiv(n, 256), 256, 0, stream>>>(B, dinv, rowptr, deg, csr_src, csr_w,
                                              bO3, X, n, 1);
    k_fc3<<<cdiv(n, 256), 256, 0, stream>>>(X, WfO3, bfO3, out, n, 3, 1);
}

// Round 11
// 1311.731 us; speedup vs baseline: 1.5593x; 1.0270x over previous
//
#include <hip/hip_runtime.h>

// ---------------------------------------------------------------------------
// GCN3D: 3x GCNConv + fc (global), instance-norm, cluster pool, 2x GCNConv
// (pooled 1024-cluster graph), gather-broadcast, 3x GCNConv + fc (out).
// N=100000 nodes, E=1600000 edges, C=1024 clusters.
// R3: atomic pooling -> cluster-CSR gather.
// R9: dense fc layers -> split-bf16 MFMA (fp32-equivalent via 3 MFMAs).
// R10: k_proppool2 (1024-thr, 8/16-way s-split).
// R11: k_gmfma2 -- 32 rows/wave (2 A-fragments, 6 MFMAs per W-fragment pair;
//   W L2 traffic halved). BN=256 splits cols 2-way across waves (barrier
//   before stores keeps in-place safe); BN<=128 blocks cover 128 rows.
// ---------------------------------------------------------------------------

#define NCLUST 1024

typedef short bf16x8 __attribute__((ext_vector_type(8)));
typedef float f32x4 __attribute__((ext_vector_type(4)));

__device__ __forceinline__ float elu1(float x) { return x > 0.f ? x : expm1f(x); }

__device__ __forceinline__ unsigned f2bf(float f) {
    union { float f; unsigned u; } c; c.f = f;
    unsigned u = c.u;
    return (u + 0x7fffu + ((u >> 16) & 1u)) >> 16;
}
__device__ __forceinline__ float bf2f(unsigned h) {
    union { unsigned u; float f; } c; c.u = h << 16; return c.f;
}

union U8 { unsigned u[4]; bf16x8 v; };

__global__ void k_zero(int4* __restrict__ p, int n4) {
    int i = blockIdx.x * 256 + threadIdx.x;
    if (i < n4) p[i] = make_int4(0, 0, 0, 0);
}

// ---------------- CSR build (shared by edge graph and cluster lists) --------
__global__ void k_hist(const int* __restrict__ key, int* __restrict__ deg, int E) {
    int e = blockIdx.x * 256 + threadIdx.x;
    if (e < E) atomicAdd(&deg[key[e]], 1);
}

__global__ void k_scan_block(const int* __restrict__ deg, int* __restrict__ rowptr,
                             int* __restrict__ bsum, int n) {
    __shared__ int lds[256];
    int tid = threadIdx.x;
    int base = blockIdx.x * 1024 + tid * 4;
    int v0 = base + 0 < n ? deg[base + 0] : 0;
    int v1 = base + 1 < n ? deg[base + 1] : 0;
    int v2 = base + 2 < n ? deg[base + 2] : 0;
    int v3 = base + 3 < n ? deg[base + 3] : 0;
    int tsum = v0 + v1 + v2 + v3;
    lds[tid] = tsum; __syncthreads();
    for (int off = 1; off < 256; off <<= 1) {
        int t = (tid >= off) ? lds[tid - off] : 0;
        __syncthreads();
        lds[tid] += t;
        __syncthreads();
    }
    int run = lds[tid] - tsum;
    if (base + 0 < n) rowptr[base + 0] = run; run += v0;
    if (base + 1 < n) rowptr[base + 1] = run; run += v1;
    if (base + 2 < n) rowptr[base + 2] = run; run += v2;
    if (base + 3 < n) rowptr[base + 3] = run;
    if (tid == 255) bsum[blockIdx.x] = lds[255];
}

__global__ void k_scan_tops(int* __restrict__ bsum, int nb) {
    __shared__ int lds[128];
    int tid = threadIdx.x;
    int v = tid < nb ? bsum[tid] : 0;
    lds[tid] = v; __syncthreads();
    for (int off = 1; off < 128; off <<= 1) {
        int t = (tid >= off) ? lds[tid - off] : 0;
        __syncthreads();
        lds[tid] += t;
        __syncthreads();
    }
    if (tid < nb) bsum[tid] = lds[tid] - v;
}

__global__ void k_scan_add(int* __restrict__ rowptr, const int* __restrict__ bsum, int n) {
    int i = blockIdx.x * 256 + threadIdx.x;
    if (i < n) rowptr[i] += bsum[i >> 10];
}

__global__ void k_dinv_bc(const int* __restrict__ deg, const int* __restrict__ cluster,
                          const int* __restrict__ inb, float* __restrict__ dinv,
                          int* __restrict__ bc, int n) {
    int i = blockIdx.x * 256 + threadIdx.x;
    if (i < n) {
        dinv[i] = rsqrtf((float)deg[i] + 1.0f);
        bc[i] = cluster[i] + inb[i] * NCLUST;
    }
}

__global__ void k_fill(const int* __restrict__ src, const int* __restrict__ dst,
                       const float* __restrict__ dinv, const int* __restrict__ rowptr,
                       int* __restrict__ fill, int* __restrict__ csr_src,
                       float* __restrict__ csr_w, int E) {
    int e = blockIdx.x * 256 + threadIdx.x;
    if (e >= E) return;
    int d = dst[e];
    int pos = rowptr[d] + atomicAdd(&fill[d], 1);
    int s = src[e];
    csr_src[pos] = s;
    csr_w[pos] = dinv[s];
}

__global__ void k_cfill(const int* __restrict__ bc, const int* __restrict__ crowptr,
                        int* __restrict__ cfill, int* __restrict__ cnodes, int n) {
    int i = blockIdx.x * 256 + threadIdx.x;
    if (i >= n) return;
    int c = bc[i];
    int pos = crowptr[c] + atomicAdd(&cfill[c], 1);
    cnodes[pos] = i;
}

// ---------------- GCN propagation: out = S*h (+bias, elu) ----------------
__global__ __launch_bounds__(256) void k_prop4(
        const float* __restrict__ h, const float* __restrict__ dinv,
        const int* __restrict__ rowptr, const int* __restrict__ deg,
        const int* __restrict__ csr_src, const float* __restrict__ csr_w,
        const float* __restrict__ bias, float* __restrict__ out,
        int n, int F, int lshift, int flags) {
    int gid = blockIdx.x * 256 + threadIdx.x;
    int node = gid >> lshift;
    if (node >= n) return;
    int fi = (gid & ((1 << lshift) - 1)) * 4;
    int start = rowptr[node];
    int cnt = deg[node];
    float ax = 0.f, ay = 0.f, az = 0.f, aw = 0.f;
    for (int j = 0; j < cnt; j++) {
        int s = csr_src[start + j];
        float w = csr_w[start + j];
        const float4 v = *reinterpret_cast<const float4*>(&h[(size_t)s * F + fi]);
        ax += w * v.x; ay += w * v.y; az += w * v.z; aw += w * v.w;
    }
    float di = dinv[node];
    const float4 sv = *reinterpret_cast<const float4*>(&h[(size_t)node * F + fi]);
    float4 o;
    o.x = di * ax + di * di * sv.x;
    o.y = di * ay + di * di * sv.y;
    o.z = di * az + di * di * sv.z;
    o.w = di * aw + di * di * sv.w;
    if (flags) {
        const float4 b = *reinterpret_cast<const float4*>(&bias[fi]);
        o.x = elu1(o.x + b.x); o.y = elu1(o.y + b.y);
        o.z = elu1(o.z + b.z); o.w = elu1(o.w + b.w);
    }
    *reinterpret_cast<float4*>(&out[(size_t)node * F + fi]) = o;
}

__global__ void k_prop3(const float* __restrict__ h, const float* __restrict__ dinv,
                        const int* __restrict__ rowptr, const int* __restrict__ deg,
                        const int* __restrict__ csr_src, const float* __restrict__ csr_w,
                        const float* __restrict__ bias, float* __restrict__ out,
                        int n, int flags) {
    int node = blockIdx.x * 256 + threadIdx.x;
    if (node >= n) return;
    int start = rowptr[node], cnt = deg[node];
    float a0 = 0.f, a1 = 0.f, a2 = 0.f;
    for (int j = 0; j < cnt; j++) {
        int s = csr_src[start + j];
        float w = csr_w[start + j];
        a0 += w * h[(size_t)s * 3 + 0];
        a1 += w * h[(size_t)s * 3 + 1];
        a2 += w * h[(size_t)s * 3 + 2];
    }
    float di = dinv[node];
    float o0 = di * a0 + di * di * h[(size_t)node * 3 + 0];
    float o1 = di * a1 + di * di * h[(size_t)node * 3 + 1];
    float o2 = di * a2 + di * di * h[(size_t)node * 3 + 2];
    if (flags) {
        o0 = elu1(o0 + bias[0]); o1 = elu1(o1 + bias[1]); o2 = elu1(o2 + bias[2]);
    }
    out[(size_t)node * 3 + 0] = o0;
    out[(size_t)node * 3 + 1] = o1;
    out[(size_t)node * 3 + 2] = o2;
}

// ---- W pre-pack to MFMA fragment order (hi/lo bf16 pairs) ----
__global__ void k_wpack(const float* __restrict__ W, unsigned* __restrict__ Phi,
                        unsigned* __restrict__ Plo, int K, int BN) {
    int t = blockIdx.x * 256 + threadIdx.x;
    int NT = BN / 16;
    int total = (K / 32) * NT * 64;
    if (t >= total) return;
    int lane = t & 63;
    int rest = t >> 6;
    int ct = rest % NT;
    int s = rest / NT;
    int col = ct * 16 + (lane & 15);
    int g = lane >> 4;
    int k0 = s * 32;
    float e[8];
#pragma unroll
    for (int j = 0; j < 4; j++) {
        e[j]     = W[(size_t)(k0 + 4 * g + j) * BN + col];
        e[4 + j] = W[(size_t)(k0 + 16 + 4 * g + j) * BN + col];
    }
#pragma unroll
    for (int j = 0; j < 4; j++) {
        unsigned h0 = f2bf(e[2 * j]), h1 = f2bf(e[2 * j + 1]);
        Phi[(size_t)t * 4 + j] = h0 | (h1 << 16);
        unsigned l0 = f2bf(e[2 * j] - bf2f(h0));
        unsigned l1 = f2bf(e[2 * j + 1] - bf2f(h1));
        Plo[(size_t)t * 4 + j] = l0 | (l1 << 16);
    }
}

// ---- split-bf16 MFMA GEMM, 32 rows/wave: C = A@W (+add[idx], +bias, elu) ---
// BN>128: 4 waves = 2 row-groups x 2 col-groups (block = 64 rows);
// BN<=128: 4 row-groups (block = 128 rows). Wave owns 2 row-fragments of 16;
// each W fragment pair feeds 6 MFMAs. __syncthreads before stores keeps the
// col-split in-place case race-free (all A reads complete first).
template <int BN>
__global__ __launch_bounds__(256) void k_gmfma(
        const float* __restrict__ A, const unsigned* __restrict__ Phi,
        const unsigned* __restrict__ Plo, const float* __restrict__ bias,
        const float* __restrict__ add, const int* __restrict__ addidx,
        float* __restrict__ C, int N, int K, int flags) {
    constexpr int NT = BN / 16;
    constexpr int WCOL = (BN > 128) ? 2 : 1;
    constexpr int NTW = NT / WCOL;          // col-tiles per wave
    constexpr int BR = 32 * (4 / WCOL);     // rows per block (64 or 128)
    const int t = threadIdx.x;
    const int w = t >> 6, l = t & 63;
    const int wr = w / WCOL, wc = w % WCOL;
    const int l15 = l & 15, g = l >> 4;
    const int row0 = blockIdx.x * BR + wr * 32;
    const int ctbase = wc * NTW;
    int ar0 = row0 + l15;      ar0 = ar0 < N ? ar0 : N - 1;
    int ar1 = row0 + 16 + l15; ar1 = ar1 < N ? ar1 : N - 1;
    const float* ap0 = A + (size_t)ar0 * K;
    const float* ap1 = A + (size_t)ar1 * K;

    f32x4 acc[2][NTW];
#pragma unroll
    for (int f = 0; f < 2; f++)
#pragma unroll
        for (int ct = 0; ct < NTW; ct++) acc[f][ct] = (f32x4){0.f, 0.f, 0.f, 0.f};

    const int nk = K / 32;
    for (int s = 0; s < nk; ++s) {
        const int k0 = s * 32;
        U8 ahi[2], alo[2];
#pragma unroll
        for (int f = 0; f < 2; f++) {
            const float* ap = f ? ap1 : ap0;
            const float4 a0 = *reinterpret_cast<const float4*>(ap + k0 + 4 * g);
            const float4 a1 = *reinterpret_cast<const float4*>(ap + k0 + 16 + 4 * g);
            float e[8] = {a0.x, a0.y, a0.z, a0.w, a1.x, a1.y, a1.z, a1.w};
#pragma unroll
            for (int j = 0; j < 4; j++) {
                unsigned h0 = f2bf(e[2 * j]), h1 = f2bf(e[2 * j + 1]);
                ahi[f].u[j] = h0 | (h1 << 16);
                unsigned l0 = f2bf(e[2 * j] - bf2f(h0));
                unsigned l1 = f2bf(e[2 * j + 1] - bf2f(h1));
                alo[f].u[j] = l0 | (l1 << 16);
            }
        }
        const unsigned* pb = Phi + ((size_t)(s * NT + ctbase) * 64 + l) * 4;
        const unsigned* pl = Plo + ((size_t)(s * NT + ctbase) * 64 + l) * 4;
#pragma unroll
        for (int ct = 0; ct < NTW; ct++) {
            U8 wh = *reinterpret_cast<const U8*>(pb + (size_t)ct * 256);
            U8 wl = *reinterpret_cast<const U8*>(pl + (size_t)ct * 256);
            acc[0][ct] = __builtin_amdgcn_mfma_f32_16x16x32_bf16(ahi[0].v, wh.v, acc[0][ct], 0, 0, 0);
            acc[0][ct] = __builtin_amdgcn_mfma_f32_16x16x32_bf16(ahi[0].v, wl.v, acc[0][ct], 0, 0, 0);
            acc[0][ct] = __builtin_amdgcn_mfma_f32_16x16x32_bf16(alo[0].v, wh.v, acc[0][ct], 0, 0, 0);
            acc[1][ct] = __builtin_amdgcn_mfma_f32_16x16x32_bf16(ahi[1].v, wh.v, acc[1][ct], 0, 0, 0);
            acc[1][ct] = __builtin_amdgcn_mfma_f32_16x16x32_bf16(ahi[1].v, wl.v, acc[1][ct], 0, 0, 0);
            acc[1][ct] = __builtin_amdgcn_mfma_f32_16x16x32_bf16(alo[1].v, wh.v, acc[1][ct], 0, 0, 0);
        }
    }
    __syncthreads();   // all A reads done before any store (in-place, col-split)
#pragma unroll
    for (int f = 0; f < 2; f++) {
#pragma unroll
        for (int r = 0; r < 4; r++) {
            int row = row0 + 16 * f + 4 * g + r;
            if (row >= N) continue;
            int gi = (add != nullptr) ? addidx[row] : 0;
#pragma unroll
            for (int ct = 0; ct < NTW; ct++) {
                int col = (ctbase + ct) * 16 + l15;
                float o = acc[f][ct][r];
                if (add != nullptr) o += add[(size_t)gi * BN + col];
                if (flags) o = elu1(o + bias[col]);
                C[(size_t)row * BN + col] = o;
            }
        }
    }
}

// ---------------- simple fc (small shapes: K=3 layer, local C=1024 stack) ----
template <int M, int RPT>
__global__ __launch_bounds__(256) void k_fc(
        const float* __restrict__ A, const float* __restrict__ W,
        const float* __restrict__ bias, const float* __restrict__ add,
        const int* __restrict__ addidx, float* __restrict__ C,
        int N, int K, int flags) {
    constexpr int TX = M / 4;
    constexpr int TY = 256 / TX;
    constexpr int RB = TY * RPT;
    int tx = threadIdx.x % TX;
    int ty = threadIdx.x / TX;
    int row0 = blockIdx.x * RB + ty * RPT;
    float4 acc[RPT];
#pragma unroll
    for (int r = 0; r < RPT; r++) acc[r] = make_float4(0.f, 0.f, 0.f, 0.f);
    for (int k = 0; k < K; k++) {
        float4 w = *reinterpret_cast<const float4*>(&W[(size_t)k * M + tx * 4]);
#pragma unroll
        for (int r = 0; r < RPT; r++) {
            int row = row0 + r;
            row = row < N ? row : N - 1;
            float a = A[(size_t)row * K + k];
            acc[r].x += a * w.x; acc[r].y += a * w.y;
            acc[r].z += a * w.z; acc[r].w += a * w.w;
        }
    }
    if (add != nullptr) {
#pragma unroll
        for (int r = 0; r < RPT; r++) {
            int row = row0 + r;
            if (row < N) {
                int g = addidx[row];
                const float4 v = *reinterpret_cast<const float4*>(&add[(size_t)g * M + tx * 4]);
                acc[r].x += v.x; acc[r].y += v.y; acc[r].z += v.z; acc[r].w += v.w;
            }
        }
    }
    __syncthreads();
    float4 b = make_float4(0.f, 0.f, 0.f, 0.f);
    if (flags) b = *reinterpret_cast<const float4*>(&bias[tx * 4]);
#pragma unroll
    for (int r = 0; r < RPT; r++) {
        int row = row0 + r;
        if (row >= N) break;
        float4 o = acc[r];
        o.x += b.x; o.y += b.y; o.z += b.z; o.w += b.w;
        if (flags) { o.x = elu1(o.x); o.y = elu1(o.y); o.z = elu1(o.z); o.w = elu1(o.w); }
        *reinterpret_cast<float4*>(&C[(size_t)row * M + tx * 4]) = o;
    }
}

// M = 3 (W: K x 3)
__global__ void k_fc3(const float* __restrict__ A, const float* __restrict__ W,
                      const float* __restrict__ b, float* __restrict__ C,
                      int n, int K, int flags) {
    int r = blockIdx.x * 256 + threadIdx.x;
    if (r >= n) return;
    float a0 = 0.f, a1 = 0.f, a2 = 0.f;
    for (int k = 0; k < K; k++) {
        float a = A[(size_t)r * K + k];
        a0 += a * W[k * 3 + 0]; a1 += a * W[k * 3 + 1]; a2 += a * W[k * 3 + 2];
    }
    if (flags) {
        a0 = elu1(a0 + b[0]); a1 = elu1(a1 + b[1]); a2 = elu1(a2 + b[2]);
    }
    C[(size_t)r * 3 + 0] = a0;
    C[(size_t)r * 3 + 1] = a1;
    C[(size_t)r * 3 + 2] = a2;
}

// ---------------- instance norm (in-place apply) ----------------
__global__ void k_instats(const float* __restrict__ h, float* __restrict__ sum,
                          float* __restrict__ sumsq, int n) {
    int c = threadIdx.x;
    int r0 = blockIdx.x * 128;
    int r1 = r0 + 128 < n ? r0 + 128 : n;
    float s = 0.f, q = 0.f;
    for (int r = r0; r < r1; r++) {
        float v = h[(size_t)r * 256 + c];
        s += v; q += v * v;
    }
    atomicAdd(&sum[c], s);
    atomicAdd(&sumsq[c], q);
}

__global__ void k_infinal(const float* __restrict__ sum, const float* __restrict__ sumsq,
                          float* __restrict__ mu, float* __restrict__ rstd, int n) {
    int c = threadIdx.x;
    float m = sum[c] / (float)n;
    float var = sumsq[c] / (float)n - m * m;
    mu[c] = m;
    rstd[c] = rsqrtf(var + 1e-5f);
}

__global__ void k_innorm(float* __restrict__ h, const float* __restrict__ mu,
                         const float* __restrict__ rstd, int n) {
    int gid = blockIdx.x * 256 + threadIdx.x;
    int node = gid >> 6;
    if (node >= n) return;
    int c = (gid & 63) * 4;
    float4 v = *reinterpret_cast<const float4*>(&h[(size_t)node * 256 + c]);
    float4 m = *reinterpret_cast<const float4*>(&mu[c]);
    float4 rs = *reinterpret_cast<const float4*>(&rstd[c]);
    v.x = (v.x - m.x) * rs.x; v.y = (v.y - m.y) * rs.y;
    v.z = (v.z - m.z) * rs.z; v.w = (v.w - m.w) * rs.w;
    *reinterpret_cast<float4*>(&h[(size_t)node * 256 + c]) = v;
}

// ---------------- cluster pooling (CSR gather, no atomics) ----------------
__global__ __launch_bounds__(256) void k_poolavg(
        const float* __restrict__ y, const int* __restrict__ crowptr,
        const int* __restrict__ cdeg, const int* __restrict__ cnodes,
        float* __restrict__ px) {
    int cl = blockIdx.x;
    int c  = threadIdx.x;
    int start = crowptr[cl];
    int cnt = cdeg[cl];
    float acc = 0.f;
    for (int j = 0; j < cnt; j++) {
        int node = cnodes[start + j];
        acc += y[(size_t)node * 256 + c];
    }
    px[(size_t)cl * 256 + c] = acc / fmaxf((float)cnt, 1.0f);
}

__global__ void k_pooledges(const int* __restrict__ src, const int* __restrict__ dst,
                            const int* __restrict__ bc, unsigned char* __restrict__ bmT, int E) {
    int e = blockIdx.x * 256 + threadIdx.x;
    if (e >= E) return;
    int ps = bc[src[e]];
    int pd = bc[dst[e]];
    bmT[(size_t)pd * NCLUST + ps] = 1;
}

__global__ __launch_bounds__(256) void k_pooldeg(
        const unsigned char* __restrict__ bmT, float* __restrict__ dinvp) {
    int d = blockIdx.x;
    int t = threadIdx.x;
    const unsigned int v = reinterpret_cast<const unsigned int*>(bmT + (size_t)d * NCLUST)[t];
    int s = (v & 0xff) + ((v >> 8) & 0xff) + ((v >> 16) & 0xff) + ((v >> 24) & 0xff);
    if (t == (d >> 2)) s -= (v >> ((d & 3) * 8)) & 0xff;
    __shared__ int red[256];
    red[t] = s; __syncthreads();
    for (int o = 128; o > 0; o >>= 1) {
        if (t < o) red[t] += red[t + o];
        __syncthreads();
    }
    if (t == 0) dinvp[d] = rsqrtf((float)red[0] + 1.0f);
}

// pooled propagation: 1024 threads = SG s-groups x F lanes.
template <int F>
__global__ __launch_bounds__(1024) void k_proppool2(
        const float* __restrict__ h, const float* __restrict__ dinvp,
        const unsigned char* __restrict__ bmT, const float* __restrict__ bias,
        float* __restrict__ out) {
    constexpr int SG = 1024 / F;
    const int d = blockIdx.x;
    const int t = threadIdx.x;
    const int f = t & (F - 1);
    const int sg = t / F;
    const unsigned char* bmrow = bmT + (size_t)d * NCLUST;
    float acc = 0.f;
#pragma unroll 4
    for (int s = sg; s < NCLUST; s += SG) {
        float m = (s != d) ? (float)bmrow[s] : 0.f;
        acc += m * dinvp[s] * h[(size_t)s * F + f];
    }
    __shared__ float red[1024];
    red[t] = acc; __syncthreads();
#pragma unroll
    for (int o = SG / 2; o > 0; o >>= 1) {
        if (sg < o) red[t] += red[t + o * F];
        __syncthreads();
    }
    if (sg == 0) {
        float di = dinvp[d];
        float r = di * red[f] + di * di * h[(size_t)d * F + f] + bias[f];
        out[(size_t)d * F + f] = elu1(r);
    }
}

// ---------------------------------------------------------------------------
extern "C" void kernel_launch(void* const* d_in, const int* in_sizes, int n_in,
                              void* d_out, int out_size, void* d_ws, size_t ws_size,
                              hipStream_t stream) {
    const float* x       = (const float*)d_in[0];
    const int*   adj     = (const int*)d_in[1];
    const int*   inb     = (const int*)d_in[3];
    const int*   cluster = (const int*)d_in[4];
    const float* WG1  = (const float*)d_in[5];   const float* bG1  = (const float*)d_in[6];
    const float* WfG1 = (const float*)d_in[7];   const float* bfG1 = (const float*)d_in[8];
    const float* WG2  = (const float*)d_in[9];   const float* bG2  = (const float*)d_in[10];
    const float* WfG2 = (const float*)d_in[11];  const float* bfG2 = (const float*)d_in[12];
    const float* WL1  = (const float*)d_in[13];  const float* bL1  = (const float*)d_in[14];
    const float* WfL1 = (const float*)d_in[15];  const float* bfL1 = (const float*)d_in[16];
    const float* WL2  = (const float*)d_in[17];  const float* bL2  = (const float*)d_in[18];
    const float* WfL2 = (const float*)d_in[19];  const float* bfL2 = (const float*)d_in[20];
    const float* WO1  = (const float*)d_in[21];  const float* bO1  = (const float*)d_in[22];
    const float* WfO1 = (const float*)d_in[23];  const float* bfO1 = (const float*)d_in[24];
    const float* WO2  = (const float*)d_in[25];  const float* bO2  = (const float*)d_in[26];
    const float* WfO2 = (const float*)d_in[27];  const float* bfO2 = (const float*)d_in[28];
    const float* WO3  = (const float*)d_in[29];  const float* bO3  = (const float*)d_in[30];
    const float* WfO3 = (const float*)d_in[31];  const float* bfO3 = (const float*)d_in[32];
    float* out = (float*)d_out;

    const int n = in_sizes[0] / 3;       // 100000
    const int E = in_sizes[1] / 2;       // 1600000
    const int* src = adj;
    const int* dst = adj + E;

    // ---- workspace carve (~174 MB) ----
    char* ws = (char*)d_ws;
    size_t off = 0;
    auto alloc = [&](size_t bytes) -> void* {
        void* p = ws + off;
        off = (off + bytes + 255) & ~(size_t)255;
        return p;
    };
    int*   deg     = (int*)alloc((size_t)n * 4);     // zero span 1 start
    int*   fill    = (int*)alloc((size_t)n * 4);
    int*   cdeg    = (int*)alloc(NCLUST * 4);
    int*   cfill   = (int*)alloc(NCLUST * 4);
    int*   rowptr  = (int*)alloc((size_t)n * 4);     // zero span 1 end (exclusive)
    int*   crowptr = (int*)alloc(NCLUST * 4);
    int*   cnodes  = (int*)alloc((size_t)n * 4);
    int*   bcarr   = (int*)alloc((size_t)n * 4);
    float* dinv    = (float*)alloc((size_t)n * 4);
    int*   bsum    = (int*)alloc(512);
    int*   csr_src = (int*)alloc((size_t)E * 4);
    float* csr_w   = (float*)alloc((size_t)E * 4);
    float* X       = (float*)alloc((size_t)n * 256 * 4);
    float* B       = (float*)alloc((size_t)n * 128 * 4);
    float* insum   = (float*)alloc(256 * 4);         // zero span 2 start
    float* insumsq = (float*)alloc(256 * 4);
    float* px      = (float*)alloc((size_t)NCLUST * 256 * 4);
    unsigned char* bmT = (unsigned char*)alloc((size_t)NCLUST * NCLUST);
    float* mu      = (float*)alloc(256 * 4);         // zero span 2 end (exclusive)
    float* rstd    = (float*)alloc(256 * 4);
    float* dinvp   = (float*)alloc(NCLUST * 4);
    float* lA      = (float*)alloc((size_t)NCLUST * 128 * 4);
    float* lB      = (float*)alloc((size_t)NCLUST * 128 * 4);
    // packed weights (u32 count = K*BN/2 each)
    unsigned* pfG1h = (unsigned*)alloc(2048 * 4);   unsigned* pfG1l = (unsigned*)alloc(2048 * 4);
    unsigned* pG2h  = (unsigned*)alloc(8192 * 4);   unsigned* pG2l  = (unsigned*)alloc(8192 * 4);
    unsigned* pfG2h = (unsigned*)alloc(32768 * 4);  unsigned* pfG2l = (unsigned*)alloc(32768 * 4);
    unsigned* pO1h  = (unsigned*)alloc(16384 * 4);  unsigned* pO1l  = (unsigned*)alloc(16384 * 4);
    unsigned* pfO1h = (unsigned*)alloc(8192 * 4);   unsigned* pfO1l = (unsigned*)alloc(8192 * 4);
    unsigned* pO2h  = (unsigned*)alloc(2048 * 4);   unsigned* pO2l  = (unsigned*)alloc(2048 * 4);
    unsigned* pfO2h = (unsigned*)alloc(512 * 4);    unsigned* pfO2l = (unsigned*)alloc(512 * 4);
    (void)ws_size; (void)n_in; (void)out_size;

    float* B0 = B;
    float* B1 = B + (size_t)n * 64;

    auto cdiv = [](int a, int b) { return (a + b - 1) / b; };
    const int EB = cdiv(E, 256);
    const int GB64 = cdiv(n, 64);        // gmfma grid, BN>128
    const int GB128 = cdiv(n, 128);      // gmfma grid, BN<=128

    // ---- zero scratch ----
    int nz1 = (int)(((char*)rowptr - (char*)deg) / 16);
    int nz2 = (int)(((char*)mu - (char*)insum) / 16);
    k_zero<<<cdiv(nz1, 256), 256, 0, stream>>>((int4*)deg, nz1);
    k_zero<<<cdiv(nz2, 256), 256, 0, stream>>>((int4*)insum, nz2);

    // ---- pack weights to MFMA fragment order ----
    k_wpack<<<cdiv(512, 256), 256, 0, stream>>>(WfG1, pfG1h, pfG1l, 64, 64);
    k_wpack<<<cdiv(2048, 256), 256, 0, stream>>>(WG2, pG2h, pG2l, 64, 256);
    k_wpack<<<cdiv(8192, 256), 256, 0, stream>>>(WfG2, pfG2h, pfG2l, 256, 256);
    k_wpack<<<cdiv(4096, 256), 256, 0, stream>>>(WO1, pO1h, pO1l, 256, 128);
    k_wpack<<<cdiv(2048, 256), 256, 0, stream>>>(WfO1, pfO1h, pfO1l, 128, 128);
    k_wpack<<<cdiv(512, 256), 256, 0, stream>>>(WO2, pO2h, pO2l, 128, 32);
    k_wpack<<<cdiv(128, 256), 256, 0, stream>>>(WfO2, pfO2h, pfO2l, 32, 32);

    // ---- CSR build (edges) ----
    k_hist<<<EB, 256, 0, stream>>>(dst, deg, E);
    int nb = cdiv(n, 1024);
    k_scan_block<<<nb, 256, 0, stream>>>(deg, rowptr, bsum, n);
    k_scan_tops<<<1, 128, 0, stream>>>(bsum, nb);
    k_scan_add<<<cdiv(n, 256), 256, 0, stream>>>(rowptr, bsum, n);
    k_dinv_bc<<<cdiv(n, 256), 256, 0, stream>>>(deg, cluster, inb, dinv, bcarr, n);
    k_fill<<<EB, 256, 0, stream>>>(src, dst, dinv, rowptr, fill, csr_src, csr_w, E);

    // ---- CSR build (cluster member lists) ----
    k_hist<<<cdiv(n, 256), 256, 0, stream>>>(bcarr, cdeg, n);
    k_scan_block<<<1, 256, 0, stream>>>(cdeg, crowptr, bsum, NCLUST);
    k_cfill<<<cdiv(n, 256), 256, 0, stream>>>(bcarr, crowptr, cfill, cnodes, n);

    // ---- global GCN stack ----
    k_prop3<<<cdiv(n, 256), 256, 0, stream>>>(x, dinv, rowptr, deg, csr_src, csr_w,
                                              nullptr, B0, n, 0);
    k_fc<64, 2><<<cdiv(n, 32), 256, 0, stream>>>(B0, WG1, bG1, nullptr, nullptr, B1, n, 3, 1);
    // h2 = elu(h1 @ WfG1 + bfG1)  (B1 in-place)
    k_gmfma<64><<<GB128, 256, 0, stream>>>(B1, pfG1h, pfG1l, bfG1, nullptr, nullptr, B1, n, 64, 1);
    k_prop4<<<cdiv(n * 16, 256), 256, 0, stream>>>(B1, dinv, rowptr, deg, csr_src, csr_w,
                                                   nullptr, B0, n, 64, 4, 0);
    // h3 = elu(p64 @ WG2 + bG2)  (X)
    k_gmfma<256><<<GB64, 256, 0, stream>>>(B0, pG2h, pG2l, bG2, nullptr, nullptr, X, n, 64, 1);
    // h4 = elu(h3 @ WfG2 + bfG2)  (X in-place)
    k_gmfma<256><<<GB64, 256, 0, stream>>>(X, pfG2h, pfG2l, bfG2, nullptr, nullptr, X, n, 256, 1);

    // ---- instance norm (in place) -> y = X ----
    k_instats<<<cdiv(n, 128), 256, 0, stream>>>(X, insum, insumsq, n);
    k_infinal<<<1, 256, 0, stream>>>(insum, insumsq, mu, rstd, n);
    k_innorm<<<cdiv(n * 64, 256), 256, 0, stream>>>(X, mu, rstd, n);

    // ---- cluster pooling (gather) ----
    k_poolavg<<<NCLUST, 256, 0, stream>>>(X, crowptr, cdeg, cnodes, px);
    k_pooledges<<<EB, 256, 0, stream>>>(src, dst, bcarr, bmT, E);
    k_pooldeg<<<NCLUST, 256, 0, stream>>>(bmT, dinvp);

    // ---- local (pooled) GCN stack ----
    k_fc<128, 2><<<cdiv(NCLUST, 16), 256, 0, stream>>>(px, WL1, nullptr, nullptr, nullptr,
                                                       lA, NCLUST, 256, 0);
    k_proppool2<128><<<NCLUST, 1024, 0, stream>>>(lA, dinvp, bmT, bL1, lB);
    k_fc<128, 2><<<cdiv(NCLUST, 16), 256, 0, stream>>>(lB, WfL1, bfL1, nullptr, nullptr,
                                                       lA, NCLUST, 128, 1);
    k_fc<64, 2><<<cdiv(NCLUST, 32), 256, 0, stream>>>(lA, WL2, nullptr, nullptr, nullptr,
                                                      lB, NCLUST, 128, 0);
    k_proppool2<64><<<NCLUST, 1024, 0, stream>>>(lB, dinvp, bmT, bL2, lA);
    k_fc<64, 2><<<cdiv(NCLUST, 32), 256, 0, stream>>>(lA, WfL2, bfL2, nullptr, nullptr,
                                                      lB, NCLUST, 64, 1);
    k_fc<128, 2><<<cdiv(NCLUST, 16), 256, 0, stream>>>(lB, WO1 + (size_t)256 * 128, nullptr,
                                                       nullptr, nullptr, lA, NCLUST, 64, 0);

    // ---- output GCN stack ----
    // t1 = y @ WO1[0:256,:] + compO[bc]  (B, N x 128)
    k_gmfma<128><<<GB128, 256, 0, stream>>>(X, pO1h, pO1l, nullptr, lA, bcarr, B, n, 256, 0);
    k_prop4<<<cdiv(n * 32, 256), 256, 0, stream>>>(B, dinv, rowptr, deg, csr_src, csr_w,
                                                   bO1, X, n, 128, 5, 1);
    // o2 = elu(o1 @ WfO1 + bfO1)  (X in-place)
    k_gmfma<128><<<GB128, 256, 0, stream>>>(X, pfO1h, pfO1l, bfO1, nullptr, nullptr, X, n, 128, 1);
    // t2 = o2 @ WO2  (B, N x 32)
    k_gmfma<32><<<GB128, 256, 0, stream>>>(X, pO2h, pO2l, nullptr, nullptr, nullptr, B, n, 128, 0);
    k_prop4<<<cdiv(n * 8, 256), 256, 0, stream>>>(B, dinv, rowptr, deg, csr_src, csr_w,
                                                  bO2, X, n, 32, 3, 1);
    // o4 = elu(o3 @ WfO2 + bfO2)  (X in-place)
    k_gmfma<32><<<GB128, 256, 0, stream>>>(X, pfO2h, pfO2l, bfO2, nullptr, nullptr, X, n, 32, 1);
    k_fc3<<<cdiv(n, 256), 256, 0, stream>>>(X, WO3, nullptr, B, n, 32, 0);
    k_prop3<<<cdiv(n, 256), 256, 0, stream>>>(B, dinv, rowptr, deg, csr_src, csr_w,
                                              bO3, X, n, 1);
    k_fc3<<<cdiv(n, 256), 256, 0, stream>>>(X, WfO3, bfO3, out, n, 3, 1);
}

// Round 12
// 1281.587 us; speedup vs baseline: 1.5960x; 1.0235x over previous
//
#include <hip/hip_runtime.h>

// ---------------------------------------------------------------------------
// GCN3D: 3x GCNConv + fc (global), instance-norm, cluster pool, 2x GCNConv
// (pooled 1024-cluster graph), gather-broadcast, 3x GCNConv + fc (out).
// N=100000 nodes, E=1600000 edges, C=1024 clusters.
// R3: atomic pooling -> cluster-CSR gather.
// R9: dense fc layers -> split-bf16 MFMA (fp32-equivalent via 3 MFMAs).
// R10: k_proppool2 (1024-thr s-split).
// R12: k_gmfma NTW=4 -- with NTW=8 the k-step's 16 W loads exceeded the VGPR
//   budget, so the compiler serialized ct-iterations (8 exposed L2 round
//   trips/k-step). NTW=4 lets ALL of a k-step's loads issue together:
//   BN=256 -> 1x4 wave split (32-row blocks), BN=128 -> 2x2 (64-row),
//   BN<=64 -> 4x1 (128-row).
// ---------------------------------------------------------------------------

#define NCLUST 1024

typedef short bf16x8 __attribute__((ext_vector_type(8)));
typedef float f32x4 __attribute__((ext_vector_type(4)));

__device__ __forceinline__ float elu1(float x) { return x > 0.f ? x : expm1f(x); }

__device__ __forceinline__ unsigned f2bf(float f) {
    union { float f; unsigned u; } c; c.f = f;
    unsigned u = c.u;
    return (u + 0x7fffu + ((u >> 16) & 1u)) >> 16;
}
__device__ __forceinline__ float bf2f(unsigned h) {
    union { unsigned u; float f; } c; c.u = h << 16; return c.f;
}

union U8 { unsigned u[4]; bf16x8 v; };

__global__ void k_zero(int4* __restrict__ p, int n4) {
    int i = blockIdx.x * 256 + threadIdx.x;
    if (i < n4) p[i] = make_int4(0, 0, 0, 0);
}

// ---------------- CSR build (shared by edge graph and cluster lists) --------
__global__ void k_hist(const int* __restrict__ key, int* __restrict__ deg, int E) {
    int e = blockIdx.x * 256 + threadIdx.x;
    if (e < E) atomicAdd(&deg[key[e]], 1);
}

__global__ void k_scan_block(const int* __restrict__ deg, int* __restrict__ rowptr,
                             int* __restrict__ bsum, int n) {
    __shared__ int lds[256];
    int tid = threadIdx.x;
    int base = blockIdx.x * 1024 + tid * 4;
    int v0 = base + 0 < n ? deg[base + 0] : 0;
    int v1 = base + 1 < n ? deg[base + 1] : 0;
    int v2 = base + 2 < n ? deg[base + 2] : 0;
    int v3 = base + 3 < n ? deg[base + 3] : 0;
    int tsum = v0 + v1 + v2 + v3;
    lds[tid] = tsum; __syncthreads();
    for (int off = 1; off < 256; off <<= 1) {
        int t = (tid >= off) ? lds[tid - off] : 0;
        __syncthreads();
        lds[tid] += t;
        __syncthreads();
    }
    int run = lds[tid] - tsum;
    if (base + 0 < n) rowptr[base + 0] = run; run += v0;
    if (base + 1 < n) rowptr[base + 1] = run; run += v1;
    if (base + 2 < n) rowptr[base + 2] = run; run += v2;
    if (base + 3 < n) rowptr[base + 3] = run;
    if (tid == 255) bsum[blockIdx.x] = lds[255];
}

__global__ void k_scan_tops(int* __restrict__ bsum, int nb) {
    __shared__ int lds[128];
    int tid = threadIdx.x;
    int v = tid < nb ? bsum[tid] : 0;
    lds[tid] = v; __syncthreads();
    for (int off = 1; off < 128; off <<= 1) {
        int t = (tid >= off) ? lds[tid - off] : 0;
        __syncthreads();
        lds[tid] += t;
        __syncthreads();
    }
    if (tid < nb) bsum[tid] = lds[tid] - v;
}

__global__ void k_scan_add(int* __restrict__ rowptr, const int* __restrict__ bsum, int n) {
    int i = blockIdx.x * 256 + threadIdx.x;
    if (i < n) rowptr[i] += bsum[i >> 10];
}

__global__ void k_dinv_bc(const int* __restrict__ deg, const int* __restrict__ cluster,
                          const int* __restrict__ inb, float* __restrict__ dinv,
                          int* __restrict__ bc, int n) {
    int i = blockIdx.x * 256 + threadIdx.x;
    if (i < n) {
        dinv[i] = rsqrtf((float)deg[i] + 1.0f);
        bc[i] = cluster[i] + inb[i] * NCLUST;
    }
}

__global__ void k_fill(const int* __restrict__ src, const int* __restrict__ dst,
                       const float* __restrict__ dinv, const int* __restrict__ rowptr,
                       int* __restrict__ fill, int* __restrict__ csr_src,
                       float* __restrict__ csr_w, int E) {
    int e = blockIdx.x * 256 + threadIdx.x;
    if (e >= E) return;
    int d = dst[e];
    int pos = rowptr[d] + atomicAdd(&fill[d], 1);
    int s = src[e];
    csr_src[pos] = s;
    csr_w[pos] = dinv[s];
}

__global__ void k_cfill(const int* __restrict__ bc, const int* __restrict__ crowptr,
                        int* __restrict__ cfill, int* __restrict__ cnodes, int n) {
    int i = blockIdx.x * 256 + threadIdx.x;
    if (i >= n) return;
    int c = bc[i];
    int pos = crowptr[c] + atomicAdd(&cfill[c], 1);
    cnodes[pos] = i;
}

// ---------------- GCN propagation: out = S*h (+bias, elu) ----------------
__global__ __launch_bounds__(256) void k_prop4(
        const float* __restrict__ h, const float* __restrict__ dinv,
        const int* __restrict__ rowptr, const int* __restrict__ deg,
        const int* __restrict__ csr_src, const float* __restrict__ csr_w,
        const float* __restrict__ bias, float* __restrict__ out,
        int n, int F, int lshift, int flags) {
    int gid = blockIdx.x * 256 + threadIdx.x;
    int node = gid >> lshift;
    if (node >= n) return;
    int fi = (gid & ((1 << lshift) - 1)) * 4;
    int start = rowptr[node];
    int cnt = deg[node];
    float ax = 0.f, ay = 0.f, az = 0.f, aw = 0.f;
    for (int j = 0; j < cnt; j++) {
        int s = csr_src[start + j];
        float w = csr_w[start + j];
        const float4 v = *reinterpret_cast<const float4*>(&h[(size_t)s * F + fi]);
        ax += w * v.x; ay += w * v.y; az += w * v.z; aw += w * v.w;
    }
    float di = dinv[node];
    const float4 sv = *reinterpret_cast<const float4*>(&h[(size_t)node * F + fi]);
    float4 o;
    o.x = di * ax + di * di * sv.x;
    o.y = di * ay + di * di * sv.y;
    o.z = di * az + di * di * sv.z;
    o.w = di * aw + di * di * sv.w;
    if (flags) {
        const float4 b = *reinterpret_cast<const float4*>(&bias[fi]);
        o.x = elu1(o.x + b.x); o.y = elu1(o.y + b.y);
        o.z = elu1(o.z + b.z); o.w = elu1(o.w + b.w);
    }
    *reinterpret_cast<float4*>(&out[(size_t)node * F + fi]) = o;
}

__global__ void k_prop3(const float* __restrict__ h, const float* __restrict__ dinv,
                        const int* __restrict__ rowptr, const int* __restrict__ deg,
                        const int* __restrict__ csr_src, const float* __restrict__ csr_w,
                        const float* __restrict__ bias, float* __restrict__ out,
                        int n, int flags) {
    int node = blockIdx.x * 256 + threadIdx.x;
    if (node >= n) return;
    int start = rowptr[node], cnt = deg[node];
    float a0 = 0.f, a1 = 0.f, a2 = 0.f;
    for (int j = 0; j < cnt; j++) {
        int s = csr_src[start + j];
        float w = csr_w[start + j];
        a0 += w * h[(size_t)s * 3 + 0];
        a1 += w * h[(size_t)s * 3 + 1];
        a2 += w * h[(size_t)s * 3 + 2];
    }
    float di = dinv[node];
    float o0 = di * a0 + di * di * h[(size_t)node * 3 + 0];
    float o1 = di * a1 + di * di * h[(size_t)node * 3 + 1];
    float o2 = di * a2 + di * di * h[(size_t)node * 3 + 2];
    if (flags) {
        o0 = elu1(o0 + bias[0]); o1 = elu1(o1 + bias[1]); o2 = elu1(o2 + bias[2]);
    }
    out[(size_t)node * 3 + 0] = o0;
    out[(size_t)node * 3 + 1] = o1;
    out[(size_t)node * 3 + 2] = o2;
}

// ---- W pre-pack to MFMA fragment order (hi/lo bf16 pairs) ----
__global__ void k_wpack(const float* __restrict__ W, unsigned* __restrict__ Phi,
                        unsigned* __restrict__ Plo, int K, int BN) {
    int t = blockIdx.x * 256 + threadIdx.x;
    int NT = BN / 16;
    int total = (K / 32) * NT * 64;
    if (t >= total) return;
    int lane = t & 63;
    int rest = t >> 6;
    int ct = rest % NT;
    int s = rest / NT;
    int col = ct * 16 + (lane & 15);
    int g = lane >> 4;
    int k0 = s * 32;
    float e[8];
#pragma unroll
    for (int j = 0; j < 4; j++) {
        e[j]     = W[(size_t)(k0 + 4 * g + j) * BN + col];
        e[4 + j] = W[(size_t)(k0 + 16 + 4 * g + j) * BN + col];
    }
#pragma unroll
    for (int j = 0; j < 4; j++) {
        unsigned h0 = f2bf(e[2 * j]), h1 = f2bf(e[2 * j + 1]);
        Phi[(size_t)t * 4 + j] = h0 | (h1 << 16);
        unsigned l0 = f2bf(e[2 * j] - bf2f(h0));
        unsigned l1 = f2bf(e[2 * j + 1] - bf2f(h1));
        Plo[(size_t)t * 4 + j] = l0 | (l1 << 16);
    }
}

// ---- split-bf16 MFMA GEMM, 32 rows/wave, NTW<=4 col-tiles/wave ----
// WROW x WCOL wave grid (WROW*WCOL = 4). All of a k-step's loads fit in the
// VGPR budget -> single latency exposure per k-step. __syncthreads before
// stores keeps in-place + col-split race-free.
template <int BN>
__global__ __launch_bounds__(256) void k_gmfma(
        const float* __restrict__ A, const unsigned* __restrict__ Phi,
        const unsigned* __restrict__ Plo, const float* __restrict__ bias,
        const float* __restrict__ add, const int* __restrict__ addidx,
        float* __restrict__ C, int N, int K, int flags) {
    constexpr int NT = BN / 16;
    constexpr int WCOL = (BN == 256) ? 4 : (BN == 128 ? 2 : 1);
    constexpr int WROW = 4 / WCOL;
    constexpr int NTW = NT / WCOL;          // col-tiles per wave (<=4)
    constexpr int BR = 32 * WROW;           // rows per block (32/64/128)
    const int t = threadIdx.x;
    const int w = t >> 6, l = t & 63;
    const int wr = w / WCOL, wc = w % WCOL;
    const int l15 = l & 15, g = l >> 4;
    const int row0 = blockIdx.x * BR + wr * 32;
    const int ctbase = wc * NTW;
    int ar0 = row0 + l15;      ar0 = ar0 < N ? ar0 : N - 1;
    int ar1 = row0 + 16 + l15; ar1 = ar1 < N ? ar1 : N - 1;
    const float* ap0 = A + (size_t)ar0 * K;
    const float* ap1 = A + (size_t)ar1 * K;

    f32x4 acc[2][NTW];
#pragma unroll
    for (int f = 0; f < 2; f++)
#pragma unroll
        for (int ct = 0; ct < NTW; ct++) acc[f][ct] = (f32x4){0.f, 0.f, 0.f, 0.f};

    const int nk = K / 32;
    for (int s = 0; s < nk; ++s) {
        const int k0 = s * 32;
        // --- load W fragments for this k-step (all issue together) ---
        const unsigned* pb = Phi + ((size_t)(s * NT + ctbase) * 64 + l) * 4;
        const unsigned* pl = Plo + ((size_t)(s * NT + ctbase) * 64 + l) * 4;
        U8 wh[NTW], wl[NTW];
#pragma unroll
        for (int ct = 0; ct < NTW; ct++) {
            wh[ct] = *reinterpret_cast<const U8*>(pb + (size_t)ct * 256);
            wl[ct] = *reinterpret_cast<const U8*>(pl + (size_t)ct * 256);
        }
        // --- load + convert A fragments ---
        U8 ahi[2], alo[2];
#pragma unroll
        for (int f = 0; f < 2; f++) {
            const float* ap = f ? ap1 : ap0;
            const float4 a0 = *reinterpret_cast<const float4*>(ap + k0 + 4 * g);
            const float4 a1 = *reinterpret_cast<const float4*>(ap + k0 + 16 + 4 * g);
            float e[8] = {a0.x, a0.y, a0.z, a0.w, a1.x, a1.y, a1.z, a1.w};
#pragma unroll
            for (int j = 0; j < 4; j++) {
                unsigned h0 = f2bf(e[2 * j]), h1 = f2bf(e[2 * j + 1]);
                ahi[f].u[j] = h0 | (h1 << 16);
                unsigned l0 = f2bf(e[2 * j] - bf2f(h0));
                unsigned l1 = f2bf(e[2 * j + 1] - bf2f(h1));
                alo[f].u[j] = l0 | (l1 << 16);
            }
        }
        // --- MFMAs ---
#pragma unroll
        for (int ct = 0; ct < NTW; ct++) {
            acc[0][ct] = __builtin_amdgcn_mfma_f32_16x16x32_bf16(ahi[0].v, wh[ct].v, acc[0][ct], 0, 0, 0);
            acc[0][ct] = __builtin_amdgcn_mfma_f32_16x16x32_bf16(ahi[0].v, wl[ct].v, acc[0][ct], 0, 0, 0);
            acc[0][ct] = __builtin_amdgcn_mfma_f32_16x16x32_bf16(alo[0].v, wh[ct].v, acc[0][ct], 0, 0, 0);
            acc[1][ct] = __builtin_amdgcn_mfma_f32_16x16x32_bf16(ahi[1].v, wh[ct].v, acc[1][ct], 0, 0, 0);
            acc[1][ct] = __builtin_amdgcn_mfma_f32_16x16x32_bf16(ahi[1].v, wl[ct].v, acc[1][ct], 0, 0, 0);
            acc[1][ct] = __builtin_amdgcn_mfma_f32_16x16x32_bf16(alo[1].v, wh[ct].v, acc[1][ct], 0, 0, 0);
        }
    }
    __syncthreads();   // all A reads done before any store (in-place, col-split)
#pragma unroll
    for (int f = 0; f < 2; f++) {
#pragma unroll
        for (int r = 0; r < 4; r++) {
            int row = row0 + 16 * f + 4 * g + r;
            if (row >= N) continue;
            int gi = (add != nullptr) ? addidx[row] : 0;
#pragma unroll
            for (int ct = 0; ct < NTW; ct++) {
                int col = (ctbase + ct) * 16 + l15;
                float o = acc[f][ct][r];
                if (add != nullptr) o += add[(size_t)gi * BN + col];
                if (flags) o = elu1(o + bias[col]);
                C[(size_t)row * BN + col] = o;
            }
        }
    }
}

// ---------------- simple fc (small shapes: K=3 layer, local C=1024 stack) ----
template <int M, int RPT>
__global__ __launch_bounds__(256) void k_fc(
        const float* __restrict__ A, const float* __restrict__ W,
        const float* __restrict__ bias, const float* __restrict__ add,
        const int* __restrict__ addidx, float* __restrict__ C,
        int N, int K, int flags) {
    constexpr int TX = M / 4;
    constexpr int TY = 256 / TX;
    constexpr int RB = TY * RPT;
    int tx = threadIdx.x % TX;
    int ty = threadIdx.x / TX;
    int row0 = blockIdx.x * RB + ty * RPT;
    float4 acc[RPT];
#pragma unroll
    for (int r = 0; r < RPT; r++) acc[r] = make_float4(0.f, 0.f, 0.f, 0.f);
    for (int k = 0; k < K; k++) {
        float4 w = *reinterpret_cast<const float4*>(&W[(size_t)k * M + tx * 4]);
#pragma unroll
        for (int r = 0; r < RPT; r++) {
            int row = row0 + r;
            row = row < N ? row : N - 1;
            float a = A[(size_t)row * K + k];
            acc[r].x += a * w.x; acc[r].y += a * w.y;
            acc[r].z += a * w.z; acc[r].w += a * w.w;
        }
    }
    if (add != nullptr) {
#pragma unroll
        for (int r = 0; r < RPT; r++) {
            int row = row0 + r;
            if (row < N) {
                int g = addidx[row];
                const float4 v = *reinterpret_cast<const float4*>(&add[(size_t)g * M + tx * 4]);
                acc[r].x += v.x; acc[r].y += v.y; acc[r].z += v.z; acc[r].w += v.w;
            }
        }
    }
    __syncthreads();
    float4 b = make_float4(0.f, 0.f, 0.f, 0.f);
    if (flags) b = *reinterpret_cast<const float4*>(&bias[tx * 4]);
#pragma unroll
    for (int r = 0; r < RPT; r++) {
        int row = row0 + r;
        if (row >= N) break;
        float4 o = acc[r];
        o.x += b.x; o.y += b.y; o.z += b.z; o.w += b.w;
        if (flags) { o.x = elu1(o.x); o.y = elu1(o.y); o.z = elu1(o.z); o.w = elu1(o.w); }
        *reinterpret_cast<float4*>(&C[(size_t)row * M + tx * 4]) = o;
    }
}

// M = 3 (W: K x 3)
__global__ void k_fc3(const float* __restrict__ A, const float* __restrict__ W,
                      const float* __restrict__ b, float* __restrict__ C,
                      int n, int K, int flags) {
    int r = blockIdx.x * 256 + threadIdx.x;
    if (r >= n) return;
    float a0 = 0.f, a1 = 0.f, a2 = 0.f;
    for (int k = 0; k < K; k++) {
        float a = A[(size_t)r * K + k];
        a0 += a * W[k * 3 + 0]; a1 += a * W[k * 3 + 1]; a2 += a * W[k * 3 + 2];
    }
    if (flags) {
        a0 = elu1(a0 + b[0]); a1 = elu1(a1 + b[1]); a2 = elu1(a2 + b[2]);
    }
    C[(size_t)r * 3 + 0] = a0;
    C[(size_t)r * 3 + 1] = a1;
    C[(size_t)r * 3 + 2] = a2;
}

// ---------------- instance norm (in-place apply) ----------------
__global__ void k_instats(const float* __restrict__ h, float* __restrict__ sum,
                          float* __restrict__ sumsq, int n) {
    int c = threadIdx.x;
    int r0 = blockIdx.x * 128;
    int r1 = r0 + 128 < n ? r0 + 128 : n;
    float s = 0.f, q = 0.f;
    for (int r = r0; r < r1; r++) {
        float v = h[(size_t)r * 256 + c];
        s += v; q += v * v;
    }
    atomicAdd(&sum[c], s);
    atomicAdd(&sumsq[c], q);
}

__global__ void k_infinal(const float* __restrict__ sum, const float* __restrict__ sumsq,
                          float* __restrict__ mu, float* __restrict__ rstd, int n) {
    int c = threadIdx.x;
    float m = sum[c] / (float)n;
    float var = sumsq[c] / (float)n - m * m;
    mu[c] = m;
    rstd[c] = rsqrtf(var + 1e-5f);
}

__global__ void k_innorm(float* __restrict__ h, const float* __restrict__ mu,
                         const float* __restrict__ rstd, int n) {
    int gid = blockIdx.x * 256 + threadIdx.x;
    int node = gid >> 6;
    if (node >= n) return;
    int c = (gid & 63) * 4;
    float4 v = *reinterpret_cast<const float4*>(&h[(size_t)node * 256 + c]);
    float4 m = *reinterpret_cast<const float4*>(&mu[c]);
    float4 rs = *reinterpret_cast<const float4*>(&rstd[c]);
    v.x = (v.x - m.x) * rs.x; v.y = (v.y - m.y) * rs.y;
    v.z = (v.z - m.z) * rs.z; v.w = (v.w - m.w) * rs.w;
    *reinterpret_cast<float4*>(&h[(size_t)node * 256 + c]) = v;
}

// ---------------- cluster pooling (CSR gather, no atomics) ----------------
__global__ __launch_bounds__(256) void k_poolavg(
        const float* __restrict__ y, const int* __restrict__ crowptr,
        const int* __restrict__ cdeg, const int* __restrict__ cnodes,
        float* __restrict__ px) {
    int cl = blockIdx.x;
    int c  = threadIdx.x;
    int start = crowptr[cl];
    int cnt = cdeg[cl];
    float acc = 0.f;
    for (int j = 0; j < cnt; j++) {
        int node = cnodes[start + j];
        acc += y[(size_t)node * 256 + c];
    }
    px[(size_t)cl * 256 + c] = acc / fmaxf((float)cnt, 1.0f);
}

__global__ void k_pooledges(const int* __restrict__ src, const int* __restrict__ dst,
                            const int* __restrict__ bc, unsigned char* __restrict__ bmT, int E) {
    int e = blockIdx.x * 256 + threadIdx.x;
    if (e >= E) return;
    int ps = bc[src[e]];
    int pd = bc[dst[e]];
    bmT[(size_t)pd * NCLUST + ps] = 1;
}

__global__ __launch_bounds__(256) void k_pooldeg(
        const unsigned char* __restrict__ bmT, float* __restrict__ dinvp) {
    int d = blockIdx.x;
    int t = threadIdx.x;
    const unsigned int v = reinterpret_cast<const unsigned int*>(bmT + (size_t)d * NCLUST)[t];
    int s = (v & 0xff) + ((v >> 8) & 0xff) + ((v >> 16) & 0xff) + ((v >> 24) & 0xff);
    if (t == (d >> 2)) s -= (v >> ((d & 3) * 8)) & 0xff;
    __shared__ int red[256];
    red[t] = s; __syncthreads();
    for (int o = 128; o > 0; o >>= 1) {
        if (t < o) red[t] += red[t + o];
        __syncthreads();
    }
    if (t == 0) dinvp[d] = rsqrtf((float)red[0] + 1.0f);
}

// pooled propagation: 1024 threads = SG s-groups x F lanes.
template <int F>
__global__ __launch_bounds__(1024) void k_proppool2(
        const float* __restrict__ h, const float* __restrict__ dinvp,
        const unsigned char* __restrict__ bmT, const float* __restrict__ bias,
        float* __restrict__ out) {
    constexpr int SG = 1024 / F;
    const int d = blockIdx.x;
    const int t = threadIdx.x;
    const int f = t & (F - 1);
    const int sg = t / F;
    const unsigned char* bmrow = bmT + (size_t)d * NCLUST;
    float acc = 0.f;
#pragma unroll 4
    for (int s = sg; s < NCLUST; s += SG) {
        float m = (s != d) ? (float)bmrow[s] : 0.f;
        acc += m * dinvp[s] * h[(size_t)s * F + f];
    }
    __shared__ float red[1024];
    red[t] = acc; __syncthreads();
#pragma unroll
    for (int o = SG / 2; o > 0; o >>= 1) {
        if (sg < o) red[t] += red[t + o * F];
        __syncthreads();
    }
    if (sg == 0) {
        float di = dinvp[d];
        float r = di * red[f] + di * di * h[(size_t)d * F + f] + bias[f];
        out[(size_t)d * F + f] = elu1(r);
    }
}

// ---------------------------------------------------------------------------
extern "C" void kernel_launch(void* const* d_in, const int* in_sizes, int n_in,
                              void* d_out, int out_size, void* d_ws, size_t ws_size,
                              hipStream_t stream) {
    const float* x       = (const float*)d_in[0];
    const int*   adj     = (const int*)d_in[1];
    const int*   inb     = (const int*)d_in[3];
    const int*   cluster = (const int*)d_in[4];
    const float* WG1  = (const float*)d_in[5];   const float* bG1  = (const float*)d_in[6];
    const float* WfG1 = (const float*)d_in[7];   const float* bfG1 = (const float*)d_in[8];
    const float* WG2  = (const float*)d_in[9];   const float* bG2  = (const float*)d_in[10];
    const float* WfG2 = (const float*)d_in[11];  const float* bfG2 = (const float*)d_in[12];
    const float* WL1  = (const float*)d_in[13];  const float* bL1  = (const float*)d_in[14];
    const float* WfL1 = (const float*)d_in[15];  const float* bfL1 = (const float*)d_in[16];
    const float* WL2  = (const float*)d_in[17];  const float* bL2  = (const float*)d_in[18];
    const float* WfL2 = (const float*)d_in[19];  const float* bfL2 = (const float*)d_in[20];
    const float* WO1  = (const float*)d_in[21];  const float* bO1  = (const float*)d_in[22];
    const float* WfO1 = (const float*)d_in[23];  const float* bfO1 = (const float*)d_in[24];
    const float* WO2  = (const float*)d_in[25];  const float* bO2  = (const float*)d_in[26];
    const float* WfO2 = (const float*)d_in[27];  const float* bfO2 = (const float*)d_in[28];
    const float* WO3  = (const float*)d_in[29];  const float* bO3  = (const float*)d_in[30];
    const float* WfO3 = (const float*)d_in[31];  const float* bfO3 = (const float*)d_in[32];
    float* out = (float*)d_out;

    const int n = in_sizes[0] / 3;       // 100000
    const int E = in_sizes[1] / 2;       // 1600000
    const int* src = adj;
    const int* dst = adj + E;

    // ---- workspace carve (~174 MB) ----
    char* ws = (char*)d_ws;
    size_t off = 0;
    auto alloc = [&](size_t bytes) -> void* {
        void* p = ws + off;
        off = (off + bytes + 255) & ~(size_t)255;
        return p;
    };
    int*   deg     = (int*)alloc((size_t)n * 4);     // zero span 1 start
    int*   fill    = (int*)alloc((size_t)n * 4);
    int*   cdeg    = (int*)alloc(NCLUST * 4);
    int*   cfill   = (int*)alloc(NCLUST * 4);
    int*   rowptr  = (int*)alloc((size_t)n * 4);     // zero span 1 end (exclusive)
    int*   crowptr = (int*)alloc(NCLUST * 4);
    int*   cnodes  = (int*)alloc((size_t)n * 4);
    int*   bcarr   = (int*)alloc((size_t)n * 4);
    float* dinv    = (float*)alloc((size_t)n * 4);
    int*   bsum    = (int*)alloc(512);
    int*   csr_src = (int*)alloc((size_t)E * 4);
    float* csr_w   = (float*)alloc((size_t)E * 4);
    float* X       = (float*)alloc((size_t)n * 256 * 4);
    float* B       = (float*)alloc((size_t)n * 128 * 4);
    float* insum   = (float*)alloc(256 * 4);         // zero span 2 start
    float* insumsq = (float*)alloc(256 * 4);
    float* px      = (float*)alloc((size_t)NCLUST * 256 * 4);
    unsigned char* bmT = (unsigned char*)alloc((size_t)NCLUST * NCLUST);
    float* mu      = (float*)alloc(256 * 4);         // zero span 2 end (exclusive)
    float* rstd    = (float*)alloc(256 * 4);
    float* dinvp   = (float*)alloc(NCLUST * 4);
    float* lA      = (float*)alloc((size_t)NCLUST * 128 * 4);
    float* lB      = (float*)alloc((size_t)NCLUST * 128 * 4);
    // packed weights (u32 count = K*BN/2 each)
    unsigned* pfG1h = (unsigned*)alloc(2048 * 4);   unsigned* pfG1l = (unsigned*)alloc(2048 * 4);
    unsigned* pG2h  = (unsigned*)alloc(8192 * 4);   unsigned* pG2l  = (unsigned*)alloc(8192 * 4);
    unsigned* pfG2h = (unsigned*)alloc(32768 * 4);  unsigned* pfG2l = (unsigned*)alloc(32768 * 4);
    unsigned* pO1h  = (unsigned*)alloc(16384 * 4);  unsigned* pO1l  = (unsigned*)alloc(16384 * 4);
    unsigned* pfO1h = (unsigned*)alloc(8192 * 4);   unsigned* pfO1l = (unsigned*)alloc(8192 * 4);
    unsigned* pO2h  = (unsigned*)alloc(2048 * 4);   unsigned* pO2l  = (unsigned*)alloc(2048 * 4);
    unsigned* pfO2h = (unsigned*)alloc(512 * 4);    unsigned* pfO2l = (unsigned*)alloc(512 * 4);
    (void)ws_size; (void)n_in; (void)out_size;

    float* B0 = B;
    float* B1 = B + (size_t)n * 64;

    auto cdiv = [](int a, int b) { return (a + b - 1) / b; };
    const int EB = cdiv(E, 256);
    const int GB32 = cdiv(n, 32);        // gmfma grid, BN=256
    const int GB64 = cdiv(n, 64);        // gmfma grid, BN=128
    const int GB128 = cdiv(n, 128);      // gmfma grid, BN<=64

    // ---- zero scratch ----
    int nz1 = (int)(((char*)rowptr - (char*)deg) / 16);
    int nz2 = (int)(((char*)mu - (char*)insum) / 16);
    k_zero<<<cdiv(nz1, 256), 256, 0, stream>>>((int4*)deg, nz1);
    k_zero<<<cdiv(nz2, 256), 256, 0, stream>>>((int4*)insum, nz2);

    // ---- pack weights to MFMA fragment order ----
    k_wpack<<<cdiv(512, 256), 256, 0, stream>>>(WfG1, pfG1h, pfG1l, 64, 64);
    k_wpack<<<cdiv(2048, 256), 256, 0, stream>>>(WG2, pG2h, pG2l, 64, 256);
    k_wpack<<<cdiv(8192, 256), 256, 0, stream>>>(WfG2, pfG2h, pfG2l, 256, 256);
    k_wpack<<<cdiv(4096, 256), 256, 0, stream>>>(WO1, pO1h, pO1l, 256, 128);
    k_wpack<<<cdiv(2048, 256), 256, 0, stream>>>(WfO1, pfO1h, pfO1l, 128, 128);
    k_wpack<<<cdiv(512, 256), 256, 0, stream>>>(WO2, pO2h, pO2l, 128, 32);
    k_wpack<<<cdiv(128, 256), 256, 0, stream>>>(WfO2, pfO2h, pfO2l, 32, 32);

    // ---- CSR build (edges) ----
    k_hist<<<EB, 256, 0, stream>>>(dst, deg, E);
    int nb = cdiv(n, 1024);
    k_scan_block<<<nb, 256, 0, stream>>>(deg, rowptr, bsum, n);
    k_scan_tops<<<1, 128, 0, stream>>>(bsum, nb);
    k_scan_add<<<cdiv(n, 256), 256, 0, stream>>>(rowptr, bsum, n);
    k_dinv_bc<<<cdiv(n, 256), 256, 0, stream>>>(deg, cluster, inb, dinv, bcarr, n);
    k_fill<<<EB, 256, 0, stream>>>(src, dst, dinv, rowptr, fill, csr_src, csr_w, E);

    // ---- CSR build (cluster member lists) ----
    k_hist<<<cdiv(n, 256), 256, 0, stream>>>(bcarr, cdeg, n);
    k_scan_block<<<1, 256, 0, stream>>>(cdeg, crowptr, bsum, NCLUST);
    k_cfill<<<cdiv(n, 256), 256, 0, stream>>>(bcarr, crowptr, cfill, cnodes, n);

    // ---- global GCN stack ----
    k_prop3<<<cdiv(n, 256), 256, 0, stream>>>(x, dinv, rowptr, deg, csr_src, csr_w,
                                              nullptr, B0, n, 0);
    k_fc<64, 2><<<cdiv(n, 32), 256, 0, stream>>>(B0, WG1, bG1, nullptr, nullptr, B1, n, 3, 1);
    // h2 = elu(h1 @ WfG1 + bfG1)  (B1 in-place)
    k_gmfma<64><<<GB128, 256, 0, stream>>>(B1, pfG1h, pfG1l, bfG1, nullptr, nullptr, B1, n, 64, 1);
    k_prop4<<<cdiv(n * 16, 256), 256, 0, stream>>>(B1, dinv, rowptr, deg, csr_src, csr_w,
                                                   nullptr, B0, n, 64, 4, 0);
    // h3 = elu(p64 @ WG2 + bG2)  (X)
    k_gmfma<256><<<GB32, 256, 0, stream>>>(B0, pG2h, pG2l, bG2, nullptr, nullptr, X, n, 64, 1);
    // h4 = elu(h3 @ WfG2 + bfG2)  (X in-place)
    k_gmfma<256><<<GB32, 256, 0, stream>>>(X, pfG2h, pfG2l, bfG2, nullptr, nullptr, X, n, 256, 1);

    // ---- instance norm (in place) -> y = X ----
    k_instats<<<cdiv(n, 128), 256, 0, stream>>>(X, insum, insumsq, n);
    k_infinal<<<1, 256, 0, stream>>>(insum, insumsq, mu, rstd, n);
    k_innorm<<<cdiv(n * 64, 256), 256, 0, stream>>>(X, mu, rstd, n);

    // ---- cluster pooling (gather) ----
    k_poolavg<<<NCLUST, 256, 0, stream>>>(X, crowptr, cdeg, cnodes, px);
    k_pooledges<<<EB, 256, 0, stream>>>(src, dst, bcarr, bmT, E);
    k_pooldeg<<<NCLUST, 256, 0, stream>>>(bmT, dinvp);

    // ---- local (pooled) GCN stack ----
    k_fc<128, 2><<<cdiv(NCLUST, 16), 256, 0, stream>>>(px, WL1, nullptr, nullptr, nullptr,
                                                       lA, NCLUST, 256, 0);
    k_proppool2<128><<<NCLUST, 1024, 0, stream>>>(lA, dinvp, bmT, bL1, lB);
    k_fc<128, 2><<<cdiv(NCLUST, 16), 256, 0, stream>>>(lB, WfL1, bfL1, nullptr, nullptr,
                                                       lA, NCLUST, 128, 1);
    k_fc<64, 2><<<cdiv(NCLUST, 32), 256, 0, stream>>>(lA, WL2, nullptr, nullptr, nullptr,
                                                      lB, NCLUST, 128, 0);
    k_proppool2<64><<<NCLUST, 1024, 0, stream>>>(lB, dinvp, bmT, bL2, lA);
    k_fc<64, 2><<<cdiv(NCLUST, 32), 256, 0, stream>>>(lA, WfL2, bfL2, nullptr, nullptr,
                                                      lB, NCLUST, 64, 1);
    k_fc<128, 2><<<cdiv(NCLUST, 16), 256, 0, stream>>>(lB, WO1 + (size_t)256 * 128, nullptr,
                                                       nullptr, nullptr, lA, NCLUST, 64, 0);

    // ---- output GCN stack ----
    // t1 = y @ WO1[0:256,:] + compO[bc]  (B, N x 128)
    k_gmfma<128><<<GB64, 256, 0, stream>>>(X, pO1h, pO1l, nullptr, lA, bcarr, B, n, 256, 0);
    k_prop4<<<cdiv(n * 32, 256), 256, 0, stream>>>(B, dinv, rowptr, deg, csr_src, csr_w,
                                                   bO1, X, n, 128, 5, 1);
    // o2 = elu(o1 @ WfO1 + bfO1)  (X in-place)
    k_gmfma<128><<<GB64, 256, 0, stream>>>(X, pfO1h, pfO1l, bfO1, nullptr, nullptr, X, n, 128, 1);
    // t2 = o2 @ WO2  (B, N x 32)
    k_gmfma<32><<<GB128, 256, 0, stream>>>(X, pO2h, pO2l, nullptr, nullptr, nullptr, B, n, 128, 0);
    k_prop4<<<cdiv(n * 8, 256), 256, 0, stream>>>(B, dinv, rowptr, deg, csr_src, csr_w,
                                                  bO2, X, n, 32, 3, 1);
    // o4 = elu(o3 @ WfO2 + bfO2)  (X in-place)
    k_gmfma<32><<<GB128, 256, 0, stream>>>(X, pfO2h, pfO2l, bfO2, nullptr, nullptr, X, n, 32, 1);
    k_fc3<<<cdiv(n, 256), 256, 0, stream>>>(X, WO3, nullptr, B, n, 32, 0);
    k_prop3<<<cdiv(n, 256), 256, 0, stream>>>(B, dinv, rowptr, deg, csr_src, csr_w,
                                              bO3, X, n, 1);
    k_fc3<<<cdiv(n, 256), 256, 0, stream>>>(X, WfO3, bfO3, out, n, 3, 1);
}